// Round 6
// baseline (7605.389 us; speedup 1.0000x reference)
//
#include <hip/hip_runtime.h>
#include <math.h>

#define S_LEN 400
#define BATCH 32
#define HID   512
#define G3    1536
#define N2    3072
#define VOC   50000
#define OUTW  (VOC + S_LEN)

typedef unsigned long long ull;
typedef unsigned int uint;
typedef float v2f __attribute__((ext_vector_type(2)));
typedef uint  uv4 __attribute__((ext_vector_type(4)));

__device__ __forceinline__ float sigf(float x) { return 1.f / (1.f + __expf(-x)); }
__device__ __forceinline__ float tanh_fast(float x) {
  const float xc = fminf(fmaxf(x, -15.f), 15.f);
  const float e = __expf(-2.f * xc);
  return (1.f - e) / (1.f + e);
}

// ---------------------------------------------------------------------------
// Persistent bidirectional GRU scan, counter-gated one-shot gather, fw/bw
// interleaved per block.
// 128 blocks x 512 thr: ht = bid&31 (16 j's), bg = bid>>5 (8 batches).
// Each block holds U-slices for BOTH directions; per iteration it runs an
// fw phase then a bw phase. Sync per (dir,bg) group of 32 blocks:
//   publish tagged 8B {fp32,step} packets (relaxed agent) + one atomicAdd
//   on the group counter per block. Consumers spin on the 4B counter only
//   (tiny LLC traffic), then gather packets once; tags remain the source of
//   truth (counter-early races re-poll). One direction's propagation hides
//   under the other direction's compute phase.
// ---------------------------------------------------------------------------
__global__ __launch_bounds__(512) void gru_scan(
    const float* __restrict__ xzm,            // [32*400][3072] fw|bw
    const float* __restrict__ Ufw, const float* __restrict__ Ubw,
    const float* __restrict__ bfw, const float* __restrict__ bbw,
    float* __restrict__ enc_seq, ull* __restrict__ pkbase,
    uint* __restrict__ ctrbase)
{
  const int bid = blockIdx.x;        // 0..127
  const int ht  = bid & 31;          // j-tile: 16 j's
  const int bg  = bid >> 5;          // 0..3: batches bg*8..bg*8+7
  const int tid = threadIdx.x;
  const int jl = tid & 15;
  const int kc = tid >> 4;           // 0..31 chunks of 16 k
  const int k0 = kc * 16;
  const int jg = ht * 16 + jl;
  const int w  = tid >> 6;           // wave 0..7

  // U tiles in registers as k-pairs, both directions
  v2f uf0[8], uf1[8], uf2[8], ub0[8], ub1[8], ub2[8];
  #pragma unroll
  for (int i = 0; i < 8; ++i) {
    const float* up = Ufw + (size_t)(k0 + 2*i) * G3 + jg;
    uf0[i] = v2f{up[0],    up[G3]};
    uf1[i] = v2f{up[512],  up[G3+512]};
    uf2[i] = v2f{up[1024], up[G3+1024]};
    const float* vp = Ubw + (size_t)(k0 + 2*i) * G3 + jg;
    ub0[i] = v2f{vp[0],    vp[G3]};
    ub1[i] = v2f{vp[512],  vp[G3+512]};
    ub2[i] = v2f{vp[1024], vp[G3+1024]};
  }

  __shared__ float h_lds[8][HID];        // 16 KB (reused by both phases)
  __shared__ float red[8][3][8][16];     // 12 KB (b, gate, wave, jl)

  // consumer mapping: wave w = batch-in-group, lane covers 8 j's
  const int cb = w;
  const int cj = (tid & 63) * 8;
  // producer mapping (threads 0..127)
  const int gbi = tid >> 4;
  const int gj  = tid & 15;
  const int gjq = ht * 16 + gj;
  const int gb  = bg * 8 + gbi;
  const float* brf = bfw + G3;
  const float* brb = bbw + G3;
  const float bfz = brf[gjq], bfr = brf[512+gjq], bfh = brf[1024+gjq];
  const float bbz = brb[gjq], bbr = brb[512+gjq], bbh = brb[1024+gjq];

  // one phase = one direction's step t
  auto phase = [&](const int dir, const int t,
                   v2f (&u0)[8], v2f (&u1)[8], v2f (&u2)[8],
                   const float brz, const float brr, const float brh,
                   const float xzv0, const float xzv1, const float xzv2) {
    ull* __restrict__ pk = pkbase + (size_t)dir * (2 * BATCH * HID);
    uint* __restrict__ ctr = ctrbase + dir * 4 + bg;
    const int ts = dir ? (S_LEN - 1 - t) : t;

    // ---- counter gate (tiny poll) ----
    if (t > 0) {
      while (__hip_atomic_load(ctr, __ATOMIC_RELAXED, __HIP_MEMORY_SCOPE_AGENT)
             < 32u * (uint)t)
        __builtin_amdgcn_s_sleep(1);
    }
    // ---- one-shot tagged gather (fallback re-poll on rare race) ----
    {
      const ull* fp = pk + ((size_t)(t & 1) * BATCH + (bg * 8 + cb)) * HID + cj;
      const uint tu = (uint)t;
      for (;;) {
        uv4 q0, q1, q2, q3;
        asm volatile(
          "global_load_dwordx4 %0, %4, off sc0 sc1\n\t"
          "global_load_dwordx4 %1, %4, off offset:16 sc0 sc1\n\t"
          "global_load_dwordx4 %2, %4, off offset:32 sc0 sc1\n\t"
          "global_load_dwordx4 %3, %4, off offset:48 sc0 sc1\n\t"
          "s_waitcnt vmcnt(0)"
          : "=&v"(q0), "=&v"(q1), "=&v"(q2), "=&v"(q3)
          : "v"(fp)
          : "memory");
        const bool ok = (q0.y == tu) & (q0.w == tu) & (q1.y == tu) & (q1.w == tu)
                      & (q2.y == tu) & (q2.w == tu) & (q3.y == tu) & (q3.w == tu);
        if (__all(ok)) {
          float2* hd = (float2*)&h_lds[cb][cj];
          hd[0] = float2{__uint_as_float(q0.x), __uint_as_float(q0.z)};
          hd[1] = float2{__uint_as_float(q1.x), __uint_as_float(q1.z)};
          hd[2] = float2{__uint_as_float(q2.x), __uint_as_float(q2.z)};
          hd[3] = float2{__uint_as_float(q3.x), __uint_as_float(q3.z)};
          break;
        }
        __builtin_amdgcn_s_sleep(1);
      }
    }
    __syncthreads();   // S1: h_lds ready

    const float hold = (tid < 128) ? h_lds[gbi][gjq] : 0.f;

    // ---- recurrent matvec: packed-fp32 partials over 16-k chunk ----
    #pragma unroll 1
    for (int b = 0; b < 8; ++b) {
      v2f a0 = v2f{0.f,0.f}, a1 = v2f{0.f,0.f}, a2 = v2f{0.f,0.f};
      const float4* hp = (const float4*)&h_lds[b][k0];
      #pragma unroll
      for (int q = 0; q < 4; ++q) {
        const float4 hv = hp[q];
        const v2f hxy = v2f{hv.x, hv.y};
        const v2f hzw = v2f{hv.z, hv.w};
        a0 += hxy * u0[2*q]; a0 += hzw * u0[2*q+1];
        a1 += hxy * u1[2*q]; a1 += hzw * u1[2*q+1];
        a2 += hxy * u2[2*q]; a2 += hzw * u2[2*q+1];
      }
      float s0 = a0.x + a0.y, s1 = a1.x + a1.y, s2 = a2.x + a2.y;
      s0 += __shfl_xor(s0, 16); s0 += __shfl_xor(s0, 32);
      s1 += __shfl_xor(s1, 16); s1 += __shfl_xor(s1, 32);
      s2 += __shfl_xor(s2, 16); s2 += __shfl_xor(s2, 32);
      if ((tid & 48) == 0) {
        red[b][0][w][jl] = s0;
        red[b][1][w][jl] = s1;
        red[b][2][w][jl] = s2;
      }
    }
    __syncthreads();   // S2: red ready

    // ---- gates + publish h(t+1) ----
    float hnew = 0.f;
    if (tid < 128) {
      float rz = brz, rr = brr, rh = brh;
      #pragma unroll
      for (int x = 0; x < 8; ++x) {
        rz += red[gbi][0][x][gj];
        rr += red[gbi][1][x][gj];
        rh += red[gbi][2][x][gj];
      }
      const float z  = sigf(xzv0 + rz);
      const float r  = sigf(xzv1 + rr);
      const float hh = tanh_fast(xzv2 + r * rh);
      hnew = z * hold + (1.f - z) * hh;
      const ull pack = ((ull)(uint)(t + 1) << 32) | (ull)__float_as_uint(hnew);
      __hip_atomic_store(pk + ((size_t)((t + 1) & 1) * BATCH + gb) * HID + gjq,
                         pack, __ATOMIC_RELAXED, __HIP_MEMORY_SCOPE_AGENT);
    }
    __syncthreads();   // S3: all publishes issued; red/h_lds free
    if (tid == 0)
      __hip_atomic_fetch_add(ctr, 1u, __ATOMIC_RELAXED, __HIP_MEMORY_SCOPE_AGENT);
    if (tid < 128)
      enc_seq[((size_t)gb * S_LEN + ts) * 1024 + dir * 512 + gjq] = hnew;
  };

  for (int t = 0; t < S_LEN; ++t) {
    // prefetch xz for both phases (independent of h)
    float xf0 = 0.f, xf1 = 0.f, xf2 = 0.f, xb0 = 0.f, xb1 = 0.f, xb2 = 0.f;
    if (tid < 128) {
      const float* xf = xzm + ((size_t)gb * S_LEN + t) * N2 + gjq;
      xf0 = xf[0]; xf1 = xf[512]; xf2 = xf[1024];
      const float* xb = xzm + ((size_t)gb * S_LEN + (S_LEN - 1 - t)) * N2 + G3 + gjq;
      xb0 = xb[0]; xb1 = xb[512]; xb2 = xb[1024];
    }
    phase(0, t, uf0, uf1, uf2, bfz, bfr, bfh, xf0, xf1, xf2);
    phase(1, t, ub0, ub1, ub2, bbz, bbr, bbh, xb0, xb1, xb2);
  }
}

// ---------------------------------------------------------------------------
// Concatenate enc_fw_W|enc_bw_W -> Wm[512][3072], biases row0 -> bm[3072]
// ---------------------------------------------------------------------------
__global__ __launch_bounds__(256) void k_mergeW(
    const float* __restrict__ fwW, const float* __restrict__ bwW,
    const float* __restrict__ fwb, const float* __restrict__ bwb,
    float* __restrict__ Wm, float* __restrict__ bm)
{
  const int idx = blockIdx.x*256 + threadIdx.x;   // < 512*1536
  const int k = idx / G3, n = idx - k*G3;
  Wm[(size_t)k*N2 + n]      = fwW[idx];
  Wm[(size_t)k*N2 + G3 + n] = bwW[idx];
  if (idx < G3) { bm[idx] = fwb[idx]; bm[G3+idx] = bwb[idx]; }
}

// ---------------------------------------------------------------------------
// fp32 tiled GEMM, 128x128x16, 256 thr, 8x8 microtile, v_pk_fma_f32 inner.
// gather: A row = emb[rowids[r]]; epi_att: fused tanh(acc+dterm)*att_V.
// ---------------------------------------------------------------------------
__global__ __launch_bounds__(256) void gemm_big(
    const int gather, const int epi_att,
    const int* __restrict__ rowids,
    const float* __restrict__ Abase, const int lda,
    const float* __restrict__ W, const int N, const int K,
    const float* __restrict__ bias,
    float* __restrict__ out,
    const float* __restrict__ dterm, const float* __restrict__ attV,
    float* __restrict__ e_part)
{
  const int m0 = blockIdx.y * 128, n0 = blockIdx.x * 128;
  const int tid = threadIdx.x;
  __shared__ float As[16][128];
  __shared__ float Bs[16][128];
  __shared__ int   rid[128];
  __shared__ float pr[128][16];
  if (tid < 128) rid[tid] = gather ? rowids[m0 + tid] : (m0 + tid);
  __syncthreads();
  v2f acc[8][4];
  #pragma unroll
  for (int i = 0; i < 8; ++i)
    #pragma unroll
    for (int j = 0; j < 4; ++j) acc[i][j] = v2f{0.f, 0.f};
  const int tx = tid & 15, ty = tid >> 4;
  const int ar = tid >> 1, ac = (tid & 1) * 8;
  const int bc = tid >> 4, bn = (tid & 15) * 8;

  for (int k0 = 0; k0 < K; k0 += 16) {
    const float* ap = Abase + (size_t)rid[ar] * lda + k0 + ac;
    const float4 av0 = *(const float4*)ap;
    const float4 av1 = *(const float4*)(ap + 4);
    const float* bp = W + (size_t)(k0 + bc) * N + n0 + bn;
    const float4 bv0 = *(const float4*)bp;
    const float4 bv1 = *(const float4*)(bp + 4);
    As[ac+0][ar] = av0.x; As[ac+1][ar] = av0.y; As[ac+2][ar] = av0.z; As[ac+3][ar] = av0.w;
    As[ac+4][ar] = av1.x; As[ac+5][ar] = av1.y; As[ac+6][ar] = av1.z; As[ac+7][ar] = av1.w;
    *(float4*)&Bs[bc][bn]   = bv0;
    *(float4*)&Bs[bc][bn+4] = bv1;
    __syncthreads();
    #pragma unroll
    for (int kk = 0; kk < 16; ++kk) {
      const float4 a0 = *(const float4*)&As[kk][ty*8];
      const float4 a1 = *(const float4*)&As[kk][ty*8+4];
      const float4 b0 = *(const float4*)&Bs[kk][tx*8];
      const float4 b1 = *(const float4*)&Bs[kk][tx*8+4];
      const float a[8]  = {a0.x,a0.y,a0.z,a0.w,a1.x,a1.y,a1.z,a1.w};
      const v2f bb[4] = {v2f{b0.x,b0.y}, v2f{b0.z,b0.w}, v2f{b1.x,b1.y}, v2f{b1.z,b1.w}};
      #pragma unroll
      for (int i = 0; i < 8; ++i) {
        const v2f ai = v2f{a[i], a[i]};
        #pragma unroll
        for (int j = 0; j < 4; ++j)
          acc[i][j] += ai * bb[j];
      }
    }
    __syncthreads();
  }

  if (!epi_att) {
    #pragma unroll
    for (int i = 0; i < 8; ++i) {
      const int r = m0 + ty*8 + i;
      float4 o0, o1;
      o0.x = acc[i][0].x + bias[n0+tx*8+0];
      o0.y = acc[i][0].y + bias[n0+tx*8+1];
      o0.z = acc[i][1].x + bias[n0+tx*8+2];
      o0.w = acc[i][1].y + bias[n0+tx*8+3];
      o1.x = acc[i][2].x + bias[n0+tx*8+4];
      o1.y = acc[i][2].y + bias[n0+tx*8+5];
      o1.z = acc[i][3].x + bias[n0+tx*8+6];
      o1.w = acc[i][3].y + bias[n0+tx*8+7];
      *(float4*)&out[(size_t)r * N + n0 + tx*8]     = o0;
      *(float4*)&out[(size_t)r * N + n0 + tx*8 + 4] = o1;
    }
  } else {
    float attv[8];
    #pragma unroll
    for (int j = 0; j < 8; ++j) attv[j] = attV[n0 + tx*8 + j];
    #pragma unroll
    for (int i = 0; i < 8; ++i) {
      const int r = m0 + ty*8 + i;
      const int b = r / S_LEN;
      const float* dtp = dterm + (size_t)b * 512 + n0 + tx*8;
      float p = 0.f;
      #pragma unroll
      for (int j = 0; j < 4; ++j) {
        p += attv[2*j]   * tanh_fast(acc[i][j].x + dtp[2*j]);
        p += attv[2*j+1] * tanh_fast(acc[i][j].y + dtp[2*j+1]);
      }
      pr[ty*8+i][tx] = p;
    }
    __syncthreads();
    if (tid < 128) {
      float s = 0.f;
      #pragma unroll
      for (int x = 0; x < 16; ++x) s += pr[tid][x];
      e_part[(size_t)(m0 + tid) * 4 + blockIdx.x] = s;
    }
  }
}

// --------------------------- small kernels ---------------------------------
__global__ __launch_bounds__(128) void k_state(const float* __restrict__ enc,
    const float* __restrict__ red_W, const float* __restrict__ red_b,
    float* __restrict__ state)
{
  const int b = blockIdx.y;
  const int j = blockIdx.x*128 + threadIdx.x;
  float acc = red_b[j];
  const float* fw = enc + ((size_t)b*S_LEN + (S_LEN-1))*1024;
  const float* bw = enc + ((size_t)b*S_LEN + 0)*1024 + 512;
  #pragma unroll 4
  for (int k = 0; k < 512; ++k) acc += fw[k] * red_W[(size_t)k*512 + j];
  #pragma unroll 4
  for (int k = 0; k < 512; ++k) acc += bw[k] * red_W[(size_t)(512+k)*512 + j];
  state[(size_t)b*512 + j] = fmaxf(acc, 0.f);
}

__global__ void k_yemb(const int* __restrict__ y_id, const float* __restrict__ emb,
                       float* __restrict__ yemb)
{
  const int b = blockIdx.x, tid = threadIdx.x;
  const int r = y_id[b];
  yemb[(size_t)b*512 + tid]       = emb[(size_t)r*512 + tid];
  yemb[(size_t)b*512 + 256 + tid] = emb[(size_t)r*512 + 256 + tid];
}

__global__ __launch_bounds__(128) void k_dec(const float* __restrict__ yemb,
    const float* __restrict__ state, const float* __restrict__ dec_W,
    const float* __restrict__ dec_U, const float* __restrict__ dec_b,
    float* __restrict__ dst)
{
  const int b = blockIdx.y;
  const int j = blockIdx.x*128 + threadIdx.x;
  float xz0 = dec_b[j], xz1 = dec_b[512+j], xz2 = dec_b[1024+j];
  float rc0 = dec_b[G3+j], rc1 = dec_b[G3+512+j], rc2 = dec_b[G3+1024+j];
  const float* ye = yemb + (size_t)b*512;
  const float* st = state + (size_t)b*512;
  #pragma unroll 2
  for (int k = 0; k < 512; ++k) {
    const float* wp = dec_W + (size_t)k*G3 + j;
    const float* up = dec_U + (size_t)k*G3 + j;
    const float yv = ye[k], sv = st[k];
    xz0 += yv*wp[0]; xz1 += yv*wp[512]; xz2 += yv*wp[1024];
    rc0 += sv*up[0]; rc1 += sv*up[512]; rc2 += sv*up[1024];
  }
  const float z  = sigf(xz0 + rc0);
  const float r  = sigf(xz1 + rc1);
  const float hh = tanh_fast(xz2 + r*rc2);
  dst[(size_t)b*512 + j] = z*st[j] + (1.f-z)*hh;
}

__global__ __launch_bounds__(128) void k_dterm(const float* __restrict__ dec,
    const float* __restrict__ att_Ws, const float* __restrict__ att_bs,
    float* __restrict__ dterm)
{
  const int b = blockIdx.y;
  const int j = blockIdx.x*128 + threadIdx.x;
  float acc = att_bs[j];
  const float* d = dec + (size_t)b*512;
  #pragma unroll 4
  for (int k = 0; k < 512; ++k) acc += d[k] * att_Ws[(size_t)k*512 + j];
  dterm[(size_t)b*512 + j] = acc;
}

__global__ __launch_bounds__(512) void k_soft(const float* __restrict__ e_part,
    const int* __restrict__ x_mask, float* __restrict__ wat)
{
  const int b = blockIdx.x, tid = threadIdx.x;
  __shared__ float sm[512];
  float e = -1e30f, ev = 0.f;
  if (tid < S_LEN) {
    const float* ep = e_part + (size_t)(b*S_LEN + tid)*4;
    ev = ep[0]+ep[1]+ep[2]+ep[3] + (float)x_mask[b*S_LEN+tid] * -1e10f;
    e = ev;
  }
  sm[tid] = e; __syncthreads();
  for (int s = 256; s > 0; s >>= 1) { if (tid < s) sm[tid] = fmaxf(sm[tid], sm[tid+s]); __syncthreads(); }
  const float m = sm[0]; __syncthreads();
  const float x = (tid < S_LEN) ? __expf(ev - m) : 0.f;
  sm[tid] = x; __syncthreads();
  for (int s = 256; s > 0; s >>= 1) { if (tid < s) sm[tid] += sm[tid+s]; __syncthreads(); }
  const float inv = 1.f / sm[0];
  if (tid < S_LEN) wat[b*S_LEN+tid] = x * inv;
}

__global__ __launch_bounds__(128) void k_ctx(const float* __restrict__ wat,
    const float* __restrict__ enc, float* __restrict__ ctx)
{
  const int b = blockIdx.y;
  const int j = blockIdx.x*128 + threadIdx.x;
  float acc = 0.f;
  const float* w = wat + b*S_LEN;
  const float* ep = enc + (size_t)b*S_LEN*1024 + j;
  #pragma unroll 4
  for (int s = 0; s < S_LEN; ++s) acc += w[s] * ep[(size_t)s*1024];
  ctx[(size_t)b*1024 + j] = acc;
}

__global__ __launch_bounds__(128) void k_yout(const float* __restrict__ dec,
    const float* __restrict__ ctx, const float* __restrict__ fc_W,
    const float* __restrict__ fc_b, float* __restrict__ y_out)
{
  const int b = blockIdx.y;
  const int j = blockIdx.x*128 + threadIdx.x;
  float acc = fc_b[j];
  const float* d = dec + (size_t)b*512;
  const float* c = ctx + (size_t)b*1024;
  #pragma unroll 4
  for (int k = 0; k < 512; ++k)  acc += d[k]*fc_W[(size_t)k*512 + j];
  #pragma unroll 4
  for (int k = 0; k < 1024; ++k) acc += c[k]*fc_W[(size_t)(512+k)*512 + j];
  y_out[(size_t)b*512 + j] = acc;
}

__global__ __launch_bounds__(256) void k_pgen(const float* __restrict__ ctx,
    const float* __restrict__ dec, const float* __restrict__ yemb,
    const float* __restrict__ pg_Wh, const float* __restrict__ pg_Ws,
    const float* __restrict__ pg_Wx, const float* __restrict__ pg_b,
    float* __restrict__ pg)
{
  const int b = blockIdx.x, tid = threadIdx.x;
  __shared__ float sm[256];
  float acc = 0.f;
  for (int k = tid; k < 1024; k += 256) acc += ctx[(size_t)b*1024+k]*pg_Wh[k];
  for (int k = tid; k < 512;  k += 256) acc += dec[(size_t)b*512+k]*pg_Ws[k] + yemb[(size_t)b*512+k]*pg_Wx[k];
  sm[tid] = acc; __syncthreads();
  for (int s = 128; s > 0; s >>= 1) { if (tid < s) sm[tid] += sm[tid+s]; __syncthreads(); }
  if (tid == 0) pg[b] = sigf(sm[0] + pg_b[0]);
}

__global__ __launch_bounds__(256) void k_vocab(const float* __restrict__ y_out,
    const float* __restrict__ vocab_W, float* __restrict__ logits)
{
  __shared__ float y_lds[256][32];   // [k][b], one k-half at a time (32 KB)
  const int tid = threadIdx.x;
  const int vq = tid & 63, bq = tid >> 6;
  const int v = blockIdx.x * 256 + vq * 4;
  v2f acc[8][2];
  #pragma unroll
  for (int i = 0; i < 8; ++i) { acc[i][0] = v2f{0.f,0.f}; acc[i][1] = v2f{0.f,0.f}; }
  for (int half = 0; half < 2; ++half) {
    __syncthreads();
    for (int i = 0; i < 32; ++i) {
      const int idx = tid + 256*i;
      const int k = idx >> 5, b = idx & 31;
      y_lds[k][b] = y_out[(size_t)b*512 + half*256 + k];
    }
    __syncthreads();
    if (v < VOC) {
      #pragma unroll 4
      for (int k = 0; k < 256; ++k) {
        const float4 wv = *(const float4*)&vocab_W[(size_t)(half*256 + k) * VOC + v];
        const v2f w0 = v2f{wv.x, wv.y}, w1 = v2f{wv.z, wv.w};
        const float4 ya = *(const float4*)&y_lds[k][bq*8];
        const float4 yb = *(const float4*)&y_lds[k][bq*8+4];
        const float yy[8] = {ya.x,ya.y,ya.z,ya.w,yb.x,yb.y,yb.z,yb.w};
        #pragma unroll
        for (int i = 0; i < 8; ++i) {
          const v2f yi = v2f{yy[i], yy[i]};
          acc[i][0] += yi * w0;
          acc[i][1] += yi * w1;
        }
      }
    }
  }
  if (v < VOC) {
    #pragma unroll
    for (int i = 0; i < 8; ++i)
      *(float4*)&logits[(size_t)(bq*8+i)*VOC + v] =
          make_float4(acc[i][0].x, acc[i][0].y, acc[i][1].x, acc[i][1].y);
  }
}

__global__ __launch_bounds__(1024) void k_vred(const float* __restrict__ logits,
                                               float* __restrict__ red2)
{
  const int b = blockIdx.x, tid = threadIdx.x;
  __shared__ float sm[1024];
  float m = -1e30f;
  for (int i = tid; i < VOC; i += 1024) m = fmaxf(m, logits[(size_t)b*VOC + i]);
  sm[tid] = m; __syncthreads();
  for (int s = 512; s > 0; s >>= 1) { if (tid < s) sm[tid] = fmaxf(sm[tid], sm[tid+s]); __syncthreads(); }
  m = sm[0]; __syncthreads();
  float sum = 0.f;
  for (int i = tid; i < VOC; i += 1024) sum += __expf(logits[(size_t)b*VOC + i] - m);
  sm[tid] = sum; __syncthreads();
  for (int s = 512; s > 0; s >>= 1) { if (tid < s) sm[tid] += sm[tid+s]; __syncthreads(); }
  if (tid == 0) { red2[b*2] = m; red2[b*2+1] = sm[0]; }
}

__global__ __launch_bounds__(256) void k_final(const float* __restrict__ logits,
    const float* __restrict__ red2, const float* __restrict__ pg,
    float* __restrict__ out)
{
  const size_t idx = (size_t)blockIdx.x*256 + threadIdx.x;
  const int b = (int)(idx / OUTW);
  const int c = (int)(idx - (size_t)b*OUTW);
  float v = 0.f;
  if (c < VOC) {
    const float m = red2[b*2], s = red2[b*2+1];
    v = pg[b] * __expf(logits[(size_t)b*VOC + c] - m) / s;
  }
  out[idx] = v;
}

__global__ __launch_bounds__(256) void k_scatter(const float* __restrict__ wat,
    const int* __restrict__ x_mask, const float* __restrict__ pg,
    const int* __restrict__ x_id, float* __restrict__ out)
{
  const int i = blockIdx.x*256 + threadIdx.x;   // < 12800
  const int b = i / S_LEN;
  const float aw = wat[i] * (1.f - (float)x_mask[i]) * (1.f - pg[b]);
  atomicAdd(out + (size_t)b*OUTW + x_id[i], aw);
}

// ---------------------------------------------------------------------------
extern "C" void kernel_launch(void* const* d_in, const int* in_sizes, int n_in,
                              void* d_out, int out_size, void* d_ws, size_t ws_size,
                              hipStream_t stream)
{
  (void)in_sizes; (void)n_in; (void)out_size; (void)ws_size;
  const int*   x_id     = (const int*)d_in[0];
  const int*   y_id     = (const int*)d_in[1];
  const int*   x_mask   = (const int*)d_in[2];
  const float* emb      = (const float*)d_in[3];
  const float* enc_fw_W = (const float*)d_in[4];
  const float* enc_fw_U = (const float*)d_in[5];
  const float* enc_fw_b = (const float*)d_in[6];
  const float* enc_bw_W = (const float*)d_in[7];
  const float* enc_bw_U = (const float*)d_in[8];
  const float* enc_bw_b = (const float*)d_in[9];
  const float* red_W    = (const float*)d_in[10];
  const float* red_b    = (const float*)d_in[11];
  const float* dec_W    = (const float*)d_in[12];
  const float* dec_U    = (const float*)d_in[13];
  const float* dec_b    = (const float*)d_in[14];
  const float* att_Wh   = (const float*)d_in[15];
  const float* att_Ws   = (const float*)d_in[16];
  const float* att_bs   = (const float*)d_in[17];
  const float* att_Wc   = (const float*)d_in[18]; (void)att_Wc; // cover == 0
  const float* att_V    = (const float*)d_in[19];
  const float* fc_W     = (const float*)d_in[20];
  const float* fc_b     = (const float*)d_in[21];
  const float* vocab_W  = (const float*)d_in[22];
  const float* pg_Wh    = (const float*)d_in[23];
  const float* pg_Ws    = (const float*)d_in[24];
  const float* pg_Wx    = (const float*)d_in[25];
  const float* pg_b     = (const float*)d_in[26];
  float* out = (float*)d_out;

  float* ws = (float*)d_ws;
  const size_t SZXZ  = (size_t)BATCH*S_LEN*N2;     // merged fw|bw
  const size_t SZENC = (size_t)BATCH*S_LEN*1024;
  const size_t NPKT  = (size_t)2*2*BATCH*HID;      // [dir][parity][b][j]
  float*    xzm    = ws;
  float*    enc    = xzm + SZXZ;
  ull*      pk     = (ull*)(enc + SZENC);
  uint*     ctr    = (uint*)(pk + NPKT);           // 8 counters (pad 128)
  float*    fstate = (float*)(ctr + 128);
  float*    yemb   = fstate + BATCH*HID;
  float*    decs   = yemb + BATCH*HID;
  float*    dterm  = decs + BATCH*HID;
  float*    epart  = dterm + BATCH*HID;
  float*    wat    = epart + (size_t)BATCH*S_LEN*4;
  float*    ctx    = wat + BATCH*S_LEN;
  float*    yout   = ctx + BATCH*1024;
  float*    pg     = yout + BATCH*HID;
  float*    logits = pg + BATCH;
  float*    red2   = logits + (size_t)BATCH*VOC;
  // Wm/bm alias the logits region (dead until k_vocab, which runs after the GEMM)
  float*    Wm     = logits;                        // 512*3072 + 3072 <= BATCH*VOC
  float*    bm     = logits + (size_t)512*N2;

  // zero packets ({0.0f, tag 0} == valid h(0)) and counters
  hipMemsetAsync(pk, 0, NPKT * sizeof(ull) + 128 * sizeof(uint), stream);

  // merged input projection xz = gather(emb, x_id) @ [Wfw|Wbw] + [bfw0|bbw0]
  k_mergeW<<<(512*G3)/256, 256, 0, stream>>>(enc_fw_W, enc_bw_W, enc_fw_b, enc_bw_b, Wm, bm);
  gemm_big<<<dim3(N2/128, 100), 256, 0, stream>>>(1,0, x_id, emb, 512, Wm, N2, 512,
                                                  bm, xzm, nullptr, nullptr, nullptr);
  // persistent bidirectional GRU scan (counter-gated gather, fw/bw interleave)
  gru_scan<<<128,512,0,stream>>>(xzm, enc_fw_U, enc_bw_U, enc_fw_b, enc_bw_b,
                                 enc, pk, ctr);
  // reduce state + decoder step + attention query term
  k_state<<<dim3(4,32),128,0,stream>>>(enc, red_W, red_b, fstate);
  k_yemb<<<32,256,0,stream>>>(y_id, emb, yemb);
  k_dec<<<dim3(4,32),128,0,stream>>>(yemb, fstate, dec_W, dec_U, dec_b, decs);
  k_dterm<<<dim3(4,32),128,0,stream>>>(decs, att_Ws, att_bs, dterm);
  // attention scores (fused tanh * att_V reduction)
  gemm_big<<<dim3(4,100),256,0,stream>>>(0,1, nullptr, enc, 1024, att_Wh, 512, 1024,
                                         nullptr, nullptr, dterm, att_V, epart);
  k_soft<<<32,512,0,stream>>>(epart, x_mask, wat);
  k_ctx<<<dim3(8,32),128,0,stream>>>(wat, enc, ctx);
  k_yout<<<dim3(4,32),128,0,stream>>>(decs, ctx, fc_W, fc_b, yout);
  k_pgen<<<32,256,0,stream>>>(ctx, decs, yemb, pg_Wh, pg_Ws, pg_Wx, pg_b, pg);
  // vocab distribution + final assembly
  k_vocab<<<196,256,0,stream>>>(yout, vocab_W, logits);
  k_vred<<<32,1024,0,stream>>>(logits, red2);
  k_final<<<6300,256,0,stream>>>(logits, red2, pg, out);
  k_scatter<<<50,256,0,stream>>>(wat, x_mask, pg, x_id, out);
}

// Round 8
// 3569.243 us; speedup vs baseline: 2.1308x; 2.1308x over previous
//
#include <hip/hip_runtime.h>
#include <math.h>

#define S_LEN 400
#define BATCH 32
#define HID   512
#define G3    1536
#define N2    3072
#define VOC   50000
#define OUTW  (VOC + S_LEN)

typedef unsigned long long ull;
typedef unsigned int uint;
typedef float v2f __attribute__((ext_vector_type(2)));

__device__ __forceinline__ float sigf(float x) { return 1.f / (1.f + __expf(-x)); }
__device__ __forceinline__ float tanh_fast(float x) {
  const float xc = fminf(fmaxf(x, -15.f), 15.f);
  const float e = __expf(-2.f * xc);
  return (1.f - e) / (1.f + e);
}

// ---------------------------------------------------------------------------
// Persistent bidirectional GRU scan — round-2 protocol + sentinel polling.
// 256 blocks x 512 thr. group = bid&7 (dir=group>>2, bg=group&3), ht=bid>>3
// (16 j's per block, full K). h moves as tagged 8B {fp32, step} packets via
// relaxed agent atomics (LLC). Consumers spin on ONE sentinel packet per
// thread (4KB/block/round, 8x less poll traffic than all-8), then gather the
// remaining 7 and tag-verify (stragglers re-poll). Tags are the sole source
// of truth. Tag monotonicity: a slot advances t -> t+2 only after every
// block consumed t, so a consumer waiting tag==t can never be skipped.
// ---------------------------------------------------------------------------
__global__ __launch_bounds__(512) void gru_scan(
    const float* __restrict__ xzm,            // [32*400][3072] fw|bw
    const float* __restrict__ Ufw, const float* __restrict__ Ubw,
    const float* __restrict__ bfw, const float* __restrict__ bbw,
    float* __restrict__ enc_seq, ull* __restrict__ hpkt)
{
  const int bid = blockIdx.x;
  const int group = bid & 7;
  const int dir = group >> 2;
  const int bg  = group & 3;
  const int ht  = bid >> 3;          // j-tile: 16 j's
  const int tid = threadIdx.x;
  const int jl = tid & 15;
  const int kc = tid >> 4;           // 0..31 chunks of 16 k
  const int k0 = kc * 16;
  const int jg = ht * 16 + jl;
  const int w  = tid >> 6;           // wave 0..7

  const float* __restrict__ U  = dir ? Ubw : Ufw;
  const float* __restrict__ br = (dir ? bbw : bfw) + G3;   // bias row 1

  // U tile in registers as k-pairs
  v2f u0[8], u1[8], u2[8];
  #pragma unroll
  for (int i = 0; i < 8; ++i) {
    const float* up = U + (size_t)(k0 + 2*i) * G3 + jg;
    u0[i] = v2f{up[0],    up[G3]};
    u1[i] = v2f{up[512],  up[G3+512]};
    u2[i] = v2f{up[1024], up[G3+1024]};
  }

  __shared__ float h_lds[8][HID];        // 16 KB
  __shared__ float red[8][3][8][16];     // 12 KB (b, gate, wave, jl)

  // consumer mapping: wave w = batch-in-group, lane covers 8 j's
  const int cb = w;
  const int cj = (tid & 63) * 8;
  // producer mapping (threads 0..127)
  const int gbi = tid >> 4;
  const int gj  = tid & 15;
  const int gjq = ht * 16 + gj;
  const int gb  = bg * 8 + gbi;
  const float brz = br[gjq], brr = br[512 + gjq], brh = br[1024 + gjq];

  ull* __restrict__ pk = hpkt + (size_t)dir * (2 * BATCH * HID);   // [parity][b][j]

  for (int t = 0; t < S_LEN; ++t) {
    const int ts = dir ? (S_LEN - 1 - t) : t;

    // xz prefetch (independent of h; overlaps the poll)
    float xzv0 = 0.f, xzv1 = 0.f, xzv2 = 0.f;
    if (tid < 128) {
      const float* xp = xzm + ((size_t)gb * S_LEN + ts) * N2 + dir * G3 + gjq;
      xzv0 = xp[0]; xzv1 = xp[512]; xzv2 = xp[1024];
    }

    // ---- consume h(t): sentinel poll, then gather + verify ----
    {
      ull* bp = pk + ((size_t)(t & 1) * BATCH + (bg * 8 + cb)) * HID + cj;
      const uint tu = (uint)t;
      ull s;
      // sentinel spin: 1 packet per thread per round
      for (;;) {
        s = __hip_atomic_load(bp, __ATOMIC_RELAXED, __HIP_MEMORY_SCOPE_AGENT);
        if (__all((uint)(s >> 32) == tu)) break;
        __builtin_amdgcn_s_sleep(1);
      }
      // gather the rest; verify; stragglers re-poll
      for (;;) {
        ull v1 = __hip_atomic_load(bp + 1, __ATOMIC_RELAXED, __HIP_MEMORY_SCOPE_AGENT);
        ull v2 = __hip_atomic_load(bp + 2, __ATOMIC_RELAXED, __HIP_MEMORY_SCOPE_AGENT);
        ull v3 = __hip_atomic_load(bp + 3, __ATOMIC_RELAXED, __HIP_MEMORY_SCOPE_AGENT);
        ull v4 = __hip_atomic_load(bp + 4, __ATOMIC_RELAXED, __HIP_MEMORY_SCOPE_AGENT);
        ull v5 = __hip_atomic_load(bp + 5, __ATOMIC_RELAXED, __HIP_MEMORY_SCOPE_AGENT);
        ull v6 = __hip_atomic_load(bp + 6, __ATOMIC_RELAXED, __HIP_MEMORY_SCOPE_AGENT);
        ull v7 = __hip_atomic_load(bp + 7, __ATOMIC_RELAXED, __HIP_MEMORY_SCOPE_AGENT);
        const bool ok = ((uint)(v1 >> 32) == tu) & ((uint)(v2 >> 32) == tu)
                      & ((uint)(v3 >> 32) == tu) & ((uint)(v4 >> 32) == tu)
                      & ((uint)(v5 >> 32) == tu) & ((uint)(v6 >> 32) == tu)
                      & ((uint)(v7 >> 32) == tu);
        if (__all(ok)) {
          float* hd = &h_lds[cb][cj];
          hd[0] = __uint_as_float((uint)s);
          hd[1] = __uint_as_float((uint)v1);
          hd[2] = __uint_as_float((uint)v2);
          hd[3] = __uint_as_float((uint)v3);
          hd[4] = __uint_as_float((uint)v4);
          hd[5] = __uint_as_float((uint)v5);
          hd[6] = __uint_as_float((uint)v6);
          hd[7] = __uint_as_float((uint)v7);
          break;
        }
        __builtin_amdgcn_s_sleep(1);
      }
    }
    __syncthreads();   // S1: h_lds ready

    // h_old for the gate phase, grabbed before the next fill can overwrite
    const float hold = (tid < 128) ? h_lds[gbi][gjq] : 0.f;

    // ---- recurrent matvec: packed-fp32 partials over 16-k chunk ----
    #pragma unroll 1
    for (int b = 0; b < 8; ++b) {
      v2f a0 = v2f{0.f,0.f}, a1 = v2f{0.f,0.f}, a2 = v2f{0.f,0.f};
      const float4* hp = (const float4*)&h_lds[b][k0];
      #pragma unroll
      for (int q = 0; q < 4; ++q) {
        const float4 hv = hp[q];
        const v2f hxy = v2f{hv.x, hv.y};
        const v2f hzw = v2f{hv.z, hv.w};
        a0 += hxy * u0[2*q]; a0 += hzw * u0[2*q+1];
        a1 += hxy * u1[2*q]; a1 += hzw * u1[2*q+1];
        a2 += hxy * u2[2*q]; a2 += hzw * u2[2*q+1];
      }
      float s0 = a0.x + a0.y, s1 = a1.x + a1.y, s2 = a2.x + a2.y;
      s0 += __shfl_xor(s0, 16); s0 += __shfl_xor(s0, 32);
      s1 += __shfl_xor(s1, 16); s1 += __shfl_xor(s1, 32);
      s2 += __shfl_xor(s2, 16); s2 += __shfl_xor(s2, 32);
      if ((tid & 48) == 0) {
        red[b][0][w][jl] = s0;
        red[b][1][w][jl] = s1;
        red[b][2][w][jl] = s2;
      }
    }
    __syncthreads();   // S2: red ready

    // ---- gates + publish h(t+1) ----
    if (tid < 128) {
      float rz = brz, rr = brr, rh = brh;
      #pragma unroll
      for (int x = 0; x < 8; ++x) {
        rz += red[gbi][0][x][gj];
        rr += red[gbi][1][x][gj];
        rh += red[gbi][2][x][gj];
      }
      const float z  = sigf(xzv0 + rz);
      const float r  = sigf(xzv1 + rr);
      const float hh = tanh_fast(xzv2 + r * rh);
      const float hnew = z * hold + (1.f - z) * hh;
      const ull pack = ((ull)(uint)(t + 1) << 32) | (ull)__float_as_uint(hnew);
      __hip_atomic_store(pk + ((size_t)((t + 1) & 1) * BATCH + gb) * HID + gjq,
                         pack, __ATOMIC_RELAXED, __HIP_MEMORY_SCOPE_AGENT);
      enc_seq[((size_t)gb * S_LEN + ts) * 1024 + dir * 512 + gjq] = hnew;
    }
    __syncthreads();   // S3: publishes issued; h_lds/red safe for next fill
  }
}

// ---------------------------------------------------------------------------
// Concatenate enc_fw_W|enc_bw_W -> Wm[512][3072], biases row0 -> bm[3072]
// ---------------------------------------------------------------------------
__global__ __launch_bounds__(256) void k_mergeW(
    const float* __restrict__ fwW, const float* __restrict__ bwW,
    const float* __restrict__ fwb, const float* __restrict__ bwb,
    float* __restrict__ Wm, float* __restrict__ bm)
{
  const int idx = blockIdx.x*256 + threadIdx.x;   // < 512*1536
  const int k = idx / G3, n = idx - k*G3;
  Wm[(size_t)k*N2 + n]      = fwW[idx];
  Wm[(size_t)k*N2 + G3 + n] = bwW[idx];
  if (idx < G3) { bm[idx] = fwb[idx]; bm[G3+idx] = bwb[idx]; }
}

// ---------------------------------------------------------------------------
// fp32 tiled GEMM, 128x128x16, 256 thr, 8x8 microtile.
// gather: A row = emb[rowids[r]]; epi_att: fused tanh(acc+dterm)*att_V.
// ---------------------------------------------------------------------------
__global__ __launch_bounds__(256) void gemm_big(
    const int gather, const int epi_att,
    const int* __restrict__ rowids,
    const float* __restrict__ Abase, const int lda,
    const float* __restrict__ W, const int N, const int K,
    const float* __restrict__ bias,
    float* __restrict__ out,
    const float* __restrict__ dterm, const float* __restrict__ attV,
    float* __restrict__ e_part)
{
  const int m0 = blockIdx.y * 128, n0 = blockIdx.x * 128;
  const int tid = threadIdx.x;
  __shared__ float As[16][128];
  __shared__ float Bs[16][128];
  __shared__ int   rid[128];
  __shared__ float pr[128][16];
  if (tid < 128) rid[tid] = gather ? rowids[m0 + tid] : (m0 + tid);
  __syncthreads();
  float acc[8][8];
  #pragma unroll
  for (int i = 0; i < 8; ++i)
    #pragma unroll
    for (int j = 0; j < 8; ++j) acc[i][j] = 0.f;
  const int tx = tid & 15, ty = tid >> 4;
  const int ar = tid >> 1, ac = (tid & 1) * 8;
  const int bc = tid >> 4, bn = (tid & 15) * 8;

  for (int k0 = 0; k0 < K; k0 += 16) {
    const float* ap = Abase + (size_t)rid[ar] * lda + k0 + ac;
    const float4 av0 = *(const float4*)ap;
    const float4 av1 = *(const float4*)(ap + 4);
    const float* bp = W + (size_t)(k0 + bc) * N + n0 + bn;
    const float4 bv0 = *(const float4*)bp;
    const float4 bv1 = *(const float4*)(bp + 4);
    As[ac+0][ar] = av0.x; As[ac+1][ar] = av0.y; As[ac+2][ar] = av0.z; As[ac+3][ar] = av0.w;
    As[ac+4][ar] = av1.x; As[ac+5][ar] = av1.y; As[ac+6][ar] = av1.z; As[ac+7][ar] = av1.w;
    *(float4*)&Bs[bc][bn]   = bv0;
    *(float4*)&Bs[bc][bn+4] = bv1;
    __syncthreads();
    #pragma unroll
    for (int kk = 0; kk < 16; ++kk) {
      const float4 a0 = *(const float4*)&As[kk][ty*8];
      const float4 a1 = *(const float4*)&As[kk][ty*8+4];
      const float4 b0 = *(const float4*)&Bs[kk][tx*8];
      const float4 b1 = *(const float4*)&Bs[kk][tx*8+4];
      const float a[8]  = {a0.x,a0.y,a0.z,a0.w,a1.x,a1.y,a1.z,a1.w};
      const float bb[8] = {b0.x,b0.y,b0.z,b0.w,b1.x,b1.y,b1.z,b1.w};
      #pragma unroll
      for (int i = 0; i < 8; ++i)
        #pragma unroll
        for (int j = 0; j < 8; ++j)
          acc[i][j] += a[i] * bb[j];
    }
    __syncthreads();
  }

  if (!epi_att) {
    #pragma unroll
    for (int i = 0; i < 8; ++i) {
      const int r = m0 + ty*8 + i;
      float4 o0, o1;
      o0.x = acc[i][0] + bias[n0+tx*8+0];
      o0.y = acc[i][1] + bias[n0+tx*8+1];
      o0.z = acc[i][2] + bias[n0+tx*8+2];
      o0.w = acc[i][3] + bias[n0+tx*8+3];
      o1.x = acc[i][4] + bias[n0+tx*8+4];
      o1.y = acc[i][5] + bias[n0+tx*8+5];
      o1.z = acc[i][6] + bias[n0+tx*8+6];
      o1.w = acc[i][7] + bias[n0+tx*8+7];
      *(float4*)&out[(size_t)r * N + n0 + tx*8]     = o0;
      *(float4*)&out[(size_t)r * N + n0 + tx*8 + 4] = o1;
    }
  } else {
    float attv[8];
    #pragma unroll
    for (int j = 0; j < 8; ++j) attv[j] = attV[n0 + tx*8 + j];
    #pragma unroll
    for (int i = 0; i < 8; ++i) {
      const int r = m0 + ty*8 + i;
      const int b = r / S_LEN;
      const float* dtp = dterm + (size_t)b * 512 + n0 + tx*8;
      float p = 0.f;
      #pragma unroll
      for (int j = 0; j < 8; ++j) p += attv[j] * tanh_fast(acc[i][j] + dtp[j]);
      pr[ty*8+i][tx] = p;
    }
    __syncthreads();
    if (tid < 128) {
      float s = 0.f;
      #pragma unroll
      for (int x = 0; x < 16; ++x) s += pr[tid][x];
      e_part[(size_t)(m0 + tid) * 4 + blockIdx.x] = s;
    }
  }
}

// --------------------------- small kernels ---------------------------------
__global__ __launch_bounds__(128) void k_state(const float* __restrict__ enc,
    const float* __restrict__ red_W, const float* __restrict__ red_b,
    float* __restrict__ state)
{
  const int b = blockIdx.y;
  const int j = blockIdx.x*128 + threadIdx.x;
  float acc = red_b[j];
  const float* fw = enc + ((size_t)b*S_LEN + (S_LEN-1))*1024;
  const float* bw = enc + ((size_t)b*S_LEN + 0)*1024 + 512;
  #pragma unroll 4
  for (int k = 0; k < 512; ++k) acc += fw[k] * red_W[(size_t)k*512 + j];
  #pragma unroll 4
  for (int k = 0; k < 512; ++k) acc += bw[k] * red_W[(size_t)(512+k)*512 + j];
  state[(size_t)b*512 + j] = fmaxf(acc, 0.f);
}

__global__ void k_yemb(const int* __restrict__ y_id, const float* __restrict__ emb,
                       float* __restrict__ yemb)
{
  const int b = blockIdx.x, tid = threadIdx.x;
  const int r = y_id[b];
  yemb[(size_t)b*512 + tid]       = emb[(size_t)r*512 + tid];
  yemb[(size_t)b*512 + 256 + tid] = emb[(size_t)r*512 + 256 + tid];
}

__global__ __launch_bounds__(128) void k_dec(const float* __restrict__ yemb,
    const float* __restrict__ state, const float* __restrict__ dec_W,
    const float* __restrict__ dec_U, const float* __restrict__ dec_b,
    float* __restrict__ dst)
{
  const int b = blockIdx.y;
  const int j = blockIdx.x*128 + threadIdx.x;
  float xz0 = dec_b[j], xz1 = dec_b[512+j], xz2 = dec_b[1024+j];
  float rc0 = dec_b[G3+j], rc1 = dec_b[G3+512+j], rc2 = dec_b[G3+1024+j];
  const float* ye = yemb + (size_t)b*512;
  const float* st = state + (size_t)b*512;
  #pragma unroll 2
  for (int k = 0; k < 512; ++k) {
    const float* wp = dec_W + (size_t)k*G3 + j;
    const float* up = dec_U + (size_t)k*G3 + j;
    const float yv = ye[k], sv = st[k];
    xz0 += yv*wp[0]; xz1 += yv*wp[512]; xz2 += yv*wp[1024];
    rc0 += sv*up[0]; rc1 += sv*up[512]; rc2 += sv*up[1024];
  }
  const float z  = sigf(xz0 + rc0);
  const float r  = sigf(xz1 + rc1);
  const float hh = tanh_fast(xz2 + r*rc2);
  dst[(size_t)b*512 + j] = z*st[j] + (1.f-z)*hh;
}

__global__ __launch_bounds__(128) void k_dterm(const float* __restrict__ dec,
    const float* __restrict__ att_Ws, const float* __restrict__ att_bs,
    float* __restrict__ dterm)
{
  const int b = blockIdx.y;
  const int j = blockIdx.x*128 + threadIdx.x;
  float acc = att_bs[j];
  const float* d = dec + (size_t)b*512;
  #pragma unroll 4
  for (int k = 0; k < 512; ++k) acc += d[k] * att_Ws[(size_t)k*512 + j];
  dterm[(size_t)b*512 + j] = acc;
}

__global__ __launch_bounds__(512) void k_soft(const float* __restrict__ e_part,
    const int* __restrict__ x_mask, float* __restrict__ wat)
{
  const int b = blockIdx.x, tid = threadIdx.x;
  __shared__ float sm[512];
  float e = -1e30f, ev = 0.f;
  if (tid < S_LEN) {
    const float* ep = e_part + (size_t)(b*S_LEN + tid)*4;
    ev = ep[0]+ep[1]+ep[2]+ep[3] + (float)x_mask[b*S_LEN+tid] * -1e10f;
    e = ev;
  }
  sm[tid] = e; __syncthreads();
  for (int s = 256; s > 0; s >>= 1) { if (tid < s) sm[tid] = fmaxf(sm[tid], sm[tid+s]); __syncthreads(); }
  const float m = sm[0]; __syncthreads();
  const float x = (tid < S_LEN) ? __expf(ev - m) : 0.f;
  sm[tid] = x; __syncthreads();
  for (int s = 256; s > 0; s >>= 1) { if (tid < s) sm[tid] += sm[tid+s]; __syncthreads(); }
  const float inv = 1.f / sm[0];
  if (tid < S_LEN) wat[b*S_LEN+tid] = x * inv;
}

__global__ __launch_bounds__(128) void k_ctx(const float* __restrict__ wat,
    const float* __restrict__ enc, float* __restrict__ ctx)
{
  const int b = blockIdx.y;
  const int j = blockIdx.x*128 + threadIdx.x;
  float acc = 0.f;
  const float* w = wat + b*S_LEN;
  const float* ep = enc + (size_t)b*S_LEN*1024 + j;
  #pragma unroll 4
  for (int s = 0; s < S_LEN; ++s) acc += w[s] * ep[(size_t)s*1024];
  ctx[(size_t)b*1024 + j] = acc;
}

__global__ __launch_bounds__(128) void k_yout(const float* __restrict__ dec,
    const float* __restrict__ ctx, const float* __restrict__ fc_W,
    const float* __restrict__ fc_b, float* __restrict__ y_out)
{
  const int b = blockIdx.y;
  const int j = blockIdx.x*128 + threadIdx.x;
  float acc = fc_b[j];
  const float* d = dec + (size_t)b*512;
  const float* c = ctx + (size_t)b*1024;
  #pragma unroll 4
  for (int k = 0; k < 512; ++k)  acc += d[k]*fc_W[(size_t)k*512 + j];
  #pragma unroll 4
  for (int k = 0; k < 1024; ++k) acc += c[k]*fc_W[(size_t)(512+k)*512 + j];
  y_out[(size_t)b*512 + j] = acc;
}

__global__ __launch_bounds__(256) void k_pgen(const float* __restrict__ ctx,
    const float* __restrict__ dec, const float* __restrict__ yemb,
    const float* __restrict__ pg_Wh, const float* __restrict__ pg_Ws,
    const float* __restrict__ pg_Wx, const float* __restrict__ pg_b,
    float* __restrict__ pg)
{
  const int b = blockIdx.x, tid = threadIdx.x;
  __shared__ float sm[256];
  float acc = 0.f;
  for (int k = tid; k < 1024; k += 256) acc += ctx[(size_t)b*1024+k]*pg_Wh[k];
  for (int k = tid; k < 512;  k += 256) acc += dec[(size_t)b*512+k]*pg_Ws[k] + yemb[(size_t)b*512+k]*pg_Wx[k];
  sm[tid] = acc; __syncthreads();
  for (int s = 128; s > 0; s >>= 1) { if (tid < s) sm[tid] += sm[tid+s]; __syncthreads(); }
  if (tid == 0) pg[b] = sigf(sm[0] + pg_b[0]);
}

__global__ __launch_bounds__(256) void k_vocab(const float* __restrict__ y_out,
    const float* __restrict__ vocab_W, float* __restrict__ logits)
{
  __shared__ float y_lds[256][32];   // [k][b], one k-half at a time (32 KB)
  const int tid = threadIdx.x;
  const int vq = tid & 63, bq = tid >> 6;
  const int v = blockIdx.x * 256 + vq * 4;
  float acc[8][4];
  #pragma unroll
  for (int i = 0; i < 8; ++i)
    #pragma unroll
    for (int j = 0; j < 4; ++j) acc[i][j] = 0.f;
  for (int half = 0; half < 2; ++half) {
    __syncthreads();
    for (int i = 0; i < 32; ++i) {
      const int idx = tid + 256*i;
      const int k = idx >> 5, b = idx & 31;
      y_lds[k][b] = y_out[(size_t)b*512 + half*256 + k];
    }
    __syncthreads();
    if (v < VOC) {
      #pragma unroll 4
      for (int k = 0; k < 256; ++k) {
        const float4 wv = *(const float4*)&vocab_W[(size_t)(half*256 + k) * VOC + v];
        const float4 ya = *(const float4*)&y_lds[k][bq*8];
        const float4 yb = *(const float4*)&y_lds[k][bq*8+4];
        const float yy[8] = {ya.x,ya.y,ya.z,ya.w,yb.x,yb.y,yb.z,yb.w};
        #pragma unroll
        for (int i = 0; i < 8; ++i) {
          acc[i][0] += yy[i]*wv.x; acc[i][1] += yy[i]*wv.y;
          acc[i][2] += yy[i]*wv.z; acc[i][3] += yy[i]*wv.w;
        }
      }
    }
  }
  if (v < VOC) {
    #pragma unroll
    for (int i = 0; i < 8; ++i)
      *(float4*)&logits[(size_t)(bq*8+i)*VOC + v] = make_float4(acc[i][0],acc[i][1],acc[i][2],acc[i][3]);
  }
}

__global__ __launch_bounds__(1024) void k_vred(const float* __restrict__ logits,
                                               float* __restrict__ red2)
{
  const int b = blockIdx.x, tid = threadIdx.x;
  __shared__ float sm[1024];
  float m = -1e30f;
  for (int i = tid; i < VOC; i += 1024) m = fmaxf(m, logits[(size_t)b*VOC + i]);
  sm[tid] = m; __syncthreads();
  for (int s = 512; s > 0; s >>= 1) { if (tid < s) sm[tid] = fmaxf(sm[tid], sm[tid+s]); __syncthreads(); }
  m = sm[0]; __syncthreads();
  float sum = 0.f;
  for (int i = tid; i < VOC; i += 1024) sum += __expf(logits[(size_t)b*VOC + i] - m);
  sm[tid] = sum; __syncthreads();
  for (int s = 512; s > 0; s >>= 1) { if (tid < s) sm[tid] += sm[tid+s]; __syncthreads(); }
  if (tid == 0) { red2[b*2] = m; red2[b*2+1] = sm[0]; }
}

__global__ __launch_bounds__(256) void k_final(const float* __restrict__ logits,
    const float* __restrict__ red2, const float* __restrict__ pg,
    float* __restrict__ out)
{
  const size_t idx = (size_t)blockIdx.x*256 + threadIdx.x;
  const int b = (int)(idx / OUTW);
  const int c = (int)(idx - (size_t)b*OUTW);
  float v = 0.f;
  if (c < VOC) {
    const float m = red2[b*2], s = red2[b*2+1];
    v = pg[b] * __expf(logits[(size_t)b*VOC + c] - m) / s;
  }
  out[idx] = v;
}

__global__ __launch_bounds__(256) void k_scatter(const float* __restrict__ wat,
    const int* __restrict__ x_mask, const float* __restrict__ pg,
    const int* __restrict__ x_id, float* __restrict__ out)
{
  const int i = blockIdx.x*256 + threadIdx.x;   // < 12800
  const int b = i / S_LEN;
  const float aw = wat[i] * (1.f - (float)x_mask[i]) * (1.f - pg[b]);
  atomicAdd(out + (size_t)b*OUTW + x_id[i], aw);
}

// ---------------------------------------------------------------------------
extern "C" void kernel_launch(void* const* d_in, const int* in_sizes, int n_in,
                              void* d_out, int out_size, void* d_ws, size_t ws_size,
                              hipStream_t stream)
{
  (void)in_sizes; (void)n_in; (void)out_size; (void)ws_size;
  const int*   x_id     = (const int*)d_in[0];
  const int*   y_id     = (const int*)d_in[1];
  const int*   x_mask   = (const int*)d_in[2];
  const float* emb      = (const float*)d_in[3];
  const float* enc_fw_W = (const float*)d_in[4];
  const float* enc_fw_U = (const float*)d_in[5];
  const float* enc_fw_b = (const float*)d_in[6];
  const float* enc_bw_W = (const float*)d_in[7];
  const float* enc_bw_U = (const float*)d_in[8];
  const float* enc_bw_b = (const float*)d_in[9];
  const float* red_W    = (const float*)d_in[10];
  const float* red_b    = (const float*)d_in[11];
  const float* dec_W    = (const float*)d_in[12];
  const float* dec_U    = (const float*)d_in[13];
  const float* dec_b    = (const float*)d_in[14];
  const float* att_Wh   = (const float*)d_in[15];
  const float* att_Ws   = (const float*)d_in[16];
  const float* att_bs   = (const float*)d_in[17];
  const float* att_Wc   = (const float*)d_in[18]; (void)att_Wc; // cover == 0
  const float* att_V    = (const float*)d_in[19];
  const float* fc_W     = (const float*)d_in[20];
  const float* fc_b     = (const float*)d_in[21];
  const float* vocab_W  = (const float*)d_in[22];
  const float* pg_Wh    = (const float*)d_in[23];
  const float* pg_Ws    = (const float*)d_in[24];
  const float* pg_Wx    = (const float*)d_in[25];
  const float* pg_b     = (const float*)d_in[26];
  float* out = (float*)d_out;

  float* ws = (float*)d_ws;
  const size_t SZXZ  = (size_t)BATCH*S_LEN*N2;     // merged fw|bw
  const size_t SZENC = (size_t)BATCH*S_LEN*1024;
  const size_t NPKT  = (size_t)2*2*BATCH*HID;      // [dir][parity][b][j]
  float*    xzm    = ws;
  float*    enc    = xzm + SZXZ;
  ull*      hpkt   = (ull*)(enc + SZENC);
  float*    fstate = (float*)(hpkt + NPKT);
  float*    yemb   = fstate + BATCH*HID;
  float*    decs   = yemb + BATCH*HID;
  float*    dterm  = decs + BATCH*HID;
  float*    epart  = dterm + BATCH*HID;
  float*    wat    = epart + (size_t)BATCH*S_LEN*4;
  float*    ctx    = wat + BATCH*S_LEN;
  float*    yout   = ctx + BATCH*1024;
  float*    pg     = yout + BATCH*HID;
  float*    logits = pg + BATCH;
  float*    red2   = logits + (size_t)BATCH*VOC;
  // Wm/bm alias the logits region (dead until k_vocab, which runs after the GEMM)
  float*    Wm     = logits;                        // 512*3072 + 3072 <= BATCH*VOC
  float*    bm     = logits + (size_t)512*N2;

  // zero the packet buffer: {0.0f, tag 0} == valid h(0) for every slot
  hipMemsetAsync(hpkt, 0, NPKT * sizeof(ull), stream);

  // merged input projection xz = gather(emb, x_id) @ [Wfw|Wbw] + [bfw0|bbw0]
  k_mergeW<<<(512*G3)/256, 256, 0, stream>>>(enc_fw_W, enc_bw_W, enc_fw_b, enc_bw_b, Wm, bm);
  gemm_big<<<dim3(N2/128, 100), 256, 0, stream>>>(1,0, x_id, emb, 512, Wm, N2, 512,
                                                  bm, xzm, nullptr, nullptr, nullptr);
  // persistent bidirectional GRU scan (sentinel-poll LL-packet sync)
  gru_scan<<<256,512,0,stream>>>(xzm, enc_fw_U, enc_bw_U, enc_fw_b, enc_bw_b,
                                 enc, hpkt);
  // reduce state + decoder step + attention query term
  k_state<<<dim3(4,32),128,0,stream>>>(enc, red_W, red_b, fstate);
  k_yemb<<<32,256,0,stream>>>(y_id, emb, yemb);
  k_dec<<<dim3(4,32),128,0,stream>>>(yemb, fstate, dec_W, dec_U, dec_b, decs);
  k_dterm<<<dim3(4,32),128,0,stream>>>(decs, att_Ws, att_bs, dterm);
  // attention scores (fused tanh * att_V reduction)
  gemm_big<<<dim3(4,100),256,0,stream>>>(0,1, nullptr, enc, 1024, att_Wh, 512, 1024,
                                         nullptr, nullptr, dterm, att_V, epart);
  k_soft<<<32,512,0,stream>>>(epart, x_mask, wat);
  k_ctx<<<dim3(8,32),128,0,stream>>>(wat, enc, ctx);
  k_yout<<<dim3(4,32),128,0,stream>>>(decs, ctx, fc_W, fc_b, yout);
  k_pgen<<<32,256,0,stream>>>(ctx, decs, yemb, pg_Wh, pg_Ws, pg_Wx, pg_b, pg);
  // vocab distribution + final assembly
  k_vocab<<<196,256,0,stream>>>(yout, vocab_W, logits);
  k_vred<<<32,1024,0,stream>>>(logits, red2);
  k_final<<<6300,256,0,stream>>>(logits, red2, pg, out);
  k_scatter<<<50,256,0,stream>>>(wat, x_mask, pg, x_id, out);
}

// Round 9
// 2605.477 us; speedup vs baseline: 2.9190x; 1.3699x over previous
//
#include <hip/hip_runtime.h>
#include <math.h>

#define S_LEN 400
#define BATCH 32
#define HID   512
#define G3    1536
#define N2    3072
#define VOC   50000
#define OUTW  (VOC + S_LEN)

typedef unsigned long long ull;
typedef unsigned int uint;
typedef unsigned short ushort;
typedef float v2f __attribute__((ext_vector_type(2)));
typedef short bf16x8 __attribute__((ext_vector_type(8)));
typedef float f32x4 __attribute__((ext_vector_type(4)));
typedef ushort u16x8 __attribute__((ext_vector_type(8)));

__device__ __forceinline__ float sigf(float x) { return 1.f / (1.f + __expf(-x)); }
__device__ __forceinline__ float tanh_fast(float x) {
  const float xc = fminf(fmaxf(x, -15.f), 15.f);
  const float e = __expf(-2.f * xc);
  return (1.f - e) / (1.f + e);
}
__device__ __forceinline__ ushort f2bf(float f) {       // RNE fp32 -> bf16
  uint u = __float_as_uint(f);
  u += 0x7FFFu + ((u >> 16) & 1u);
  return (ushort)(u >> 16);
}
__device__ __forceinline__ float bf2f(ushort h) {
  return __uint_as_float((uint)h << 16);
}

// ---------------------------------------------------------------------------
// Persistent bidirectional GRU scan — round-2 protocol, coalesced polling.
// 256 blocks x 512 thr. group = bid&7 (dir=group>>2, bg=group&3), ht=bid>>3
// (16 j's per block, full K). h moves as tagged 8B {fp32, step} packets via
// relaxed agent atomics (LLC). Consumer: wave w = batch w; lane covers
// j = lane + 64*i (i=0..7) -> packet loads coalesce to 512B/instr and
// h_lds writes are bank-conflict-free (bank = lane mod 32). Tags are the
// sole source of truth; a slot advances t -> t+2 only after every block
// consumed t (tag monotonicity), so waiting on tag==t can never be skipped.
// ---------------------------------------------------------------------------
__global__ __launch_bounds__(512) void gru_scan(
    const ushort* __restrict__ xzm,           // [32*400][3072] bf16 fw|bw
    const float* __restrict__ Ufw, const float* __restrict__ Ubw,
    const float* __restrict__ bfw, const float* __restrict__ bbw,
    float* __restrict__ enc_seq, ull* __restrict__ hpkt)
{
  const int bid = blockIdx.x;
  const int group = bid & 7;
  const int dir = group >> 2;
  const int bg  = group & 3;
  const int ht  = bid >> 3;          // j-tile: 16 j's
  const int tid = threadIdx.x;
  const int lane = tid & 63;
  const int jl = tid & 15;
  const int kc = tid >> 4;           // 0..31 chunks of 16 k
  const int k0 = kc * 16;
  const int jg = ht * 16 + jl;
  const int w  = tid >> 6;           // wave 0..7

  const float* __restrict__ U  = dir ? Ubw : Ufw;
  const float* __restrict__ br = (dir ? bbw : bfw) + G3;   // bias row 1

  // U tile in registers as k-pairs
  v2f u0[8], u1[8], u2[8];
  #pragma unroll
  for (int i = 0; i < 8; ++i) {
    const float* up = U + (size_t)(k0 + 2*i) * G3 + jg;
    u0[i] = v2f{up[0],    up[G3]};
    u1[i] = v2f{up[512],  up[G3+512]};
    u2[i] = v2f{up[1024], up[G3+1024]};
  }

  __shared__ float h_lds[8][HID];        // 16 KB
  __shared__ float red[8][3][8][16];     // 12 KB (b, gate, wave, jl)

  // consumer mapping: wave w = batch-in-group
  const int cb = w;
  // producer mapping (threads 0..127)
  const int gbi = tid >> 4;
  const int gj  = tid & 15;
  const int gjq = ht * 16 + gj;
  const int gb  = bg * 8 + gbi;
  const float brz = br[gjq], brr = br[512 + gjq], brh = br[1024 + gjq];

  ull* __restrict__ pk = hpkt + (size_t)dir * (2 * BATCH * HID);   // [parity][b][j]

  for (int t = 0; t < S_LEN; ++t) {
    const int ts = dir ? (S_LEN - 1 - t) : t;

    // xz prefetch (bf16, independent of h; overlaps the poll)
    float xzv0 = 0.f, xzv1 = 0.f, xzv2 = 0.f;
    if (tid < 128) {
      const ushort* xp = xzm + ((size_t)gb * S_LEN + ts) * N2 + dir * G3 + gjq;
      xzv0 = bf2f(xp[0]); xzv1 = bf2f(xp[512]); xzv2 = bf2f(xp[1024]);
    }

    // ---- consume h(t): coalesced tagged poll ----
    {
      ull* bp = pk + ((size_t)(t & 1) * BATCH + (bg * 8 + cb)) * HID + lane;
      const uint tu = (uint)t;
      for (;;) {
        ull v0 = __hip_atomic_load(bp,       __ATOMIC_RELAXED, __HIP_MEMORY_SCOPE_AGENT);
        ull v1 = __hip_atomic_load(bp + 64,  __ATOMIC_RELAXED, __HIP_MEMORY_SCOPE_AGENT);
        ull v2 = __hip_atomic_load(bp + 128, __ATOMIC_RELAXED, __HIP_MEMORY_SCOPE_AGENT);
        ull v3 = __hip_atomic_load(bp + 192, __ATOMIC_RELAXED, __HIP_MEMORY_SCOPE_AGENT);
        ull v4 = __hip_atomic_load(bp + 256, __ATOMIC_RELAXED, __HIP_MEMORY_SCOPE_AGENT);
        ull v5 = __hip_atomic_load(bp + 320, __ATOMIC_RELAXED, __HIP_MEMORY_SCOPE_AGENT);
        ull v6 = __hip_atomic_load(bp + 384, __ATOMIC_RELAXED, __HIP_MEMORY_SCOPE_AGENT);
        ull v7 = __hip_atomic_load(bp + 448, __ATOMIC_RELAXED, __HIP_MEMORY_SCOPE_AGENT);
        const bool ok = ((uint)(v0 >> 32) == tu) & ((uint)(v1 >> 32) == tu)
                      & ((uint)(v2 >> 32) == tu) & ((uint)(v3 >> 32) == tu)
                      & ((uint)(v4 >> 32) == tu) & ((uint)(v5 >> 32) == tu)
                      & ((uint)(v6 >> 32) == tu) & ((uint)(v7 >> 32) == tu);
        if (__all(ok)) {
          h_lds[cb][lane]       = __uint_as_float((uint)v0);
          h_lds[cb][lane + 64]  = __uint_as_float((uint)v1);
          h_lds[cb][lane + 128] = __uint_as_float((uint)v2);
          h_lds[cb][lane + 192] = __uint_as_float((uint)v3);
          h_lds[cb][lane + 256] = __uint_as_float((uint)v4);
          h_lds[cb][lane + 320] = __uint_as_float((uint)v5);
          h_lds[cb][lane + 384] = __uint_as_float((uint)v6);
          h_lds[cb][lane + 448] = __uint_as_float((uint)v7);
          break;
        }
        __builtin_amdgcn_s_sleep(1);
      }
    }
    __syncthreads();   // S1: h_lds ready

    // h_old for the gate phase, grabbed before the next fill can overwrite
    const float hold = (tid < 128) ? h_lds[gbi][gjq] : 0.f;

    // ---- recurrent matvec: packed-fp32 partials over 16-k chunk ----
    #pragma unroll 1
    for (int b = 0; b < 8; ++b) {
      v2f a0 = v2f{0.f,0.f}, a1 = v2f{0.f,0.f}, a2 = v2f{0.f,0.f};
      const float4* hp = (const float4*)&h_lds[b][k0];
      #pragma unroll
      for (int q = 0; q < 4; ++q) {
        const float4 hv = hp[q];
        const v2f hxy = v2f{hv.x, hv.y};
        const v2f hzw = v2f{hv.z, hv.w};
        a0 += hxy * u0[2*q]; a0 += hzw * u0[2*q+1];
        a1 += hxy * u1[2*q]; a1 += hzw * u1[2*q+1];
        a2 += hxy * u2[2*q]; a2 += hzw * u2[2*q+1];
      }
      float s0 = a0.x + a0.y, s1 = a1.x + a1.y, s2 = a2.x + a2.y;
      s0 += __shfl_xor(s0, 16); s0 += __shfl_xor(s0, 32);
      s1 += __shfl_xor(s1, 16); s1 += __shfl_xor(s1, 32);
      s2 += __shfl_xor(s2, 16); s2 += __shfl_xor(s2, 32);
      if ((tid & 48) == 0) {
        red[b][0][w][jl] = s0;
        red[b][1][w][jl] = s1;
        red[b][2][w][jl] = s2;
      }
    }
    __syncthreads();   // S2: red ready

    // ---- gates + publish h(t+1) ----
    if (tid < 128) {
      float rz = brz, rr = brr, rh = brh;
      #pragma unroll
      for (int x = 0; x < 8; ++x) {
        rz += red[gbi][0][x][gj];
        rr += red[gbi][1][x][gj];
        rh += red[gbi][2][x][gj];
      }
      const float z  = sigf(xzv0 + rz);
      const float r  = sigf(xzv1 + rr);
      const float hh = tanh_fast(xzv2 + r * rh);
      const float hnew = z * hold + (1.f - z) * hh;
      const ull pack = ((ull)(uint)(t + 1) << 32) | (ull)__float_as_uint(hnew);
      __hip_atomic_store(pk + ((size_t)((t + 1) & 1) * BATCH + gb) * HID + gjq,
                         pack, __ATOMIC_RELAXED, __HIP_MEMORY_SCOPE_AGENT);
      enc_seq[((size_t)gb * S_LEN + ts) * 1024 + dir * 512 + gjq] = hnew;
    }
    __syncthreads();   // S3: publishes issued; h_lds/red safe for next fill
  }
}

// ---------------------------------------------------------------------------
// Gather + convert: A_bf[r][k] = bf16(emb[x_id[r]][k]).  3200 blocks x 256.
// ---------------------------------------------------------------------------
__global__ __launch_bounds__(256) void k_cvtA(
    const int* __restrict__ x_id, const float* __restrict__ emb,
    ushort* __restrict__ Abf)
{
  const int tid = threadIdx.x;
  const int row = blockIdx.x * 4 + (tid >> 6);
  const int k8 = (tid & 63) * 8;
  const int rid = x_id[row];
  const float4 e0 = *(const float4*)&emb[(size_t)rid * 512 + k8];
  const float4 e1 = *(const float4*)&emb[(size_t)rid * 512 + k8 + 4];
  u16x8 o;
  o[0] = f2bf(e0.x); o[1] = f2bf(e0.y); o[2] = f2bf(e0.z); o[3] = f2bf(e0.w);
  o[4] = f2bf(e1.x); o[5] = f2bf(e1.y); o[6] = f2bf(e1.z); o[7] = f2bf(e1.w);
  *(u16x8*)&Abf[(size_t)row * 512 + k8] = o;
}

// ---------------------------------------------------------------------------
// Convert + transpose weights: Wt[n][k] = bf16(W[k][n]) with n = fw|bw merged;
// bm[n] = bias row 0 merged.  768 blocks x 256.
// ---------------------------------------------------------------------------
__global__ __launch_bounds__(256) void k_cvtW(
    const float* __restrict__ fwW, const float* __restrict__ bwW,
    const float* __restrict__ fwb, const float* __restrict__ bwb,
    ushort* __restrict__ Wt, float* __restrict__ bm)
{
  const int tid = threadIdx.x;
  const int n = blockIdx.x * 4 + (tid >> 6);
  const int k8 = (tid & 63) * 8;
  const float* src = (n < G3) ? (fwW + n) : (bwW + (n - G3));
  u16x8 o;
  #pragma unroll
  for (int i = 0; i < 8; ++i) o[i] = f2bf(src[(size_t)(k8 + i) * G3]);
  *(u16x8*)&Wt[(size_t)n * 512 + k8] = o;
  if (k8 == 0) bm[n] = (n < G3) ? fwb[n] : bwb[n - G3];
}

// ---------------------------------------------------------------------------
// bf16 MFMA GEMM: C[12800][3072] = A[12800][512] @ Wt^T + bm, C in bf16.
// 128x128 tile, 256 thr (4 waves), 16x16x32 bf16 MFMA, fp32 accum.
// Wave w owns rows w*32..w*32+31 (2 row-frags x 8 col-frags).
// ---------------------------------------------------------------------------
__global__ __launch_bounds__(256) void gemm_bf16(
    const ushort* __restrict__ A,    // [M][512] bf16
    const ushort* __restrict__ Bt,   // [N][512] bf16 (row n = W col n)
    const float* __restrict__ bias,  // [N] fp32
    ushort* __restrict__ C)          // [M][3072] bf16
{
  const int m0 = blockIdx.y * 128, n0 = blockIdx.x * 128;
  const int tid = threadIdx.x;
  const int w = tid >> 6, lane = tid & 63;
  const int l15 = lane & 15, lk = lane >> 4;
  __shared__ short As[128][40];      // +8 pad: row stride 80B (16B-aligned)
  __shared__ short Bs[128][40];
  f32x4 acc[2][8];
  #pragma unroll
  for (int i = 0; i < 2; ++i)
    #pragma unroll
    for (int j = 0; j < 8; ++j) acc[i][j] = f32x4{0.f, 0.f, 0.f, 0.f};

  const int sr = tid >> 1;           // stage row 0..127
  const int sc = (tid & 1) * 8;      // k-offset 0 or 8

  for (int k0 = 0; k0 < 512; k0 += 32) {
    const uint4 a0 = *(const uint4*)&A[(size_t)(m0 + sr) * 512 + k0 + sc];
    const uint4 a1 = *(const uint4*)&A[(size_t)(m0 + sr) * 512 + k0 + 16 + sc];
    const uint4 b0 = *(const uint4*)&Bt[(size_t)(n0 + sr) * 512 + k0 + sc];
    const uint4 b1 = *(const uint4*)&Bt[(size_t)(n0 + sr) * 512 + k0 + 16 + sc];
    *(uint4*)&As[sr][sc]      = a0;
    *(uint4*)&As[sr][16 + sc] = a1;
    *(uint4*)&Bs[sr][sc]      = b0;
    *(uint4*)&Bs[sr][16 + sc] = b1;
    __syncthreads();

    bf16x8 af[2], bfr[8];
    #pragma unroll
    for (int rf = 0; rf < 2; ++rf)
      af[rf] = *(const bf16x8*)&As[w * 32 + rf * 16 + l15][lk * 8];
    #pragma unroll
    for (int cf = 0; cf < 8; ++cf)
      bfr[cf] = *(const bf16x8*)&Bs[cf * 16 + l15][lk * 8];
    #pragma unroll
    for (int rf = 0; rf < 2; ++rf)
      #pragma unroll
      for (int cf = 0; cf < 8; ++cf)
        acc[rf][cf] = __builtin_amdgcn_mfma_f32_16x16x32_bf16(
            af[rf], bfr[cf], acc[rf][cf], 0, 0, 0);
    __syncthreads();
  }

  // epilogue: + bias, fp32 -> bf16, direct stores
  #pragma unroll
  for (int rf = 0; rf < 2; ++rf) {
    #pragma unroll
    for (int cf = 0; cf < 8; ++cf) {
      const int col = n0 + cf * 16 + l15;
      const float bv = bias[col];
      const int rowb = m0 + w * 32 + rf * 16 + lk * 4;
      #pragma unroll
      for (int r = 0; r < 4; ++r)
        C[(size_t)(rowb + r) * N2 + col] = f2bf(acc[rf][cf][r] + bv);
    }
  }
}

// ---------------------------------------------------------------------------
// fp32 tiled GEMM (attention path), 128x128x16, 256 thr, 8x8 microtile.
// epi_att: fused tanh(acc+dterm)*att_V row-reduction -> e_part.
// ---------------------------------------------------------------------------
__global__ __launch_bounds__(256) void gemm_big(
    const int epi_att,
    const float* __restrict__ Abase, const int lda,
    const float* __restrict__ W, const int N, const int K,
    const float* __restrict__ bias,
    float* __restrict__ out,
    const float* __restrict__ dterm, const float* __restrict__ attV,
    float* __restrict__ e_part)
{
  const int m0 = blockIdx.y * 128, n0 = blockIdx.x * 128;
  const int tid = threadIdx.x;
  __shared__ float As[16][128];
  __shared__ float Bs[16][128];
  __shared__ float pr[128][16];
  float acc[8][8];
  #pragma unroll
  for (int i = 0; i < 8; ++i)
    #pragma unroll
    for (int j = 0; j < 8; ++j) acc[i][j] = 0.f;
  const int tx = tid & 15, ty = tid >> 4;
  const int ar = tid >> 1, ac = (tid & 1) * 8;
  const int bc = tid >> 4, bn = (tid & 15) * 8;

  for (int k0 = 0; k0 < K; k0 += 16) {
    const float* ap = Abase + (size_t)(m0 + ar) * lda + k0 + ac;
    const float4 av0 = *(const float4*)ap;
    const float4 av1 = *(const float4*)(ap + 4);
    const float* bp = W + (size_t)(k0 + bc) * N + n0 + bn;
    const float4 bv0 = *(const float4*)bp;
    const float4 bv1 = *(const float4*)(bp + 4);
    As[ac+0][ar] = av0.x; As[ac+1][ar] = av0.y; As[ac+2][ar] = av0.z; As[ac+3][ar] = av0.w;
    As[ac+4][ar] = av1.x; As[ac+5][ar] = av1.y; As[ac+6][ar] = av1.z; As[ac+7][ar] = av1.w;
    *(float4*)&Bs[bc][bn]   = bv0;
    *(float4*)&Bs[bc][bn+4] = bv1;
    __syncthreads();
    #pragma unroll
    for (int kk = 0; kk < 16; ++kk) {
      const float4 a0 = *(const float4*)&As[kk][ty*8];
      const float4 a1 = *(const float4*)&As[kk][ty*8+4];
      const float4 b0 = *(const float4*)&Bs[kk][tx*8];
      const float4 b1 = *(const float4*)&Bs[kk][tx*8+4];
      const float a[8]  = {a0.x,a0.y,a0.z,a0.w,a1.x,a1.y,a1.z,a1.w};
      const float bb[8] = {b0.x,b0.y,b0.z,b0.w,b1.x,b1.y,b1.z,b1.w};
      #pragma unroll
      for (int i = 0; i < 8; ++i)
        #pragma unroll
        for (int j = 0; j < 8; ++j)
          acc[i][j] += a[i] * bb[j];
    }
    __syncthreads();
  }

  if (!epi_att) {
    #pragma unroll
    for (int i = 0; i < 8; ++i) {
      const int r = m0 + ty*8 + i;
      float4 o0, o1;
      o0.x = acc[i][0] + bias[n0+tx*8+0];
      o0.y = acc[i][1] + bias[n0+tx*8+1];
      o0.z = acc[i][2] + bias[n0+tx*8+2];
      o0.w = acc[i][3] + bias[n0+tx*8+3];
      o1.x = acc[i][4] + bias[n0+tx*8+4];
      o1.y = acc[i][5] + bias[n0+tx*8+5];
      o1.z = acc[i][6] + bias[n0+tx*8+6];
      o1.w = acc[i][7] + bias[n0+tx*8+7];
      *(float4*)&out[(size_t)r * N + n0 + tx*8]     = o0;
      *(float4*)&out[(size_t)r * N + n0 + tx*8 + 4] = o1;
    }
  } else {
    float attv[8];
    #pragma unroll
    for (int j = 0; j < 8; ++j) attv[j] = attV[n0 + tx*8 + j];
    #pragma unroll
    for (int i = 0; i < 8; ++i) {
      const int r = m0 + ty*8 + i;
      const int b = r / S_LEN;
      const float* dtp = dterm + (size_t)b * 512 + n0 + tx*8;
      float p = 0.f;
      #pragma unroll
      for (int j = 0; j < 8; ++j) p += attv[j] * tanh_fast(acc[i][j] + dtp[j]);
      pr[ty*8+i][tx] = p;
    }
    __syncthreads();
    if (tid < 128) {
      float s = 0.f;
      #pragma unroll
      for (int x = 0; x < 16; ++x) s += pr[tid][x];
      e_part[(size_t)(m0 + tid) * 4 + blockIdx.x] = s;
    }
  }
}

// --------------------------- small kernels ---------------------------------
__global__ __launch_bounds__(128) void k_state(const float* __restrict__ enc,
    const float* __restrict__ red_W, const float* __restrict__ red_b,
    float* __restrict__ state)
{
  const int b = blockIdx.y;
  const int j = blockIdx.x*128 + threadIdx.x;
  float acc = red_b[j];
  const float* fw = enc + ((size_t)b*S_LEN + (S_LEN-1))*1024;
  const float* bw = enc + ((size_t)b*S_LEN + 0)*1024 + 512;
  #pragma unroll 4
  for (int k = 0; k < 512; ++k) acc += fw[k] * red_W[(size_t)k*512 + j];
  #pragma unroll 4
  for (int k = 0; k < 512; ++k) acc += bw[k] * red_W[(size_t)(512+k)*512 + j];
  state[(size_t)b*512 + j] = fmaxf(acc, 0.f);
}

__global__ void k_yemb(const int* __restrict__ y_id, const float* __restrict__ emb,
                       float* __restrict__ yemb)
{
  const int b = blockIdx.x, tid = threadIdx.x;
  const int r = y_id[b];
  yemb[(size_t)b*512 + tid]       = emb[(size_t)r*512 + tid];
  yemb[(size_t)b*512 + 256 + tid] = emb[(size_t)r*512 + 256 + tid];
}

__global__ __launch_bounds__(128) void k_dec(const float* __restrict__ yemb,
    const float* __restrict__ state, const float* __restrict__ dec_W,
    const float* __restrict__ dec_U, const float* __restrict__ dec_b,
    float* __restrict__ dst)
{
  const int b = blockIdx.y;
  const int j = blockIdx.x*128 + threadIdx.x;
  float xz0 = dec_b[j], xz1 = dec_b[512+j], xz2 = dec_b[1024+j];
  float rc0 = dec_b[G3+j], rc1 = dec_b[G3+512+j], rc2 = dec_b[G3+1024+j];
  const float* ye = yemb + (size_t)b*512;
  const float* st = state + (size_t)b*512;
  #pragma unroll 2
  for (int k = 0; k < 512; ++k) {
    const float* wp = dec_W + (size_t)k*G3 + j;
    const float* up = dec_U + (size_t)k*G3 + j;
    const float yv = ye[k], sv = st[k];
    xz0 += yv*wp[0]; xz1 += yv*wp[512]; xz2 += yv*wp[1024];
    rc0 += sv*up[0]; rc1 += sv*up[512]; rc2 += sv*up[1024];
  }
  const float z  = sigf(xz0 + rc0);
  const float r  = sigf(xz1 + rc1);
  const float hh = tanh_fast(xz2 + r*rc2);
  dst[(size_t)b*512 + j] = z*st[j] + (1.f-z)*hh;
}

__global__ __launch_bounds__(128) void k_dterm(const float* __restrict__ dec,
    const float* __restrict__ att_Ws, const float* __restrict__ att_bs,
    float* __restrict__ dterm)
{
  const int b = blockIdx.y;
  const int j = blockIdx.x*128 + threadIdx.x;
  float acc = att_bs[j];
  const float* d = dec + (size_t)b*512;
  #pragma unroll 4
  for (int k = 0; k < 512; ++k) acc += d[k] * att_Ws[(size_t)k*512 + j];
  dterm[(size_t)b*512 + j] = acc;
}

__global__ __launch_bounds__(512) void k_soft(const float* __restrict__ e_part,
    const int* __restrict__ x_mask, float* __restrict__ wat)
{
  const int b = blockIdx.x, tid = threadIdx.x;
  __shared__ float sm[512];
  float e = -1e30f, ev = 0.f;
  if (tid < S_LEN) {
    const float* ep = e_part + (size_t)(b*S_LEN + tid)*4;
    ev = ep[0]+ep[1]+ep[2]+ep[3] + (float)x_mask[b*S_LEN+tid] * -1e10f;
    e = ev;
  }
  sm[tid] = e; __syncthreads();
  for (int s = 256; s > 0; s >>= 1) { if (tid < s) sm[tid] = fmaxf(sm[tid], sm[tid+s]); __syncthreads(); }
  const float m = sm[0]; __syncthreads();
  const float x = (tid < S_LEN) ? __expf(ev - m) : 0.f;
  sm[tid] = x; __syncthreads();
  for (int s = 256; s > 0; s >>= 1) { if (tid < s) sm[tid] += sm[tid+s]; __syncthreads(); }
  const float inv = 1.f / sm[0];
  if (tid < S_LEN) wat[b*S_LEN+tid] = x * inv;
}

__global__ __launch_bounds__(128) void k_ctx(const float* __restrict__ wat,
    const float* __restrict__ enc, float* __restrict__ ctx)
{
  const int b = blockIdx.y;
  const int j = blockIdx.x*128 + threadIdx.x;
  float acc = 0.f;
  const float* w = wat + b*S_LEN;
  const float* ep = enc + (size_t)b*S_LEN*1024 + j;
  #pragma unroll 4
  for (int s = 0; s < S_LEN; ++s) acc += w[s] * ep[(size_t)s*1024];
  ctx[(size_t)b*1024 + j] = acc;
}

__global__ __launch_bounds__(128) void k_yout(const float* __restrict__ dec,
    const float* __restrict__ ctx, const float* __restrict__ fc_W,
    const float* __restrict__ fc_b, float* __restrict__ y_out)
{
  const int b = blockIdx.y;
  const int j = blockIdx.x*128 + threadIdx.x;
  float acc = fc_b[j];
  const float* d = dec + (size_t)b*512;
  const float* c = ctx + (size_t)b*1024;
  #pragma unroll 4
  for (int k = 0; k < 512; ++k)  acc += d[k]*fc_W[(size_t)k*512 + j];
  #pragma unroll 4
  for (int k = 0; k < 1024; ++k) acc += c[k]*fc_W[(size_t)(512+k)*512 + j];
  y_out[(size_t)b*512 + j] = acc;
}

__global__ __launch_bounds__(256) void k_pgen(const float* __restrict__ ctx,
    const float* __restrict__ dec, const float* __restrict__ yemb,
    const float* __restrict__ pg_Wh, const float* __restrict__ pg_Ws,
    const float* __restrict__ pg_Wx, const float* __restrict__ pg_b,
    float* __restrict__ pg)
{
  const int b = blockIdx.x, tid = threadIdx.x;
  __shared__ float sm[256];
  float acc = 0.f;
  for (int k = tid; k < 1024; k += 256) acc += ctx[(size_t)b*1024+k]*pg_Wh[k];
  for (int k = tid; k < 512;  k += 256) acc += dec[(size_t)b*512+k]*pg_Ws[k] + yemb[(size_t)b*512+k]*pg_Wx[k];
  sm[tid] = acc; __syncthreads();
  for (int s = 128; s > 0; s >>= 1) { if (tid < s) sm[tid] += sm[tid+s]; __syncthreads(); }
  if (tid == 0) pg[b] = sigf(sm[0] + pg_b[0]);
}

__global__ __launch_bounds__(256) void k_vocab(const float* __restrict__ y_out,
    const float* __restrict__ vocab_W, float* __restrict__ logits)
{
  __shared__ float y_lds[256][32];   // [k][b], one k-half at a time (32 KB)
  const int tid = threadIdx.x;
  const int vq = tid & 63, bq = tid >> 6;
  const int v = blockIdx.x * 256 + vq * 4;
  float acc[8][4];
  #pragma unroll
  for (int i = 0; i < 8; ++i)
    #pragma unroll
    for (int j = 0; j < 4; ++j) acc[i][j] = 0.f;
  for (int half = 0; half < 2; ++half) {
    __syncthreads();
    for (int i = 0; i < 32; ++i) {
      const int idx = tid + 256*i;
      const int k = idx >> 5, b = idx & 31;
      y_lds[k][b] = y_out[(size_t)b*512 + half*256 + k];
    }
    __syncthreads();
    if (v < VOC) {
      #pragma unroll 4
      for (int k = 0; k < 256; ++k) {
        const float4 wv = *(const float4*)&vocab_W[(size_t)(half*256 + k) * VOC + v];
        const float4 ya = *(const float4*)&y_lds[k][bq*8];
        const float4 yb = *(const float4*)&y_lds[k][bq*8+4];
        const float yy[8] = {ya.x,ya.y,ya.z,ya.w,yb.x,yb.y,yb.z,yb.w};
        #pragma unroll
        for (int i = 0; i < 8; ++i) {
          acc[i][0] += yy[i]*wv.x; acc[i][1] += yy[i]*wv.y;
          acc[i][2] += yy[i]*wv.z; acc[i][3] += yy[i]*wv.w;
        }
      }
    }
  }
  if (v < VOC) {
    #pragma unroll
    for (int i = 0; i < 8; ++i)
      *(float4*)&logits[(size_t)(bq*8+i)*VOC + v] = make_float4(acc[i][0],acc[i][1],acc[i][2],acc[i][3]);
  }
}

__global__ __launch_bounds__(1024) void k_vred(const float* __restrict__ logits,
                                               float* __restrict__ red2)
{
  const int b = blockIdx.x, tid = threadIdx.x;
  __shared__ float sm[1024];
  float m = -1e30f;
  for (int i = tid; i < VOC; i += 1024) m = fmaxf(m, logits[(size_t)b*VOC + i]);
  sm[tid] = m; __syncthreads();
  for (int s = 512; s > 0; s >>= 1) { if (tid < s) sm[tid] = fmaxf(sm[tid], sm[tid+s]); __syncthreads(); }
  m = sm[0]; __syncthreads();
  float sum = 0.f;
  for (int i = tid; i < VOC; i += 1024) sum += __expf(logits[(size_t)b*VOC + i] - m);
  sm[tid] = sum; __syncthreads();
  for (int s = 512; s > 0; s >>= 1) { if (tid < s) sm[tid] += sm[tid+s]; __syncthreads(); }
  if (tid == 0) { red2[b*2] = m; red2[b*2+1] = sm[0]; }
}

__global__ __launch_bounds__(256) void k_final(const float* __restrict__ logits,
    const float* __restrict__ red2, const float* __restrict__ pg,
    float* __restrict__ out)
{
  const size_t idx = (size_t)blockIdx.x*256 + threadIdx.x;
  const int b = (int)(idx / OUTW);
  const int c = (int)(idx - (size_t)b*OUTW);
  float v = 0.f;
  if (c < VOC) {
    const float m = red2[b*2], s = red2[b*2+1];
    v = pg[b] * __expf(logits[(size_t)b*VOC + c] - m) / s;
  }
  out[idx] = v;
}

__global__ __launch_bounds__(256) void k_scatter(const float* __restrict__ wat,
    const int* __restrict__ x_mask, const float* __restrict__ pg,
    const int* __restrict__ x_id, float* __restrict__ out)
{
  const int i = blockIdx.x*256 + threadIdx.x;   // < 12800
  const int b = i / S_LEN;
  const float aw = wat[i] * (1.f - (float)x_mask[i]) * (1.f - pg[b]);
  atomicAdd(out + (size_t)b*OUTW + x_id[i], aw);
}

// ---------------------------------------------------------------------------
extern "C" void kernel_launch(void* const* d_in, const int* in_sizes, int n_in,
                              void* d_out, int out_size, void* d_ws, size_t ws_size,
                              hipStream_t stream)
{
  (void)in_sizes; (void)n_in; (void)out_size; (void)ws_size;
  const int*   x_id     = (const int*)d_in[0];
  const int*   y_id     = (const int*)d_in[1];
  const int*   x_mask   = (const int*)d_in[2];
  const float* emb      = (const float*)d_in[3];
  const float* enc_fw_W = (const float*)d_in[4];
  const float* enc_fw_U = (const float*)d_in[5];
  const float* enc_fw_b = (const float*)d_in[6];
  const float* enc_bw_W = (const float*)d_in[7];
  const float* enc_bw_U = (const float*)d_in[8];
  const float* enc_bw_b = (const float*)d_in[9];
  const float* red_W    = (const float*)d_in[10];
  const float* red_b    = (const float*)d_in[11];
  const float* dec_W    = (const float*)d_in[12];
  const float* dec_U    = (const float*)d_in[13];
  const float* dec_b    = (const float*)d_in[14];
  const float* att_Wh   = (const float*)d_in[15];
  const float* att_Ws   = (const float*)d_in[16];
  const float* att_bs   = (const float*)d_in[17];
  const float* att_Wc   = (const float*)d_in[18]; (void)att_Wc; // cover == 0
  const float* att_V    = (const float*)d_in[19];
  const float* fc_W     = (const float*)d_in[20];
  const float* fc_b     = (const float*)d_in[21];
  const float* vocab_W  = (const float*)d_in[22];
  const float* pg_Wh    = (const float*)d_in[23];
  const float* pg_Ws    = (const float*)d_in[24];
  const float* pg_Wx    = (const float*)d_in[25];
  const float* pg_b     = (const float*)d_in[26];
  float* out = (float*)d_out;

  const size_t NPKT = (size_t)2*2*BATCH*HID;            // [dir][parity][b][j]
  char* p = (char*)d_ws;
  ushort* xzm  = (ushort*)p; p += (size_t)BATCH*S_LEN*N2*2;     // 78.6 MB
  float*  enc  = (float*)p;  p += (size_t)BATCH*S_LEN*1024*4;   // 52.4 MB
  ull*   hpkt  = (ull*)p;    p += NPKT*8;                       // 1 MB
  ushort* Abf  = (ushort*)p; p += (size_t)BATCH*S_LEN*512*2;    // 13.1 MB
  ushort* Wt   = (ushort*)p; p += (size_t)N2*512*2;             // 3.1 MB
  float*  bm   = (float*)p;  p += (size_t)N2*4;
  float*  fstate = (float*)p; p += (size_t)BATCH*HID*4;
  float*  yemb   = (float*)p; p += (size_t)BATCH*HID*4;
  float*  decs   = (float*)p; p += (size_t)BATCH*HID*4;
  float*  dterm  = (float*)p; p += (size_t)BATCH*HID*4;
  float*  epart  = (float*)p; p += (size_t)BATCH*S_LEN*4*4;
  float*  wat    = (float*)p; p += (size_t)BATCH*S_LEN*4;
  float*  ctx    = (float*)p; p += (size_t)BATCH*1024*4;
  float*  yout   = (float*)p; p += (size_t)BATCH*HID*4;
  float*  pg     = (float*)p; p += (size_t)256*4;
  float*  logits = (float*)p; p += (size_t)BATCH*VOC*4;         // 6.4 MB
  float*  red2   = (float*)p; p += (size_t)64*4;

  // zero the packet buffer: {0.0f, tag 0} == valid h(0) for every slot
  hipMemsetAsync(hpkt, 0, NPKT * sizeof(ull), stream);

  // convert inputs to bf16 (gather + weight transpose/merge)
  k_cvtA<<<BATCH*S_LEN/4, 256, 0, stream>>>(x_id, emb, Abf);
  k_cvtW<<<N2/4, 256, 0, stream>>>(enc_fw_W, enc_bw_W, enc_fw_b, enc_bw_b, Wt, bm);
  // merged input projection (bf16 MFMA): xz = A @ [Wfw|Wbw] + [bfw0|bbw0]
  gemm_bf16<<<dim3(N2/128, BATCH*S_LEN/128), 256, 0, stream>>>(Abf, Wt, bm, xzm);
  // persistent bidirectional GRU scan (coalesced tagged-packet sync)
  gru_scan<<<256,512,0,stream>>>(xzm, enc_fw_U, enc_bw_U, enc_fw_b, enc_bw_b,
                                 enc, hpkt);
  // reduce state + decoder step + attention query term
  k_state<<<dim3(4,32),128,0,stream>>>(enc, red_W, red_b, fstate);
  k_yemb<<<32,256,0,stream>>>(y_id, emb, yemb);
  k_dec<<<dim3(4,32),128,0,stream>>>(yemb, fstate, dec_W, dec_U, dec_b, decs);
  k_dterm<<<dim3(4,32),128,0,stream>>>(decs, att_Ws, att_bs, dterm);
  // attention scores (fused tanh * att_V reduction), fp32
  gemm_big<<<dim3(4,100),256,0,stream>>>(1, enc, 1024, att_Wh, 512, 1024,
                                         nullptr, nullptr, dterm, att_V, epart);
  k_soft<<<32,512,0,stream>>>(epart, x_mask, wat);
  k_ctx<<<dim3(8,32),128,0,stream>>>(wat, enc, ctx);
  k_yout<<<dim3(4,32),128,0,stream>>>(decs, ctx, fc_W, fc_b, yout);
  k_pgen<<<32,256,0,stream>>>(ctx, decs, yemb, pg_Wh, pg_Ws, pg_Wx, pg_b, pg);
  // vocab distribution + final assembly
  k_vocab<<<196,256,0,stream>>>(yout, vocab_W, logits);
  k_vred<<<32,1024,0,stream>>>(logits, red2);
  k_final<<<6300,256,0,stream>>>(logits, red2, pg, out);
  k_scatter<<<50,256,0,stream>>>(wat, x_mask, pg, x_id, out);
}

// Round 10
// 2459.814 us; speedup vs baseline: 3.0919x; 1.0592x over previous
//
#include <hip/hip_runtime.h>
#include <math.h>

#define S_LEN 400
#define BATCH 32
#define HID   512
#define G3    1536
#define N2    3072
#define VOC   50000
#define OUTW  (VOC + S_LEN)

typedef unsigned long long ull;
typedef unsigned int uint;
typedef unsigned short ushort;
typedef float v2f __attribute__((ext_vector_type(2)));
typedef short bf16x8 __attribute__((ext_vector_type(8)));
typedef float f32x4 __attribute__((ext_vector_type(4)));
typedef ushort u16x8 __attribute__((ext_vector_type(8)));

__device__ __forceinline__ float sigf(float x) { return 1.f / (1.f + __expf(-x)); }
__device__ __forceinline__ float tanh_fast(float x) {
  const float xc = fminf(fmaxf(x, -15.f), 15.f);
  const float e = __expf(-2.f * xc);
  return (1.f - e) / (1.f + e);
}
__device__ __forceinline__ ushort f2bf(float f) {       // RNE fp32 -> bf16
  uint u = __float_as_uint(f);
  u += 0x7FFFu + ((u >> 16) & 1u);
  return (ushort)(u >> 16);
}
__device__ __forceinline__ float bf2f(ushort h) {
  return __uint_as_float((uint)h << 16);
}

// ---------------------------------------------------------------------------
// Persistent bidirectional GRU scan — tagged-packet sync, coalesced polling.
// (structure unchanged from round 9; additionally emits enc in bf16)
// ---------------------------------------------------------------------------
__global__ __launch_bounds__(512) void gru_scan(
    const ushort* __restrict__ xzm,           // [32*400][3072] bf16 fw|bw
    const float* __restrict__ Ufw, const float* __restrict__ Ubw,
    const float* __restrict__ bfw, const float* __restrict__ bbw,
    float* __restrict__ enc_seq, ushort* __restrict__ enc_bf,
    ull* __restrict__ hpkt)
{
  const int bid = blockIdx.x;
  const int group = bid & 7;
  const int dir = group >> 2;
  const int bg  = group & 3;
  const int ht  = bid >> 3;          // j-tile: 16 j's
  const int tid = threadIdx.x;
  const int lane = tid & 63;
  const int jl = tid & 15;
  const int kc = tid >> 4;           // 0..31 chunks of 16 k
  const int k0 = kc * 16;
  const int jg = ht * 16 + jl;
  const int w  = tid >> 6;           // wave 0..7

  const float* __restrict__ U  = dir ? Ubw : Ufw;
  const float* __restrict__ br = (dir ? bbw : bfw) + G3;   // bias row 1

  // U tile in registers as k-pairs
  v2f u0[8], u1[8], u2[8];
  #pragma unroll
  for (int i = 0; i < 8; ++i) {
    const float* up = U + (size_t)(k0 + 2*i) * G3 + jg;
    u0[i] = v2f{up[0],    up[G3]};
    u1[i] = v2f{up[512],  up[G3+512]};
    u2[i] = v2f{up[1024], up[G3+1024]};
  }

  __shared__ float h_lds[8][HID];        // 16 KB
  __shared__ float red[8][3][8][16];     // 12 KB (b, gate, wave, jl)

  const int cb = w;
  const int gbi = tid >> 4;
  const int gj  = tid & 15;
  const int gjq = ht * 16 + gj;
  const int gb  = bg * 8 + gbi;
  const float brz = br[gjq], brr = br[512 + gjq], brh = br[1024 + gjq];

  ull* __restrict__ pk = hpkt + (size_t)dir * (2 * BATCH * HID);   // [parity][b][j]

  for (int t = 0; t < S_LEN; ++t) {
    const int ts = dir ? (S_LEN - 1 - t) : t;

    // xz prefetch (bf16, independent of h; overlaps the poll)
    float xzv0 = 0.f, xzv1 = 0.f, xzv2 = 0.f;
    if (tid < 128) {
      const ushort* xp = xzm + ((size_t)gb * S_LEN + ts) * N2 + dir * G3 + gjq;
      xzv0 = bf2f(xp[0]); xzv1 = bf2f(xp[512]); xzv2 = bf2f(xp[1024]);
    }

    // ---- consume h(t): coalesced tagged poll ----
    {
      ull* bp = pk + ((size_t)(t & 1) * BATCH + (bg * 8 + cb)) * HID + lane;
      const uint tu = (uint)t;
      for (;;) {
        ull v0 = __hip_atomic_load(bp,       __ATOMIC_RELAXED, __HIP_MEMORY_SCOPE_AGENT);
        ull v1 = __hip_atomic_load(bp + 64,  __ATOMIC_RELAXED, __HIP_MEMORY_SCOPE_AGENT);
        ull v2 = __hip_atomic_load(bp + 128, __ATOMIC_RELAXED, __HIP_MEMORY_SCOPE_AGENT);
        ull v3 = __hip_atomic_load(bp + 192, __ATOMIC_RELAXED, __HIP_MEMORY_SCOPE_AGENT);
        ull v4 = __hip_atomic_load(bp + 256, __ATOMIC_RELAXED, __HIP_MEMORY_SCOPE_AGENT);
        ull v5 = __hip_atomic_load(bp + 320, __ATOMIC_RELAXED, __HIP_MEMORY_SCOPE_AGENT);
        ull v6 = __hip_atomic_load(bp + 384, __ATOMIC_RELAXED, __HIP_MEMORY_SCOPE_AGENT);
        ull v7 = __hip_atomic_load(bp + 448, __ATOMIC_RELAXED, __HIP_MEMORY_SCOPE_AGENT);
        const bool ok = ((uint)(v0 >> 32) == tu) & ((uint)(v1 >> 32) == tu)
                      & ((uint)(v2 >> 32) == tu) & ((uint)(v3 >> 32) == tu)
                      & ((uint)(v4 >> 32) == tu) & ((uint)(v5 >> 32) == tu)
                      & ((uint)(v6 >> 32) == tu) & ((uint)(v7 >> 32) == tu);
        if (__all(ok)) {
          h_lds[cb][lane]       = __uint_as_float((uint)v0);
          h_lds[cb][lane + 64]  = __uint_as_float((uint)v1);
          h_lds[cb][lane + 128] = __uint_as_float((uint)v2);
          h_lds[cb][lane + 192] = __uint_as_float((uint)v3);
          h_lds[cb][lane + 256] = __uint_as_float((uint)v4);
          h_lds[cb][lane + 320] = __uint_as_float((uint)v5);
          h_lds[cb][lane + 384] = __uint_as_float((uint)v6);
          h_lds[cb][lane + 448] = __uint_as_float((uint)v7);
          break;
        }
        __builtin_amdgcn_s_sleep(1);
      }
    }
    __syncthreads();   // S1: h_lds ready

    const float hold = (tid < 128) ? h_lds[gbi][gjq] : 0.f;

    // ---- recurrent matvec: packed-fp32 partials over 16-k chunk ----
    #pragma unroll 1
    for (int b = 0; b < 8; ++b) {
      v2f a0 = v2f{0.f,0.f}, a1 = v2f{0.f,0.f}, a2 = v2f{0.f,0.f};
      const float4* hp = (const float4*)&h_lds[b][k0];
      #pragma unroll
      for (int q = 0; q < 4; ++q) {
        const float4 hv = hp[q];
        const v2f hxy = v2f{hv.x, hv.y};
        const v2f hzw = v2f{hv.z, hv.w};
        a0 += hxy * u0[2*q]; a0 += hzw * u0[2*q+1];
        a1 += hxy * u1[2*q]; a1 += hzw * u1[2*q+1];
        a2 += hxy * u2[2*q]; a2 += hzw * u2[2*q+1];
      }
      float s0 = a0.x + a0.y, s1 = a1.x + a1.y, s2 = a2.x + a2.y;
      s0 += __shfl_xor(s0, 16); s0 += __shfl_xor(s0, 32);
      s1 += __shfl_xor(s1, 16); s1 += __shfl_xor(s1, 32);
      s2 += __shfl_xor(s2, 16); s2 += __shfl_xor(s2, 32);
      if ((tid & 48) == 0) {
        red[b][0][w][jl] = s0;
        red[b][1][w][jl] = s1;
        red[b][2][w][jl] = s2;
      }
    }
    __syncthreads();   // S2: red ready

    // ---- gates + publish h(t+1) ----
    if (tid < 128) {
      float rz = brz, rr = brr, rh = brh;
      #pragma unroll
      for (int x = 0; x < 8; ++x) {
        rz += red[gbi][0][x][gj];
        rr += red[gbi][1][x][gj];
        rh += red[gbi][2][x][gj];
      }
      const float z  = sigf(xzv0 + rz);
      const float r  = sigf(xzv1 + rr);
      const float hh = tanh_fast(xzv2 + r * rh);
      const float hnew = z * hold + (1.f - z) * hh;
      const ull pack = ((ull)(uint)(t + 1) << 32) | (ull)__float_as_uint(hnew);
      __hip_atomic_store(pk + ((size_t)((t + 1) & 1) * BATCH + gb) * HID + gjq,
                         pack, __ATOMIC_RELAXED, __HIP_MEMORY_SCOPE_AGENT);
      const size_t eidx = ((size_t)gb * S_LEN + ts) * 1024 + dir * 512 + gjq;
      enc_seq[eidx] = hnew;
      enc_bf[eidx]  = f2bf(hnew);
    }
    __syncthreads();   // S3: publishes issued; h_lds/red safe for next fill
  }
}

// ---------------------------------------------------------------------------
// Gather + convert: A_bf[r][k] = bf16(emb[x_id[r]][k]).  3200 blocks x 256.
// ---------------------------------------------------------------------------
__global__ __launch_bounds__(256) void k_cvtA(
    const int* __restrict__ x_id, const float* __restrict__ emb,
    ushort* __restrict__ Abf)
{
  const int tid = threadIdx.x;
  const int row = blockIdx.x * 4 + (tid >> 6);
  const int k8 = (tid & 63) * 8;
  const int rid = x_id[row];
  const float4 e0 = *(const float4*)&emb[(size_t)rid * 512 + k8];
  const float4 e1 = *(const float4*)&emb[(size_t)rid * 512 + k8 + 4];
  u16x8 o;
  o[0] = f2bf(e0.x); o[1] = f2bf(e0.y); o[2] = f2bf(e0.z); o[3] = f2bf(e0.w);
  o[4] = f2bf(e1.x); o[5] = f2bf(e1.y); o[6] = f2bf(e1.z); o[7] = f2bf(e1.w);
  *(u16x8*)&Abf[(size_t)row * 512 + k8] = o;
}

// ---------------------------------------------------------------------------
// Tiled transpose + bf16 convert: dst[n][k] = bf16(src[k][n]).
// src is split column-wise at `split` between srcA|srcB (both row stride
// `srcStride`). 64x64 tiles via LDS, coalesced both sides. Optional bias
// merge on the k0==0 tile row.
// grid: (Krows/64, Ncols/64), 256 threads.
// ---------------------------------------------------------------------------
__global__ __launch_bounds__(256) void k_transW(
    const float* __restrict__ srcA, const float* __restrict__ srcB,
    const int split, const int srcStride, const int Krows,
    ushort* __restrict__ dst,
    const float* __restrict__ biasA, const float* __restrict__ biasB,
    float* __restrict__ bm)
{
  __shared__ float t[64][65];
  const int k0 = blockIdx.x * 64, n0 = blockIdx.y * 64;
  const int tid = threadIdx.x;
  const int j = tid & 63, i0 = tid >> 6;
  {
    const int n = n0 + j;
    const float* s = (n < split) ? (srcA + n) : (srcB + (n - split));
    #pragma unroll
    for (int i = i0; i < 64; i += 4)
      t[i][j] = s[(size_t)(k0 + i) * srcStride];
  }
  __syncthreads();
  const int ii = tid & 63;
  #pragma unroll
  for (int jj = i0; jj < 64; jj += 4)
    dst[(size_t)(n0 + jj) * Krows + k0 + ii] = f2bf(t[ii][jj]);
  if (bm != nullptr && k0 == 0 && tid < 64) {
    const int n = n0 + tid;
    bm[n] = (n < split) ? biasA[n] : biasB[n - split];
  }
}

// ---------------------------------------------------------------------------
// bf16 MFMA GEMM: C[12800][3072] = A[12800][512] @ Wt^T + bm, C in bf16.
// 128x128 tile, 256 thr (4 waves), 16x16x32 bf16 MFMA, fp32 accum.
// ---------------------------------------------------------------------------
__global__ __launch_bounds__(256) void gemm_bf16(
    const ushort* __restrict__ A,    // [M][512] bf16
    const ushort* __restrict__ Bt,   // [N][512] bf16 (row n = W col n)
    const float* __restrict__ bias,  // [N] fp32
    ushort* __restrict__ C)          // [M][3072] bf16
{
  const int m0 = blockIdx.y * 128, n0 = blockIdx.x * 128;
  const int tid = threadIdx.x;
  const int w = tid >> 6, lane = tid & 63;
  const int l15 = lane & 15, lk = lane >> 4;
  __shared__ short As[128][40];      // +8 pad: row stride 80B (16B-aligned)
  __shared__ short Bs[128][40];
  f32x4 acc[2][8];
  #pragma unroll
  for (int i = 0; i < 2; ++i)
    #pragma unroll
    for (int j = 0; j < 8; ++j) acc[i][j] = f32x4{0.f, 0.f, 0.f, 0.f};

  const int sr = tid >> 1;           // stage row 0..127
  const int sc = (tid & 1) * 8;      // k-offset 0 or 8

  for (int k0 = 0; k0 < 512; k0 += 32) {
    const uint4 a0 = *(const uint4*)&A[(size_t)(m0 + sr) * 512 + k0 + sc];
    const uint4 a1 = *(const uint4*)&A[(size_t)(m0 + sr) * 512 + k0 + 16 + sc];
    const uint4 b0 = *(const uint4*)&Bt[(size_t)(n0 + sr) * 512 + k0 + sc];
    const uint4 b1 = *(const uint4*)&Bt[(size_t)(n0 + sr) * 512 + k0 + 16 + sc];
    *(uint4*)&As[sr][sc]      = a0;
    *(uint4*)&As[sr][16 + sc] = a1;
    *(uint4*)&Bs[sr][sc]      = b0;
    *(uint4*)&Bs[sr][16 + sc] = b1;
    __syncthreads();

    bf16x8 af[2], bfr[8];
    #pragma unroll
    for (int rf = 0; rf < 2; ++rf)
      af[rf] = *(const bf16x8*)&As[w * 32 + rf * 16 + l15][lk * 8];
    #pragma unroll
    for (int cf = 0; cf < 8; ++cf)
      bfr[cf] = *(const bf16x8*)&Bs[cf * 16 + l15][lk * 8];
    #pragma unroll
    for (int rf = 0; rf < 2; ++rf)
      #pragma unroll
      for (int cf = 0; cf < 8; ++cf)
        acc[rf][cf] = __builtin_amdgcn_mfma_f32_16x16x32_bf16(
            af[rf], bfr[cf], acc[rf][cf], 0, 0, 0);
    __syncthreads();
  }

  #pragma unroll
  for (int rf = 0; rf < 2; ++rf) {
    #pragma unroll
    for (int cf = 0; cf < 8; ++cf) {
      const int col = n0 + cf * 16 + l15;
      const float bv = bias[col];
      const int rowb = m0 + w * 32 + rf * 16 + lk * 4;
      #pragma unroll
      for (int r = 0; r < 4; ++r)
        C[(size_t)(rowb + r) * N2 + col] = f2bf(acc[rf][cf][r] + bv);
    }
  }
}

// ---------------------------------------------------------------------------
// bf16 MFMA attention-score GEMM with fused epilogue:
// e_part[row][bx] = sum_n attV[n] * tanh(enc_bf[row]@Wh[:,n] + dterm[b][n])
// A = enc_bf [12800][1024], Bt = Whbf [512][1024]. 128x128 tile over N=512
// (grid.x = 4), K = 1024. In-register shfl row-reduction.
// ---------------------------------------------------------------------------
__global__ __launch_bounds__(256) void gemm_att(
    const ushort* __restrict__ A,    // [12800][1024] bf16
    const ushort* __restrict__ Bt,   // [512][1024] bf16
    const float* __restrict__ dterm, // [32][512] fp32
    const float* __restrict__ attV,  // [512] fp32
    float* __restrict__ e_part)      // [12800][4]
{
  const int m0 = blockIdx.y * 128, n0 = blockIdx.x * 128;
  const int tid = threadIdx.x;
  const int w = tid >> 6, lane = tid & 63;
  const int l15 = lane & 15, lk = lane >> 4;
  __shared__ short As[128][40];
  __shared__ short Bs[128][40];
  f32x4 acc[2][8];
  #pragma unroll
  for (int i = 0; i < 2; ++i)
    #pragma unroll
    for (int j = 0; j < 8; ++j) acc[i][j] = f32x4{0.f, 0.f, 0.f, 0.f};

  const int sr = tid >> 1;
  const int sc = (tid & 1) * 8;

  for (int k0 = 0; k0 < 1024; k0 += 32) {
    const uint4 a0 = *(const uint4*)&A[(size_t)(m0 + sr) * 1024 + k0 + sc];
    const uint4 a1 = *(const uint4*)&A[(size_t)(m0 + sr) * 1024 + k0 + 16 + sc];
    const uint4 b0 = *(const uint4*)&Bt[(size_t)(n0 + sr) * 1024 + k0 + sc];
    const uint4 b1 = *(const uint4*)&Bt[(size_t)(n0 + sr) * 1024 + k0 + 16 + sc];
    *(uint4*)&As[sr][sc]      = a0;
    *(uint4*)&As[sr][16 + sc] = a1;
    *(uint4*)&Bs[sr][sc]      = b0;
    *(uint4*)&Bs[sr][16 + sc] = b1;
    __syncthreads();

    bf16x8 af[2], bfr[8];
    #pragma unroll
    for (int rf = 0; rf < 2; ++rf)
      af[rf] = *(const bf16x8*)&As[w * 32 + rf * 16 + l15][lk * 8];
    #pragma unroll
    for (int cf = 0; cf < 8; ++cf)
      bfr[cf] = *(const bf16x8*)&Bs[cf * 16 + l15][lk * 8];
    #pragma unroll
    for (int rf = 0; rf < 2; ++rf)
      #pragma unroll
      for (int cf = 0; cf < 8; ++cf)
        acc[rf][cf] = __builtin_amdgcn_mfma_f32_16x16x32_bf16(
            af[rf], bfr[cf], acc[rf][cf], 0, 0, 0);
    __syncthreads();
  }

  // fused epilogue: p = sum_cols attV * tanh(acc + dterm); reduce over l15
  #pragma unroll
  for (int rf = 0; rf < 2; ++rf) {
    #pragma unroll
    for (int r = 0; r < 4; ++r) {
      const int row = m0 + w * 32 + rf * 16 + lk * 4 + r;
      const int b = row / S_LEN;
      float p = 0.f;
      #pragma unroll
      for (int cf = 0; cf < 8; ++cf) {
        const int col = n0 + cf * 16 + l15;
        p += attV[col] * tanh_fast(acc[rf][cf][r] + dterm[(size_t)b * 512 + col]);
      }
      p += __shfl_xor(p, 1); p += __shfl_xor(p, 2);
      p += __shfl_xor(p, 4); p += __shfl_xor(p, 8);
      if (l15 == 0) e_part[(size_t)row * 4 + blockIdx.x] = p;
    }
  }
}

// --------------------------- small kernels ---------------------------------
__global__ __launch_bounds__(128) void k_state(const float* __restrict__ enc,
    const float* __restrict__ red_W, const float* __restrict__ red_b,
    float* __restrict__ state)
{
  const int b = blockIdx.y;
  const int j = blockIdx.x*128 + threadIdx.x;
  float acc = red_b[j];
  const float* fw = enc + ((size_t)b*S_LEN + (S_LEN-1))*1024;
  const float* bw = enc + ((size_t)b*S_LEN + 0)*1024 + 512;
  #pragma unroll 4
  for (int k = 0; k < 512; ++k) acc += fw[k] * red_W[(size_t)k*512 + j];
  #pragma unroll 4
  for (int k = 0; k < 512; ++k) acc += bw[k] * red_W[(size_t)(512+k)*512 + j];
  state[(size_t)b*512 + j] = fmaxf(acc, 0.f);
}

__global__ void k_yemb(const int* __restrict__ y_id, const float* __restrict__ emb,
                       float* __restrict__ yemb)
{
  const int b = blockIdx.x, tid = threadIdx.x;
  const int r = y_id[b];
  yemb[(size_t)b*512 + tid]       = emb[(size_t)r*512 + tid];
  yemb[(size_t)b*512 + 256 + tid] = emb[(size_t)r*512 + 256 + tid];
}

__global__ __launch_bounds__(128) void k_dec(const float* __restrict__ yemb,
    const float* __restrict__ state, const float* __restrict__ dec_W,
    const float* __restrict__ dec_U, const float* __restrict__ dec_b,
    float* __restrict__ dst)
{
  const int b = blockIdx.y;
  const int j = blockIdx.x*128 + threadIdx.x;
  float xz0 = dec_b[j], xz1 = dec_b[512+j], xz2 = dec_b[1024+j];
  float rc0 = dec_b[G3+j], rc1 = dec_b[G3+512+j], rc2 = dec_b[G3+1024+j];
  const float* ye = yemb + (size_t)b*512;
  const float* st = state + (size_t)b*512;
  #pragma unroll 2
  for (int k = 0; k < 512; ++k) {
    const float* wp = dec_W + (size_t)k*G3 + j;
    const float* up = dec_U + (size_t)k*G3 + j;
    const float yv = ye[k], sv = st[k];
    xz0 += yv*wp[0]; xz1 += yv*wp[512]; xz2 += yv*wp[1024];
    rc0 += sv*up[0]; rc1 += sv*up[512]; rc2 += sv*up[1024];
  }
  const float z  = sigf(xz0 + rc0);
  const float r  = sigf(xz1 + rc1);
  const float hh = tanh_fast(xz2 + r*rc2);
  dst[(size_t)b*512 + j] = z*st[j] + (1.f-z)*hh;
}

__global__ __launch_bounds__(128) void k_dterm(const float* __restrict__ dec,
    const float* __restrict__ att_Ws, const float* __restrict__ att_bs,
    float* __restrict__ dterm)
{
  const int b = blockIdx.y;
  const int j = blockIdx.x*128 + threadIdx.x;
  float acc = att_bs[j];
  const float* d = dec + (size_t)b*512;
  #pragma unroll 4
  for (int k = 0; k < 512; ++k) acc += d[k] * att_Ws[(size_t)k*512 + j];
  dterm[(size_t)b*512 + j] = acc;
}

__global__ __launch_bounds__(512) void k_soft(const float* __restrict__ e_part,
    const int* __restrict__ x_mask, float* __restrict__ wat)
{
  const int b = blockIdx.x, tid = threadIdx.x;
  __shared__ float sm[512];
  float e = -1e30f, ev = 0.f;
  if (tid < S_LEN) {
    const float* ep = e_part + (size_t)(b*S_LEN + tid)*4;
    ev = ep[0]+ep[1]+ep[2]+ep[3] + (float)x_mask[b*S_LEN+tid] * -1e10f;
    e = ev;
  }
  sm[tid] = e; __syncthreads();
  for (int s = 256; s > 0; s >>= 1) { if (tid < s) sm[tid] = fmaxf(sm[tid], sm[tid+s]); __syncthreads(); }
  const float m = sm[0]; __syncthreads();
  const float x = (tid < S_LEN) ? __expf(ev - m) : 0.f;
  sm[tid] = x; __syncthreads();
  for (int s = 256; s > 0; s >>= 1) { if (tid < s) sm[tid] += sm[tid+s]; __syncthreads(); }
  const float inv = 1.f / sm[0];
  if (tid < S_LEN) wat[b*S_LEN+tid] = x * inv;
}

__global__ __launch_bounds__(128) void k_ctx(const float* __restrict__ wat,
    const float* __restrict__ enc, float* __restrict__ ctx)
{
  const int b = blockIdx.y;
  const int j = blockIdx.x*128 + threadIdx.x;
  float acc = 0.f;
  const float* w = wat + b*S_LEN;
  const float* ep = enc + (size_t)b*S_LEN*1024 + j;
  #pragma unroll 4
  for (int s = 0; s < S_LEN; ++s) acc += w[s] * ep[(size_t)s*1024];
  ctx[(size_t)b*1024 + j] = acc;
}

__global__ __launch_bounds__(128) void k_yout(const float* __restrict__ dec,
    const float* __restrict__ ctx, const float* __restrict__ fc_W,
    const float* __restrict__ fc_b, float* __restrict__ y_out)
{
  const int b = blockIdx.y;
  const int j = blockIdx.x*128 + threadIdx.x;
  float acc = fc_b[j];
  const float* d = dec + (size_t)b*512;
  const float* c = ctx + (size_t)b*1024;
  #pragma unroll 4
  for (int k = 0; k < 512; ++k)  acc += d[k]*fc_W[(size_t)k*512 + j];
  #pragma unroll 4
  for (int k = 0; k < 1024; ++k) acc += c[k]*fc_W[(size_t)(512+k)*512 + j];
  y_out[(size_t)b*512 + j] = acc;
}

__global__ __launch_bounds__(256) void k_pgen(const float* __restrict__ ctx,
    const float* __restrict__ dec, const float* __restrict__ yemb,
    const float* __restrict__ pg_Wh, const float* __restrict__ pg_Ws,
    const float* __restrict__ pg_Wx, const float* __restrict__ pg_b,
    float* __restrict__ pg)
{
  const int b = blockIdx.x, tid = threadIdx.x;
  __shared__ float sm[256];
  float acc = 0.f;
  for (int k = tid; k < 1024; k += 256) acc += ctx[(size_t)b*1024+k]*pg_Wh[k];
  for (int k = tid; k < 512;  k += 256) acc += dec[(size_t)b*512+k]*pg_Ws[k] + yemb[(size_t)b*512+k]*pg_Wx[k];
  sm[tid] = acc; __syncthreads();
  for (int s = 128; s > 0; s >>= 1) { if (tid < s) sm[tid] += sm[tid+s]; __syncthreads(); }
  if (tid == 0) pg[b] = sigf(sm[0] + pg_b[0]);
}

__global__ __launch_bounds__(256) void k_vocab(const float* __restrict__ y_out,
    const float* __restrict__ vocab_W, float* __restrict__ logits)
{
  __shared__ float y_lds[256][32];   // [k][b], one k-half at a time (32 KB)
  const int tid = threadIdx.x;
  const int vq = tid & 63, bq = tid >> 6;
  const int v = blockIdx.x * 256 + vq * 4;
  float acc[8][4];
  #pragma unroll
  for (int i = 0; i < 8; ++i)
    #pragma unroll
    for (int j = 0; j < 4; ++j) acc[i][j] = 0.f;
  for (int half = 0; half < 2; ++half) {
    __syncthreads();
    for (int i = 0; i < 32; ++i) {
      const int idx = tid + 256*i;
      const int k = idx >> 5, b = idx & 31;
      y_lds[k][b] = y_out[(size_t)b*512 + half*256 + k];
    }
    __syncthreads();
    if (v < VOC) {
      #pragma unroll 4
      for (int k = 0; k < 256; ++k) {
        const float4 wv = *(const float4*)&vocab_W[(size_t)(half*256 + k) * VOC + v];
        const float4 ya = *(const float4*)&y_lds[k][bq*8];
        const float4 yb = *(const float4*)&y_lds[k][bq*8+4];
        const float yy[8] = {ya.x,ya.y,ya.z,ya.w,yb.x,yb.y,yb.z,yb.w};
        #pragma unroll
        for (int i = 0; i < 8; ++i) {
          acc[i][0] += yy[i]*wv.x; acc[i][1] += yy[i]*wv.y;
          acc[i][2] += yy[i]*wv.z; acc[i][3] += yy[i]*wv.w;
        }
      }
    }
  }
  if (v < VOC) {
    #pragma unroll
    for (int i = 0; i < 8; ++i)
      *(float4*)&logits[(size_t)(bq*8+i)*VOC + v] = make_float4(acc[i][0],acc[i][1],acc[i][2],acc[i][3]);
  }
}

__global__ __launch_bounds__(1024) void k_vred(const float* __restrict__ logits,
                                               float* __restrict__ red2)
{
  const int b = blockIdx.x, tid = threadIdx.x;
  __shared__ float sm[1024];
  float m = -1e30f;
  for (int i = tid; i < VOC; i += 1024) m = fmaxf(m, logits[(size_t)b*VOC + i]);
  sm[tid] = m; __syncthreads();
  for (int s = 512; s > 0; s >>= 1) { if (tid < s) sm[tid] = fmaxf(sm[tid], sm[tid+s]); __syncthreads(); }
  m = sm[0]; __syncthreads();
  float sum = 0.f;
  for (int i = tid; i < VOC; i += 1024) sum += __expf(logits[(size_t)b*VOC + i] - m);
  sm[tid] = sum; __syncthreads();
  for (int s = 512; s > 0; s >>= 1) { if (tid < s) sm[tid] += sm[tid+s]; __syncthreads(); }
  if (tid == 0) { red2[b*2] = m; red2[b*2+1] = sm[0]; }
}

__global__ __launch_bounds__(256) void k_final(const float* __restrict__ logits,
    const float* __restrict__ red2, const float* __restrict__ pg,
    float* __restrict__ out)
{
  const size_t idx = (size_t)blockIdx.x*256 + threadIdx.x;
  const int b = (int)(idx / OUTW);
  const int c = (int)(idx - (size_t)b*OUTW);
  float v = 0.f;
  if (c < VOC) {
    const float m = red2[b*2], s = red2[b*2+1];
    v = pg[b] * __expf(logits[(size_t)b*VOC + c] - m) / s;
  }
  out[idx] = v;
}

__global__ __launch_bounds__(256) void k_scatter(const float* __restrict__ wat,
    const int* __restrict__ x_mask, const float* __restrict__ pg,
    const int* __restrict__ x_id, float* __restrict__ out)
{
  const int i = blockIdx.x*256 + threadIdx.x;   // < 12800
  const int b = i / S_LEN;
  const float aw = wat[i] * (1.f - (float)x_mask[i]) * (1.f - pg[b]);
  atomicAdd(out + (size_t)b*OUTW + x_id[i], aw);
}

// ---------------------------------------------------------------------------
extern "C" void kernel_launch(void* const* d_in, const int* in_sizes, int n_in,
                              void* d_out, int out_size, void* d_ws, size_t ws_size,
                              hipStream_t stream)
{
  (void)in_sizes; (void)n_in; (void)out_size; (void)ws_size;
  const int*   x_id     = (const int*)d_in[0];
  const int*   y_id     = (const int*)d_in[1];
  const int*   x_mask   = (const int*)d_in[2];
  const float* emb      = (const float*)d_in[3];
  const float* enc_fw_W = (const float*)d_in[4];
  const float* enc_fw_U = (const float*)d_in[5];
  const float* enc_fw_b = (const float*)d_in[6];
  const float* enc_bw_W = (const float*)d_in[7];
  const float* enc_bw_U = (const float*)d_in[8];
  const float* enc_bw_b = (const float*)d_in[9];
  const float* red_W    = (const float*)d_in[10];
  const float* red_b    = (const float*)d_in[11];
  const float* dec_W    = (const float*)d_in[12];
  const float* dec_U    = (const float*)d_in[13];
  const float* dec_b    = (const float*)d_in[14];
  const float* att_Wh   = (const float*)d_in[15];
  const float* att_Ws   = (const float*)d_in[16];
  const float* att_bs   = (const float*)d_in[17];
  const float* att_Wc   = (const float*)d_in[18]; (void)att_Wc; // cover == 0
  const float* att_V    = (const float*)d_in[19];
  const float* fc_W     = (const float*)d_in[20];
  const float* fc_b     = (const float*)d_in[21];
  const float* vocab_W  = (const float*)d_in[22];
  const float* pg_Wh    = (const float*)d_in[23];
  const float* pg_Ws    = (const float*)d_in[24];
  const float* pg_Wx    = (const float*)d_in[25];
  const float* pg_b     = (const float*)d_in[26];
  float* out = (float*)d_out;

  const size_t NPKT = (size_t)2*2*BATCH*HID;            // [dir][parity][b][j]
  char* p = (char*)d_ws;
  ushort* xzm   = (ushort*)p; p += (size_t)BATCH*S_LEN*N2*2;     // 78.6 MB
  float*  enc   = (float*)p;  p += (size_t)BATCH*S_LEN*1024*4;   // 52.4 MB
  ushort* encbf = (ushort*)p; p += (size_t)BATCH*S_LEN*1024*2;   // 26.2 MB
  ull*   hpkt   = (ull*)p;    p += NPKT*8;                       // 1 MB
  ushort* Abf   = (ushort*)p; p += (size_t)BATCH*S_LEN*512*2;    // 13.1 MB
  ushort* Wt    = (ushort*)p; p += (size_t)N2*512*2;             // 3.1 MB
  ushort* Whbf  = (ushort*)p; p += (size_t)512*1024*2;           // 1.0 MB
  float*  bm    = (float*)p;  p += (size_t)N2*4;
  float*  fstate = (float*)p; p += (size_t)BATCH*HID*4;
  float*  yemb   = (float*)p; p += (size_t)BATCH*HID*4;
  float*  decs   = (float*)p; p += (size_t)BATCH*HID*4;
  float*  dterm  = (float*)p; p += (size_t)BATCH*HID*4;
  float*  epart  = (float*)p; p += (size_t)BATCH*S_LEN*4*4;
  float*  wat    = (float*)p; p += (size_t)BATCH*S_LEN*4;
  float*  ctx    = (float*)p; p += (size_t)BATCH*1024*4;
  float*  yout   = (float*)p; p += (size_t)BATCH*HID*4;
  float*  pg     = (float*)p; p += (size_t)256*4;
  float*  logits = (float*)p; p += (size_t)BATCH*VOC*4;          // 6.4 MB
  float*  red2   = (float*)p; p += (size_t)64*4;

  // zero the packet buffer: {0.0f, tag 0} == valid h(0) for every slot
  hipMemsetAsync(hpkt, 0, NPKT * sizeof(ull), stream);

  // bf16 conversions: embedding gather, xz weights (transpose), attn weights
  k_cvtA<<<BATCH*S_LEN/4, 256, 0, stream>>>(x_id, emb, Abf);
  k_transW<<<dim3(512/64, N2/64), 256, 0, stream>>>(
      enc_fw_W, enc_bw_W, G3, G3, 512, Wt, enc_fw_b, enc_bw_b, bm);
  k_transW<<<dim3(1024/64, 512/64), 256, 0, stream>>>(
      att_Wh, att_Wh, 512, 512, 1024, Whbf, nullptr, nullptr, nullptr);
  // merged input projection (bf16 MFMA): xz = A @ [Wfw|Wbw] + [bfw0|bbw0]
  gemm_bf16<<<dim3(N2/128, BATCH*S_LEN/128), 256, 0, stream>>>(Abf, Wt, bm, xzm);
  // persistent bidirectional GRU scan (coalesced tagged-packet sync)
  gru_scan<<<256,512,0,stream>>>(xzm, enc_fw_U, enc_bw_U, enc_fw_b, enc_bw_b,
                                 enc, encbf, hpkt);
  // reduce state + decoder step + attention query term
  k_state<<<dim3(4,32),128,0,stream>>>(enc, red_W, red_b, fstate);
  k_yemb<<<32,256,0,stream>>>(y_id, emb, yemb);
  k_dec<<<dim3(4,32),128,0,stream>>>(yemb, fstate, dec_W, dec_U, dec_b, decs);
  k_dterm<<<dim3(4,32),128,0,stream>>>(decs, att_Ws, att_bs, dterm);
  // attention scores (bf16 MFMA + fused tanh * att_V reduction)
  gemm_att<<<dim3(4, BATCH*S_LEN/128), 256, 0, stream>>>(encbf, Whbf, dterm,
                                                         att_V, epart);
  k_soft<<<32,512,0,stream>>>(epart, x_mask, wat);
  k_ctx<<<dim3(8,32),128,0,stream>>>(wat, enc, ctx);
  k_yout<<<dim3(4,32),128,0,stream>>>(decs, ctx, fc_W, fc_b, yout);
  k_pgen<<<32,256,0,stream>>>(ctx, decs, yemb, pg_Wh, pg_Ws, pg_Wx, pg_b, pg);
  // vocab distribution + final assembly
  k_vocab<<<196,256,0,stream>>>(yout, vocab_W, logits);
  k_vred<<<32,1024,0,stream>>>(logits, red2);
  k_final<<<6300,256,0,stream>>>(logits, red2, pg, out);
  k_scatter<<<50,256,0,stream>>>(wat, x_mask, pg, x_id, out);
}

// Round 11
// 1677.147 us; speedup vs baseline: 4.5347x; 1.4667x over previous
//
#include <hip/hip_runtime.h>
#include <math.h>

#define S_LEN 400
#define BATCH 32
#define HID   512
#define G3    1536
#define N2    3072
#define VOC   50000
#define OUTW  (VOC + S_LEN)

typedef unsigned long long ull;
typedef unsigned int uint;
typedef unsigned short ushort;
typedef short bf16x8 __attribute__((ext_vector_type(8)));
typedef float f32x4 __attribute__((ext_vector_type(4)));
typedef ushort u16x8 __attribute__((ext_vector_type(8)));

__device__ __forceinline__ float sigf(float x) { return 1.f / (1.f + __expf(-x)); }
__device__ __forceinline__ float tanh_fast(float x) {
  const float xc = fminf(fmaxf(x, -15.f), 15.f);
  const float e = __expf(-2.f * xc);
  return (1.f - e) / (1.f + e);
}
__device__ __forceinline__ ushort f2bf(float f) {       // RNE fp32 -> bf16
  uint u = __float_as_uint(f);
  u += 0x7FFFu + ((u >> 16) & 1u);
  return (ushort)(u >> 16);
}
__device__ __forceinline__ float bf2f(ushort h) {
  return __uint_as_float((uint)h << 16);
}

// ---------------------------------------------------------------------------
// Persistent bidirectional GRU scan — tagged-packet sync + MFMA matvec.
// 256 blocks x 512 thr. group = bid&7 (dir=group>>2, bg=group&3), ht=bid>>3
// (16 j's per block). h moves as tagged 8B {fp32, step} packets via relaxed
// agent atomics (LLC); tags are the sole source of truth (monotone t->t+2).
// Per step: all 8 waves poll batch cb=w's 512 packets (coalesced, stride 64)
// and write h as bf16 into h_bf[16][520] (rows 8-15 zero). Waves 0-5 then run
// the recurrent matvec as MFMA 16x16x32 bf16: wave (gate=w%3, half=w/3) does
// 8 K-steps with U fragments preloaded in registers from Utbf (transposed
// bf16 U). Gate phase (tid<128) reads fp32 h_old from its OWN packet (polled
// jointly), so h storage precision stays fp32 — bf16 enters only the matvec,
// same error class as the xz term.
// ---------------------------------------------------------------------------
__global__ __launch_bounds__(512) void gru_scan(
    const ushort* __restrict__ xzm,           // [32*400][3072] bf16 fw|bw
    const ushort* __restrict__ Utbf,          // [2][1536][512] bf16 (U^T)
    const float* __restrict__ bfw, const float* __restrict__ bbw,
    float* __restrict__ enc_seq, ushort* __restrict__ enc_bf,
    ull* __restrict__ hpkt)
{
  const int bid = blockIdx.x;
  const int group = bid & 7;
  const int dir = group >> 2;
  const int bg  = group & 3;
  const int ht  = bid >> 3;          // j-tile: 16 j's
  const int tid = threadIdx.x;
  const int lane = tid & 63;
  const int w  = tid >> 6;           // wave 0..7
  const int l15 = lane & 15;
  const int lk  = lane >> 4;

  const float* __restrict__ br = (dir ? bbw : bfw) + G3;   // bias row 1

  // U fragments in registers (waves 0..5): gate = w%3, half = w/3.
  // ufrag[s][i] = Ut[dir][gate*512 + ht*16 + l15][half*256 + s*32 + lk*8 + i]
  const int gate = w % 3, half = w / 3;
  bf16x8 ufrag[8];
  if (w < 6) {
    const ushort* ub = Utbf + ((size_t)dir * G3 + gate * 512 + ht * 16 + l15) * 512
                     + half * 256 + lk * 8;
    #pragma unroll
    for (int s = 0; s < 8; ++s)
      ufrag[s] = *(const bf16x8*)(ub + s * 32);
  }

  __shared__ ushort h_bf[16][520];       // bf16 h, rows 8-15 zero (16.6 KB)
  __shared__ float red2[2][3][8][16];    // [half][gate][b][j] (3 KB)

  // zero h_bf once (rows 8-15 stay zero forever)
  for (int i = tid; i < 16 * 520; i += 512) ((ushort*)h_bf)[i] = 0;

  // consumer mapping: wave w = batch-in-group
  const int cb = w;
  // gate mapping (threads 0..127)
  const int gbi = tid >> 4;              // 0..7 for tid<128
  const int gj  = tid & 15;
  const int gjq = ht * 16 + gj;
  const int gb  = bg * 8 + (gbi & 7);
  const float brz = br[gjq], brr = br[512 + gjq], brh = br[1024 + gjq];

  ull* __restrict__ pk = hpkt + (size_t)dir * (2 * BATCH * HID);   // [parity][b][j]
  __syncthreads();   // h_bf zero visible

  for (int t = 0; t < S_LEN; ++t) {
    const int ts = dir ? (S_LEN - 1 - t) : t;

    // xz prefetch (bf16, independent of h; overlaps the poll)
    float xzv0 = 0.f, xzv1 = 0.f, xzv2 = 0.f;
    if (tid < 128) {
      const ushort* xp = xzm + ((size_t)gb * S_LEN + ts) * N2 + dir * G3 + gjq;
      xzv0 = bf2f(xp[0]); xzv1 = bf2f(xp[512]); xzv2 = bf2f(xp[1024]);
    }

    // ---- consume h(t): coalesced tagged poll (+ own fp32 hold, tid<128) ----
    float hold = 0.f;
    {
      ull* bp = pk + ((size_t)(t & 1) * BATCH + (bg * 8 + cb)) * HID + lane;
      ull* hp = pk + ((size_t)(t & 1) * BATCH + gb) * HID + gjq;
      const uint tu = (uint)t;
      for (;;) {
        ull v0 = __hip_atomic_load(bp,       __ATOMIC_RELAXED, __HIP_MEMORY_SCOPE_AGENT);
        ull v1 = __hip_atomic_load(bp + 64,  __ATOMIC_RELAXED, __HIP_MEMORY_SCOPE_AGENT);
        ull v2 = __hip_atomic_load(bp + 128, __ATOMIC_RELAXED, __HIP_MEMORY_SCOPE_AGENT);
        ull v3 = __hip_atomic_load(bp + 192, __ATOMIC_RELAXED, __HIP_MEMORY_SCOPE_AGENT);
        ull v4 = __hip_atomic_load(bp + 256, __ATOMIC_RELAXED, __HIP_MEMORY_SCOPE_AGENT);
        ull v5 = __hip_atomic_load(bp + 320, __ATOMIC_RELAXED, __HIP_MEMORY_SCOPE_AGENT);
        ull v6 = __hip_atomic_load(bp + 384, __ATOMIC_RELAXED, __HIP_MEMORY_SCOPE_AGENT);
        ull v7 = __hip_atomic_load(bp + 448, __ATOMIC_RELAXED, __HIP_MEMORY_SCOPE_AGENT);
        bool ok = ((uint)(v0 >> 32) == tu) & ((uint)(v1 >> 32) == tu)
                & ((uint)(v2 >> 32) == tu) & ((uint)(v3 >> 32) == tu)
                & ((uint)(v4 >> 32) == tu) & ((uint)(v5 >> 32) == tu)
                & ((uint)(v6 >> 32) == tu) & ((uint)(v7 >> 32) == tu);
        ull hv = 0;
        if (tid < 128) {
          hv = __hip_atomic_load(hp, __ATOMIC_RELAXED, __HIP_MEMORY_SCOPE_AGENT);
          ok &= ((uint)(hv >> 32) == tu);
        }
        if (__all(ok)) {
          h_bf[cb][lane]       = f2bf(__uint_as_float((uint)v0));
          h_bf[cb][lane + 64]  = f2bf(__uint_as_float((uint)v1));
          h_bf[cb][lane + 128] = f2bf(__uint_as_float((uint)v2));
          h_bf[cb][lane + 192] = f2bf(__uint_as_float((uint)v3));
          h_bf[cb][lane + 256] = f2bf(__uint_as_float((uint)v4));
          h_bf[cb][lane + 320] = f2bf(__uint_as_float((uint)v5));
          h_bf[cb][lane + 384] = f2bf(__uint_as_float((uint)v6));
          h_bf[cb][lane + 448] = f2bf(__uint_as_float((uint)v7));
          if (tid < 128) hold = __uint_as_float((uint)hv);
          break;
        }
        __builtin_amdgcn_s_sleep(1);
      }
    }
    __syncthreads();   // S1: h_bf ready

    // ---- recurrent matvec: MFMA 16x16x32 bf16, waves 0..5 ----
    if (w < 6) {
      f32x4 acc = f32x4{0.f, 0.f, 0.f, 0.f};
      const int kbase = half * 256;
      #pragma unroll
      for (int s = 0; s < 8; ++s) {
        const bf16x8 af = *(const bf16x8*)&h_bf[l15][kbase + s * 32 + lk * 8];
        acc = __builtin_amdgcn_mfma_f32_16x16x32_bf16(af, ufrag[s], acc, 0, 0, 0);
      }
      if (lk < 2) {   // rows 0..7 = real batches
        #pragma unroll
        for (int r = 0; r < 4; ++r)
          red2[half][gate][lk * 4 + r][l15] = acc[r];
      }
    }
    __syncthreads();   // S2: red2 ready

    // ---- gates + publish h(t+1) ----
    if (tid < 128) {
      const float rz = red2[0][0][gbi][gj] + red2[1][0][gbi][gj] + brz;
      const float rr = red2[0][1][gbi][gj] + red2[1][1][gbi][gj] + brr;
      const float rh = red2[0][2][gbi][gj] + red2[1][2][gbi][gj] + brh;
      const float z  = sigf(xzv0 + rz);
      const float r  = sigf(xzv1 + rr);
      const float hh = tanh_fast(xzv2 + r * rh);
      const float hnew = z * hold + (1.f - z) * hh;
      const ull pack = ((ull)(uint)(t + 1) << 32) | (ull)__float_as_uint(hnew);
      __hip_atomic_store(pk + ((size_t)((t + 1) & 1) * BATCH + gb) * HID + gjq,
                         pack, __ATOMIC_RELAXED, __HIP_MEMORY_SCOPE_AGENT);
      const size_t eidx = ((size_t)gb * S_LEN + ts) * 1024 + dir * 512 + gjq;
      enc_seq[eidx] = hnew;
      enc_bf[eidx]  = f2bf(hnew);
    }
    __syncthreads();   // S3: publishes issued; h_bf/red2 safe for next fill
  }
}

// ---------------------------------------------------------------------------
// Gather + convert: A_bf[r][k] = bf16(emb[x_id[r]][k]).  3200 blocks x 256.
// ---------------------------------------------------------------------------
__global__ __launch_bounds__(256) void k_cvtA(
    const int* __restrict__ x_id, const float* __restrict__ emb,
    ushort* __restrict__ Abf)
{
  const int tid = threadIdx.x;
  const int row = blockIdx.x * 4 + (tid >> 6);
  const int k8 = (tid & 63) * 8;
  const int rid = x_id[row];
  const float4 e0 = *(const float4*)&emb[(size_t)rid * 512 + k8];
  const float4 e1 = *(const float4*)&emb[(size_t)rid * 512 + k8 + 4];
  u16x8 o;
  o[0] = f2bf(e0.x); o[1] = f2bf(e0.y); o[2] = f2bf(e0.z); o[3] = f2bf(e0.w);
  o[4] = f2bf(e1.x); o[5] = f2bf(e1.y); o[6] = f2bf(e1.z); o[7] = f2bf(e1.w);
  *(u16x8*)&Abf[(size_t)row * 512 + k8] = o;
}

// ---------------------------------------------------------------------------
// Tiled transpose + bf16 convert: dst[n][k] = bf16(src[k][n]).
// src split column-wise at `split` between srcA|srcB (row stride srcStride).
// 64x64 tiles via LDS. Optional bias merge on the k0==0 tile row.
// grid: (Krows/64, Ncols/64), 256 threads.
// ---------------------------------------------------------------------------
__global__ __launch_bounds__(256) void k_transW(
    const float* __restrict__ srcA, const float* __restrict__ srcB,
    const int split, const int srcStride, const int Krows,
    ushort* __restrict__ dst,
    const float* __restrict__ biasA, const float* __restrict__ biasB,
    float* __restrict__ bm)
{
  __shared__ float t[64][65];
  const int k0 = blockIdx.x * 64, n0 = blockIdx.y * 64;
  const int tid = threadIdx.x;
  const int j = tid & 63, i0 = tid >> 6;
  {
    const int n = n0 + j;
    const float* s = (n < split) ? (srcA + n) : (srcB + (n - split));
    #pragma unroll
    for (int i = i0; i < 64; i += 4)
      t[i][j] = s[(size_t)(k0 + i) * srcStride];
  }
  __syncthreads();
  const int ii = tid & 63;
  #pragma unroll
  for (int jj = i0; jj < 64; jj += 4)
    dst[(size_t)(n0 + jj) * Krows + k0 + ii] = f2bf(t[ii][jj]);
  if (bm != nullptr && k0 == 0 && tid < 64) {
    const int n = n0 + tid;
    bm[n] = (n < split) ? biasA[n] : biasB[n - split];
  }
}

// ---------------------------------------------------------------------------
// bf16 MFMA GEMM: C[12800][3072] = A[12800][512] @ Wt^T + bm, C in bf16.
// 128x128 tile, 256 thr (4 waves), 16x16x32 bf16 MFMA, fp32 accum.
// ---------------------------------------------------------------------------
__global__ __launch_bounds__(256) void gemm_bf16(
    const ushort* __restrict__ A,    // [M][512] bf16
    const ushort* __restrict__ Bt,   // [N][512] bf16 (row n = W col n)
    const float* __restrict__ bias,  // [N] fp32
    ushort* __restrict__ C)          // [M][3072] bf16
{
  const int m0 = blockIdx.y * 128, n0 = blockIdx.x * 128;
  const int tid = threadIdx.x;
  const int w = tid >> 6, lane = tid & 63;
  const int l15 = lane & 15, lk = lane >> 4;
  __shared__ short As[128][40];      // +8 pad: row stride 80B (16B-aligned)
  __shared__ short Bs[128][40];
  f32x4 acc[2][8];
  #pragma unroll
  for (int i = 0; i < 2; ++i)
    #pragma unroll
    for (int j = 0; j < 8; ++j) acc[i][j] = f32x4{0.f, 0.f, 0.f, 0.f};

  const int sr = tid >> 1;           // stage row 0..127
  const int sc = (tid & 1) * 8;      // k-offset 0 or 8

  for (int k0 = 0; k0 < 512; k0 += 32) {
    const uint4 a0 = *(const uint4*)&A[(size_t)(m0 + sr) * 512 + k0 + sc];
    const uint4 a1 = *(const uint4*)&A[(size_t)(m0 + sr) * 512 + k0 + 16 + sc];
    const uint4 b0 = *(const uint4*)&Bt[(size_t)(n0 + sr) * 512 + k0 + sc];
    const uint4 b1 = *(const uint4*)&Bt[(size_t)(n0 + sr) * 512 + k0 + 16 + sc];
    *(uint4*)&As[sr][sc]      = a0;
    *(uint4*)&As[sr][16 + sc] = a1;
    *(uint4*)&Bs[sr][sc]      = b0;
    *(uint4*)&Bs[sr][16 + sc] = b1;
    __syncthreads();

    bf16x8 af[2], bfr[8];
    #pragma unroll
    for (int rf = 0; rf < 2; ++rf)
      af[rf] = *(const bf16x8*)&As[w * 32 + rf * 16 + l15][lk * 8];
    #pragma unroll
    for (int cf = 0; cf < 8; ++cf)
      bfr[cf] = *(const bf16x8*)&Bs[cf * 16 + l15][lk * 8];
    #pragma unroll
    for (int rf = 0; rf < 2; ++rf)
      #pragma unroll
      for (int cf = 0; cf < 8; ++cf)
        acc[rf][cf] = __builtin_amdgcn_mfma_f32_16x16x32_bf16(
            af[rf], bfr[cf], acc[rf][cf], 0, 0, 0);
    __syncthreads();
  }

  #pragma unroll
  for (int rf = 0; rf < 2; ++rf) {
    #pragma unroll
    for (int cf = 0; cf < 8; ++cf) {
      const int col = n0 + cf * 16 + l15;
      const float bv = bias[col];
      const int rowb = m0 + w * 32 + rf * 16 + lk * 4;
      #pragma unroll
      for (int r = 0; r < 4; ++r)
        C[(size_t)(rowb + r) * N2 + col] = f2bf(acc[rf][cf][r] + bv);
    }
  }
}

// ---------------------------------------------------------------------------
// bf16 MFMA attention-score GEMM with fused epilogue:
// e_part[row][bx] = sum_n attV[n] * tanh(enc_bf[row]@Wh[:,n] + dterm[b][n])
// ---------------------------------------------------------------------------
__global__ __launch_bounds__(256) void gemm_att(
    const ushort* __restrict__ A,    // [12800][1024] bf16
    const ushort* __restrict__ Bt,   // [512][1024] bf16
    const float* __restrict__ dterm, // [32][512] fp32
    const float* __restrict__ attV,  // [512] fp32
    float* __restrict__ e_part)      // [12800][4]
{
  const int m0 = blockIdx.y * 128, n0 = blockIdx.x * 128;
  const int tid = threadIdx.x;
  const int w = tid >> 6, lane = tid & 63;
  const int l15 = lane & 15, lk = lane >> 4;
  __shared__ short As[128][40];
  __shared__ short Bs[128][40];
  f32x4 acc[2][8];
  #pragma unroll
  for (int i = 0; i < 2; ++i)
    #pragma unroll
    for (int j = 0; j < 8; ++j) acc[i][j] = f32x4{0.f, 0.f, 0.f, 0.f};

  const int sr = tid >> 1;
  const int sc = (tid & 1) * 8;

  for (int k0 = 0; k0 < 1024; k0 += 32) {
    const uint4 a0 = *(const uint4*)&A[(size_t)(m0 + sr) * 1024 + k0 + sc];
    const uint4 a1 = *(const uint4*)&A[(size_t)(m0 + sr) * 1024 + k0 + 16 + sc];
    const uint4 b0 = *(const uint4*)&Bt[(size_t)(n0 + sr) * 1024 + k0 + sc];
    const uint4 b1 = *(const uint4*)&Bt[(size_t)(n0 + sr) * 1024 + k0 + 16 + sc];
    *(uint4*)&As[sr][sc]      = a0;
    *(uint4*)&As[sr][16 + sc] = a1;
    *(uint4*)&Bs[sr][sc]      = b0;
    *(uint4*)&Bs[sr][16 + sc] = b1;
    __syncthreads();

    bf16x8 af[2], bfr[8];
    #pragma unroll
    for (int rf = 0; rf < 2; ++rf)
      af[rf] = *(const bf16x8*)&As[w * 32 + rf * 16 + l15][lk * 8];
    #pragma unroll
    for (int cf = 0; cf < 8; ++cf)
      bfr[cf] = *(const bf16x8*)&Bs[cf * 16 + l15][lk * 8];
    #pragma unroll
    for (int rf = 0; rf < 2; ++rf)
      #pragma unroll
      for (int cf = 0; cf < 8; ++cf)
        acc[rf][cf] = __builtin_amdgcn_mfma_f32_16x16x32_bf16(
            af[rf], bfr[cf], acc[rf][cf], 0, 0, 0);
    __syncthreads();
  }

  #pragma unroll
  for (int rf = 0; rf < 2; ++rf) {
    #pragma unroll
    for (int r = 0; r < 4; ++r) {
      const int row = m0 + w * 32 + rf * 16 + lk * 4 + r;
      const int b = row / S_LEN;
      float p = 0.f;
      #pragma unroll
      for (int cf = 0; cf < 8; ++cf) {
        const int col = n0 + cf * 16 + l15;
        p += attV[col] * tanh_fast(acc[rf][cf][r] + dterm[(size_t)b * 512 + col]);
      }
      p += __shfl_xor(p, 1); p += __shfl_xor(p, 2);
      p += __shfl_xor(p, 4); p += __shfl_xor(p, 8);
      if (l15 == 0) e_part[(size_t)row * 4 + blockIdx.x] = p;
    }
  }
}

// --------------------------- small kernels ---------------------------------
__global__ __launch_bounds__(128) void k_state(const float* __restrict__ enc,
    const float* __restrict__ red_W, const float* __restrict__ red_b,
    float* __restrict__ state)
{
  const int b = blockIdx.y;
  const int j = blockIdx.x*128 + threadIdx.x;
  float acc = red_b[j];
  const float* fw = enc + ((size_t)b*S_LEN + (S_LEN-1))*1024;
  const float* bw = enc + ((size_t)b*S_LEN + 0)*1024 + 512;
  #pragma unroll 4
  for (int k = 0; k < 512; ++k) acc += fw[k] * red_W[(size_t)k*512 + j];
  #pragma unroll 4
  for (int k = 0; k < 512; ++k) acc += bw[k] * red_W[(size_t)(512+k)*512 + j];
  state[(size_t)b*512 + j] = fmaxf(acc, 0.f);
}

__global__ void k_yemb(const int* __restrict__ y_id, const float* __restrict__ emb,
                       float* __restrict__ yemb)
{
  const int b = blockIdx.x, tid = threadIdx.x;
  const int r = y_id[b];
  yemb[(size_t)b*512 + tid]       = emb[(size_t)r*512 + tid];
  yemb[(size_t)b*512 + 256 + tid] = emb[(size_t)r*512 + 256 + tid];
}

__global__ __launch_bounds__(128) void k_dec(const float* __restrict__ yemb,
    const float* __restrict__ state, const float* __restrict__ dec_W,
    const float* __restrict__ dec_U, const float* __restrict__ dec_b,
    float* __restrict__ dst)
{
  const int b = blockIdx.y;
  const int j = blockIdx.x*128 + threadIdx.x;
  float xz0 = dec_b[j], xz1 = dec_b[512+j], xz2 = dec_b[1024+j];
  float rc0 = dec_b[G3+j], rc1 = dec_b[G3+512+j], rc2 = dec_b[G3+1024+j];
  const float* ye = yemb + (size_t)b*512;
  const float* st = state + (size_t)b*512;
  #pragma unroll 2
  for (int k = 0; k < 512; ++k) {
    const float* wp = dec_W + (size_t)k*G3 + j;
    const float* up = dec_U + (size_t)k*G3 + j;
    const float yv = ye[k], sv = st[k];
    xz0 += yv*wp[0]; xz1 += yv*wp[512]; xz2 += yv*wp[1024];
    rc0 += sv*up[0]; rc1 += sv*up[512]; rc2 += sv*up[1024];
  }
  const float z  = sigf(xz0 + rc0);
  const float r  = sigf(xz1 + rc1);
  const float hh = tanh_fast(xz2 + r*rc2);
  dst[(size_t)b*512 + j] = z*st[j] + (1.f-z)*hh;
}

__global__ __launch_bounds__(128) void k_dterm(const float* __restrict__ dec,
    const float* __restrict__ att_Ws, const float* __restrict__ att_bs,
    float* __restrict__ dterm)
{
  const int b = blockIdx.y;
  const int j = blockIdx.x*128 + threadIdx.x;
  float acc = att_bs[j];
  const float* d = dec + (size_t)b*512;
  #pragma unroll 4
  for (int k = 0; k < 512; ++k) acc += d[k] * att_Ws[(size_t)k*512 + j];
  dterm[(size_t)b*512 + j] = acc;
}

__global__ __launch_bounds__(512) void k_soft(const float* __restrict__ e_part,
    const int* __restrict__ x_mask, float* __restrict__ wat)
{
  const int b = blockIdx.x, tid = threadIdx.x;
  __shared__ float sm[512];
  float e = -1e30f, ev = 0.f;
  if (tid < S_LEN) {
    const float* ep = e_part + (size_t)(b*S_LEN + tid)*4;
    ev = ep[0]+ep[1]+ep[2]+ep[3] + (float)x_mask[b*S_LEN+tid] * -1e10f;
    e = ev;
  }
  sm[tid] = e; __syncthreads();
  for (int s = 256; s > 0; s >>= 1) { if (tid < s) sm[tid] = fmaxf(sm[tid], sm[tid+s]); __syncthreads(); }
  const float m = sm[0]; __syncthreads();
  const float x = (tid < S_LEN) ? __expf(ev - m) : 0.f;
  sm[tid] = x; __syncthreads();
  for (int s = 256; s > 0; s >>= 1) { if (tid < s) sm[tid] += sm[tid+s]; __syncthreads(); }
  const float inv = 1.f / sm[0];
  if (tid < S_LEN) wat[b*S_LEN+tid] = x * inv;
}

__global__ __launch_bounds__(128) void k_ctx(const float* __restrict__ wat,
    const float* __restrict__ enc, float* __restrict__ ctx)
{
  const int b = blockIdx.y;
  const int j = blockIdx.x*128 + threadIdx.x;
  float acc = 0.f;
  const float* w = wat + b*S_LEN;
  const float* ep = enc + (size_t)b*S_LEN*1024 + j;
  #pragma unroll 4
  for (int s = 0; s < S_LEN; ++s) acc += w[s] * ep[(size_t)s*1024];
  ctx[(size_t)b*1024 + j] = acc;
}

__global__ __launch_bounds__(128) void k_yout(const float* __restrict__ dec,
    const float* __restrict__ ctx, const float* __restrict__ fc_W,
    const float* __restrict__ fc_b, float* __restrict__ y_out)
{
  const int b = blockIdx.y;
  const int j = blockIdx.x*128 + threadIdx.x;
  float acc = fc_b[j];
  const float* d = dec + (size_t)b*512;
  const float* c = ctx + (size_t)b*1024;
  #pragma unroll 4
  for (int k = 0; k < 512; ++k)  acc += d[k]*fc_W[(size_t)k*512 + j];
  #pragma unroll 4
  for (int k = 0; k < 1024; ++k) acc += c[k]*fc_W[(size_t)(512+k)*512 + j];
  y_out[(size_t)b*512 + j] = acc;
}

__global__ __launch_bounds__(256) void k_pgen(const float* __restrict__ ctx,
    const float* __restrict__ dec, const float* __restrict__ yemb,
    const float* __restrict__ pg_Wh, const float* __restrict__ pg_Ws,
    const float* __restrict__ pg_Wx, const float* __restrict__ pg_b,
    float* __restrict__ pg)
{
  const int b = blockIdx.x, tid = threadIdx.x;
  __shared__ float sm[256];
  float acc = 0.f;
  for (int k = tid; k < 1024; k += 256) acc += ctx[(size_t)b*1024+k]*pg_Wh[k];
  for (int k = tid; k < 512;  k += 256) acc += dec[(size_t)b*512+k]*pg_Ws[k] + yemb[(size_t)b*512+k]*pg_Wx[k];
  sm[tid] = acc; __syncthreads();
  for (int s = 128; s > 0; s >>= 1) { if (tid < s) sm[tid] += sm[tid+s]; __syncthreads(); }
  if (tid == 0) pg[b] = sigf(sm[0] + pg_b[0]);
}

__global__ __launch_bounds__(256) void k_vocab(const float* __restrict__ y_out,
    const float* __restrict__ vocab_W, float* __restrict__ logits)
{
  __shared__ float y_lds[256][32];   // [k][b], one k-half at a time (32 KB)
  const int tid = threadIdx.x;
  const int vq = tid & 63, bq = tid >> 6;
  const int v = blockIdx.x * 256 + vq * 4;
  float acc[8][4];
  #pragma unroll
  for (int i = 0; i < 8; ++i)
    #pragma unroll
    for (int j = 0; j < 4; ++j) acc[i][j] = 0.f;
  for (int half = 0; half < 2; ++half) {
    __syncthreads();
    for (int i = 0; i < 32; ++i) {
      const int idx = tid + 256*i;
      const int k = idx >> 5, b = idx & 31;
      y_lds[k][b] = y_out[(size_t)b*512 + half*256 + k];
    }
    __syncthreads();
    if (v < VOC) {
      #pragma unroll 4
      for (int k = 0; k < 256; ++k) {
        const float4 wv = *(const float4*)&vocab_W[(size_t)(half*256 + k) * VOC + v];
        const float4 ya = *(const float4*)&y_lds[k][bq*8];
        const float4 yb = *(const float4*)&y_lds[k][bq*8+4];
        const float yy[8] = {ya.x,ya.y,ya.z,ya.w,yb.x,yb.y,yb.z,yb.w};
        #pragma unroll
        for (int i = 0; i < 8; ++i) {
          acc[i][0] += yy[i]*wv.x; acc[i][1] += yy[i]*wv.y;
          acc[i][2] += yy[i]*wv.z; acc[i][3] += yy[i]*wv.w;
        }
      }
    }
  }
  if (v < VOC) {
    #pragma unroll
    for (int i = 0; i < 8; ++i)
      *(float4*)&logits[(size_t)(bq*8+i)*VOC + v] = make_float4(acc[i][0],acc[i][1],acc[i][2],acc[i][3]);
  }
}

__global__ __launch_bounds__(1024) void k_vred(const float* __restrict__ logits,
                                               float* __restrict__ red2)
{
  const int b = blockIdx.x, tid = threadIdx.x;
  __shared__ float sm[1024];
  float m = -1e30f;
  for (int i = tid; i < VOC; i += 1024) m = fmaxf(m, logits[(size_t)b*VOC + i]);
  sm[tid] = m; __syncthreads();
  for (int s = 512; s > 0; s >>= 1) { if (tid < s) sm[tid] = fmaxf(sm[tid], sm[tid+s]); __syncthreads(); }
  m = sm[0]; __syncthreads();
  float sum = 0.f;
  for (int i = tid; i < VOC; i += 1024) sum += __expf(logits[(size_t)b*VOC + i] - m);
  sm[tid] = sum; __syncthreads();
  for (int s = 512; s > 0; s >>= 1) { if (tid < s) sm[tid] += sm[tid+s]; __syncthreads(); }
  if (tid == 0) { red2[b*2] = m; red2[b*2+1] = sm[0]; }
}

__global__ __launch_bounds__(256) void k_final(const float* __restrict__ logits,
    const float* __restrict__ red2, const float* __restrict__ pg,
    float* __restrict__ out)
{
  const size_t idx = (size_t)blockIdx.x*256 + threadIdx.x;
  const int b = (int)(idx / OUTW);
  const int c = (int)(idx - (size_t)b*OUTW);
  float v = 0.f;
  if (c < VOC) {
    const float m = red2[b*2], s = red2[b*2+1];
    v = pg[b] * __expf(logits[(size_t)b*VOC + c] - m) / s;
  }
  out[idx] = v;
}

__global__ __launch_bounds__(256) void k_scatter(const float* __restrict__ wat,
    const int* __restrict__ x_mask, const float* __restrict__ pg,
    const int* __restrict__ x_id, float* __restrict__ out)
{
  const int i = blockIdx.x*256 + threadIdx.x;   // < 12800
  const int b = i / S_LEN;
  const float aw = wat[i] * (1.f - (float)x_mask[i]) * (1.f - pg[b]);
  atomicAdd(out + (size_t)b*OUTW + x_id[i], aw);
}

// ---------------------------------------------------------------------------
extern "C" void kernel_launch(void* const* d_in, const int* in_sizes, int n_in,
                              void* d_out, int out_size, void* d_ws, size_t ws_size,
                              hipStream_t stream)
{
  (void)in_sizes; (void)n_in; (void)out_size; (void)ws_size;
  const int*   x_id     = (const int*)d_in[0];
  const int*   y_id     = (const int*)d_in[1];
  const int*   x_mask   = (const int*)d_in[2];
  const float* emb      = (const float*)d_in[3];
  const float* enc_fw_W = (const float*)d_in[4];
  const float* enc_fw_U = (const float*)d_in[5];
  const float* enc_fw_b = (const float*)d_in[6];
  const float* enc_bw_W = (const float*)d_in[7];
  const float* enc_bw_U = (const float*)d_in[8];
  const float* enc_bw_b = (const float*)d_in[9];
  const float* red_W    = (const float*)d_in[10];
  const float* red_b    = (const float*)d_in[11];
  const float* dec_W    = (const float*)d_in[12];
  const float* dec_U    = (const float*)d_in[13];
  const float* dec_b    = (const float*)d_in[14];
  const float* att_Wh   = (const float*)d_in[15];
  const float* att_Ws   = (const float*)d_in[16];
  const float* att_bs   = (const float*)d_in[17];
  const float* att_Wc   = (const float*)d_in[18]; (void)att_Wc; // cover == 0
  const float* att_V    = (const float*)d_in[19];
  const float* fc_W     = (const float*)d_in[20];
  const float* fc_b     = (const float*)d_in[21];
  const float* vocab_W  = (const float*)d_in[22];
  const float* pg_Wh    = (const float*)d_in[23];
  const float* pg_Ws    = (const float*)d_in[24];
  const float* pg_Wx    = (const float*)d_in[25];
  const float* pg_b     = (const float*)d_in[26];
  float* out = (float*)d_out;

  const size_t NPKT = (size_t)2*2*BATCH*HID;            // [dir][parity][b][j]
  char* p = (char*)d_ws;
  ushort* xzm   = (ushort*)p; p += (size_t)BATCH*S_LEN*N2*2;     // 78.6 MB
  float*  enc   = (float*)p;  p += (size_t)BATCH*S_LEN*1024*4;   // 52.4 MB
  ushort* encbf = (ushort*)p; p += (size_t)BATCH*S_LEN*1024*2;   // 26.2 MB
  ull*   hpkt   = (ull*)p;    p += NPKT*8;                       // 1 MB
  ushort* Abf   = (ushort*)p; p += (size_t)BATCH*S_LEN*512*2;    // 13.1 MB
  ushort* Wt    = (ushort*)p; p += (size_t)N2*512*2;             // 3.1 MB
  ushort* Whbf  = (ushort*)p; p += (size_t)512*1024*2;           // 1.0 MB
  ushort* Utbf  = (ushort*)p; p += (size_t)2*G3*512*2;           // 3.1 MB
  float*  bm    = (float*)p;  p += (size_t)N2*4;
  float*  fstate = (float*)p; p += (size_t)BATCH*HID*4;
  float*  yemb   = (float*)p; p += (size_t)BATCH*HID*4;
  float*  decs   = (float*)p; p += (size_t)BATCH*HID*4;
  float*  dterm  = (float*)p; p += (size_t)BATCH*HID*4;
  float*  epart  = (float*)p; p += (size_t)BATCH*S_LEN*4*4;
  float*  wat    = (float*)p; p += (size_t)BATCH*S_LEN*4;
  float*  ctx    = (float*)p; p += (size_t)BATCH*1024*4;
  float*  yout   = (float*)p; p += (size_t)BATCH*HID*4;
  float*  pg     = (float*)p; p += (size_t)256*4;
  float*  logits = (float*)p; p += (size_t)BATCH*VOC*4;          // 6.4 MB
  float*  red2   = (float*)p; p += (size_t)64*4;

  // zero the packet buffer: {0.0f, tag 0} == valid h(0) for every slot
  hipMemsetAsync(hpkt, 0, NPKT * sizeof(ull), stream);

  // bf16 conversions: embedding gather; W, att_Wh, U transposes
  k_cvtA<<<BATCH*S_LEN/4, 256, 0, stream>>>(x_id, emb, Abf);
  k_transW<<<dim3(512/64, N2/64), 256, 0, stream>>>(
      enc_fw_W, enc_bw_W, G3, G3, 512, Wt, enc_fw_b, enc_bw_b, bm);
  k_transW<<<dim3(1024/64, 512/64), 256, 0, stream>>>(
      att_Wh, att_Wh, 512, 512, 1024, Whbf, nullptr, nullptr, nullptr);
  k_transW<<<dim3(512/64, G3/64), 256, 0, stream>>>(
      enc_fw_U, enc_fw_U, G3, G3, 512, Utbf, nullptr, nullptr, nullptr);
  k_transW<<<dim3(512/64, G3/64), 256, 0, stream>>>(
      enc_bw_U, enc_bw_U, G3, G3, 512, Utbf + (size_t)G3*512, nullptr, nullptr, nullptr);
  // merged input projection (bf16 MFMA): xz = A @ [Wfw|Wbw] + [bfw0|bbw0]
  gemm_bf16<<<dim3(N2/128, BATCH*S_LEN/128), 256, 0, stream>>>(Abf, Wt, bm, xzm);
  // persistent bidirectional GRU scan (tagged packets + MFMA matvec)
  gru_scan<<<256,512,0,stream>>>(xzm, Utbf, enc_fw_b, enc_bw_b,
                                 enc, encbf, hpkt);
  // reduce state + decoder step + attention query term
  k_state<<<dim3(4,32),128,0,stream>>>(enc, red_W, red_b, fstate);
  k_yemb<<<32,256,0,stream>>>(y_id, emb, yemb);
  k_dec<<<dim3(4,32),128,0,stream>>>(yemb, fstate, dec_W, dec_U, dec_b, decs);
  k_dterm<<<dim3(4,32),128,0,stream>>>(decs, att_Ws, att_bs, dterm);
  // attention scores (bf16 MFMA + fused tanh * att_V reduction)
  gemm_att<<<dim3(4, BATCH*S_LEN/128), 256, 0, stream>>>(encbf, Whbf, dterm,
                                                         att_V, epart);
  k_soft<<<32,512,0,stream>>>(epart, x_mask, wat);
  k_ctx<<<dim3(8,32),128,0,stream>>>(wat, enc, ctx);
  k_yout<<<dim3(4,32),128,0,stream>>>(decs, ctx, fc_W, fc_b, yout);
  k_pgen<<<32,256,0,stream>>>(ctx, decs, yemb, pg_Wh, pg_Ws, pg_Wx, pg_b, pg);
  // vocab distribution + final assembly
  k_vocab<<<196,256,0,stream>>>(yout, vocab_W, logits);
  k_vred<<<32,1024,0,stream>>>(logits, red2);
  k_final<<<6300,256,0,stream>>>(logits, red2, pg, out);
  k_scatter<<<50,256,0,stream>>>(wat, x_mask, pg, x_id, out);
}

// Round 12
// 1397.422 us; speedup vs baseline: 5.4424x; 1.2002x over previous
//
#include <hip/hip_runtime.h>
#include <math.h>

#define S_LEN 400
#define BATCH 32
#define HID   512
#define G3    1536
#define N2    3072
#define VOC   50000
#define OUTW  (VOC + S_LEN)

typedef unsigned long long ull;
typedef unsigned int uint;
typedef unsigned short ushort;
typedef short bf16x8 __attribute__((ext_vector_type(8)));
typedef float f32x4 __attribute__((ext_vector_type(4)));
typedef ushort u16x8 __attribute__((ext_vector_type(8)));

__device__ __forceinline__ float sigf(float x) { return 1.f / (1.f + __expf(-x)); }
__device__ __forceinline__ float tanh_fast(float x) {
  const float xc = fminf(fmaxf(x, -15.f), 15.f);
  const float e = __expf(-2.f * xc);
  return (1.f - e) / (1.f + e);
}
__device__ __forceinline__ ushort f2bf(float f) {       // RNE fp32 -> bf16
  uint u = __float_as_uint(f);
  u += 0x7FFFu + ((u >> 16) & 1u);
  return (ushort)(u >> 16);
}
__device__ __forceinline__ float bf2f(ushort h) {
  return __uint_as_float((uint)h << 16);
}
__device__ __forceinline__ float dot4(float4 a, float4 b) {
  return a.x*b.x + a.y*b.y + a.z*b.z + a.w*b.w;
}

// ---------------------------------------------------------------------------
// Persistent bidirectional GRU scan — tagged-packet sync + MFMA matvec.
// 128 blocks x 512 thr. group = bid&7 (dir=group>>2, bg=group&3), ht=bid>>3
// (0..15, 32 j's per block). h moves as tagged 8B {fp32, step} packets via
// relaxed agent atomics (LLC); tags are the sole source of truth (monotone
// t->t+2). Narrower groups (16 producers) shrink the per-step straggler max.
// Waves 0-5 run the matvec as MFMA 16x16x32 bf16: wave (gate=w%3, jh=w/3)
// covers 16 j's over full K=512 (16 MFMA steps, U fragments in registers).
// Gate phase (tid<256) reads fp32 h_old from its OWN packet (polled jointly),
// so h storage precision stays fp32.
// ---------------------------------------------------------------------------
__global__ __launch_bounds__(512) void gru_scan(
    const ushort* __restrict__ xzm,           // [32*400][3072] bf16 fw|bw
    const ushort* __restrict__ Utbf,          // [2][1536][512] bf16 (U^T)
    const float* __restrict__ bfw, const float* __restrict__ bbw,
    float* __restrict__ enc_seq, ushort* __restrict__ enc_bf,
    ull* __restrict__ hpkt)
{
  const int bid = blockIdx.x;        // 0..127
  const int group = bid & 7;
  const int dir = group >> 2;
  const int bg  = group & 3;
  const int ht  = bid >> 3;          // 0..15: j-tile of 32
  const int tid = threadIdx.x;
  const int lane = tid & 63;
  const int w  = tid >> 6;           // wave 0..7
  const int l15 = lane & 15;
  const int lk  = lane >> 4;

  const float* __restrict__ br = (dir ? bbw : bfw) + G3;   // bias row 1

  // U fragments in registers (waves 0..5): gate = w%3, jh = w/3 (16 j's).
  const int gate = w % 3, jh = w / 3;
  bf16x8 ufrag[16];
  if (w < 6) {
    const ushort* ub = Utbf + ((size_t)dir * G3 + gate * 512 + ht * 32 + jh * 16 + l15) * 512
                     + lk * 8;
    #pragma unroll
    for (int s = 0; s < 16; ++s)
      ufrag[s] = *(const bf16x8*)(ub + s * 32);
  }

  __shared__ ushort h_bf[16][520];       // bf16 h, rows 8-15 zero (16.6 KB)
  __shared__ float redm[3][8][32];       // [gate][batch][j32] (3 KB)

  // zero h_bf once (rows 8-15 stay zero forever)
  for (int i = tid; i < 16 * 520; i += 512) ((ushort*)h_bf)[i] = 0;

  // consumer mapping: wave w = batch-in-group
  const int cb = w;
  // gate/producer mapping (threads 0..255)
  const int gbi = tid >> 5;              // 0..7 for tid<256
  const int gj  = tid & 31;
  const int gjq = ht * 32 + gj;
  const int gb  = bg * 8 + (gbi & 7);
  const float brz = br[gjq], brr = br[512 + gjq], brh = br[1024 + gjq];

  ull* __restrict__ pk = hpkt + (size_t)dir * (2 * BATCH * HID);   // [parity][b][j]
  __syncthreads();   // h_bf zero visible

  for (int t = 0; t < S_LEN; ++t) {
    const int ts = dir ? (S_LEN - 1 - t) : t;

    // xz prefetch (bf16, independent of h; overlaps the poll)
    float xzv0 = 0.f, xzv1 = 0.f, xzv2 = 0.f;
    if (tid < 256) {
      const ushort* xp = xzm + ((size_t)gb * S_LEN + ts) * N2 + dir * G3 + gjq;
      xzv0 = bf2f(xp[0]); xzv1 = bf2f(xp[512]); xzv2 = bf2f(xp[1024]);
    }

    // ---- consume h(t): coalesced tagged poll (+ own fp32 hold, tid<256) ----
    float hold = 0.f;
    {
      ull* bp = pk + ((size_t)(t & 1) * BATCH + (bg * 8 + cb)) * HID + lane;
      ull* hp = pk + ((size_t)(t & 1) * BATCH + gb) * HID + gjq;
      const uint tu = (uint)t;
      for (;;) {
        ull v0 = __hip_atomic_load(bp,       __ATOMIC_RELAXED, __HIP_MEMORY_SCOPE_AGENT);
        ull v1 = __hip_atomic_load(bp + 64,  __ATOMIC_RELAXED, __HIP_MEMORY_SCOPE_AGENT);
        ull v2 = __hip_atomic_load(bp + 128, __ATOMIC_RELAXED, __HIP_MEMORY_SCOPE_AGENT);
        ull v3 = __hip_atomic_load(bp + 192, __ATOMIC_RELAXED, __HIP_MEMORY_SCOPE_AGENT);
        ull v4 = __hip_atomic_load(bp + 256, __ATOMIC_RELAXED, __HIP_MEMORY_SCOPE_AGENT);
        ull v5 = __hip_atomic_load(bp + 320, __ATOMIC_RELAXED, __HIP_MEMORY_SCOPE_AGENT);
        ull v6 = __hip_atomic_load(bp + 384, __ATOMIC_RELAXED, __HIP_MEMORY_SCOPE_AGENT);
        ull v7 = __hip_atomic_load(bp + 448, __ATOMIC_RELAXED, __HIP_MEMORY_SCOPE_AGENT);
        bool ok = ((uint)(v0 >> 32) == tu) & ((uint)(v1 >> 32) == tu)
                & ((uint)(v2 >> 32) == tu) & ((uint)(v3 >> 32) == tu)
                & ((uint)(v4 >> 32) == tu) & ((uint)(v5 >> 32) == tu)
                & ((uint)(v6 >> 32) == tu) & ((uint)(v7 >> 32) == tu);
        ull hv = 0;
        if (tid < 256) {
          hv = __hip_atomic_load(hp, __ATOMIC_RELAXED, __HIP_MEMORY_SCOPE_AGENT);
          ok &= ((uint)(hv >> 32) == tu);
        }
        if (__all(ok)) {
          h_bf[cb][lane]       = f2bf(__uint_as_float((uint)v0));
          h_bf[cb][lane + 64]  = f2bf(__uint_as_float((uint)v1));
          h_bf[cb][lane + 128] = f2bf(__uint_as_float((uint)v2));
          h_bf[cb][lane + 192] = f2bf(__uint_as_float((uint)v3));
          h_bf[cb][lane + 256] = f2bf(__uint_as_float((uint)v4));
          h_bf[cb][lane + 320] = f2bf(__uint_as_float((uint)v5));
          h_bf[cb][lane + 384] = f2bf(__uint_as_float((uint)v6));
          h_bf[cb][lane + 448] = f2bf(__uint_as_float((uint)v7));
          if (tid < 256) hold = __uint_as_float((uint)hv);
          break;
        }
        __builtin_amdgcn_s_sleep(1);
      }
    }
    __syncthreads();   // S1: h_bf ready

    // ---- recurrent matvec: MFMA 16x16x32 bf16, waves 0..5, full K ----
    if (w < 6) {
      f32x4 acc = f32x4{0.f, 0.f, 0.f, 0.f};
      #pragma unroll
      for (int s = 0; s < 16; ++s) {
        const bf16x8 af = *(const bf16x8*)&h_bf[l15][s * 32 + lk * 8];
        acc = __builtin_amdgcn_mfma_f32_16x16x32_bf16(af, ufrag[s], acc, 0, 0, 0);
      }
      if (lk < 2) {   // rows 0..7 = real batches
        #pragma unroll
        for (int r = 0; r < 4; ++r)
          redm[gate][lk * 4 + r][jh * 16 + l15] = acc[r];
      }
    }
    __syncthreads();   // S2: redm ready

    // ---- gates + publish h(t+1) ----
    if (tid < 256) {
      const float rz = redm[0][gbi][gj] + brz;
      const float rr = redm[1][gbi][gj] + brr;
      const float rh = redm[2][gbi][gj] + brh;
      const float z  = sigf(xzv0 + rz);
      const float r  = sigf(xzv1 + rr);
      const float hh = tanh_fast(xzv2 + r * rh);
      const float hnew = z * hold + (1.f - z) * hh;
      const ull pack = ((ull)(uint)(t + 1) << 32) | (ull)__float_as_uint(hnew);
      __hip_atomic_store(pk + ((size_t)((t + 1) & 1) * BATCH + gb) * HID + gjq,
                         pack, __ATOMIC_RELAXED, __HIP_MEMORY_SCOPE_AGENT);
      const size_t eidx = ((size_t)gb * S_LEN + ts) * 1024 + dir * 512 + gjq;
      enc_seq[eidx] = hnew;
      enc_bf[eidx]  = f2bf(hnew);
    }
    __syncthreads();   // S3: publishes issued; h_bf/redm safe for next fill
  }
}

// ---------------------------------------------------------------------------
// Tiled transpose + bf16 convert: dst[n][k] = bf16(src[k][n]).
// src split column-wise at `split` between srcA|srcB (row stride srcStride).
// Optional bias merge on the k0==0 tile row. grid: (K/64, N/64), 256 thr.
// ---------------------------------------------------------------------------
__global__ __launch_bounds__(256) void k_transW(
    const float* __restrict__ srcA, const float* __restrict__ srcB,
    const int split, const int srcStride, const int Krows,
    ushort* __restrict__ dst,
    const float* __restrict__ biasA, const float* __restrict__ biasB,
    float* __restrict__ bm)
{
  __shared__ float t[64][65];
  const int k0 = blockIdx.x * 64, n0 = blockIdx.y * 64;
  const int tid = threadIdx.x;
  const int j = tid & 63, i0 = tid >> 6;
  {
    const int n = n0 + j;
    const float* s = (n < split) ? (srcA + n) : (srcB + (n - split));
    #pragma unroll
    for (int i = i0; i < 64; i += 4)
      t[i][j] = s[(size_t)(k0 + i) * srcStride];
  }
  __syncthreads();
  const int ii = tid & 63;
  #pragma unroll
  for (int jj = i0; jj < 64; jj += 4)
    dst[(size_t)(n0 + jj) * Krows + k0 + ii] = f2bf(t[ii][jj]);
  if (bm != nullptr && k0 == 0 && tid < 64) {
    const int n = n0 + tid;
    bm[n] = (n < split) ? biasA[n] : biasB[n - split];
  }
}

// ---------------------------------------------------------------------------
// Tiled fp32 transpose: dst[n][k] = src[k][n], same split convention.
// ---------------------------------------------------------------------------
__global__ __launch_bounds__(256) void k_transF(
    const float* __restrict__ srcA, const float* __restrict__ srcB,
    const int split, const int srcStride, const int Krows,
    float* __restrict__ dst)
{
  __shared__ float t[64][65];
  const int k0 = blockIdx.x * 64, n0 = blockIdx.y * 64;
  const int tid = threadIdx.x;
  const int j = tid & 63, i0 = tid >> 6;
  {
    const int n = n0 + j;
    const float* s = (n < split) ? (srcA + n) : (srcB + (n - split));
    #pragma unroll
    for (int i = i0; i < 64; i += 4)
      t[i][j] = s[(size_t)(k0 + i) * srcStride];
  }
  __syncthreads();
  const int ii = tid & 63;
  #pragma unroll
  for (int jj = i0; jj < 64; jj += 4)
    dst[(size_t)(n0 + jj) * Krows + k0 + ii] = t[ii][jj];
}

// ---------------------------------------------------------------------------
// bf16 MFMA GEMM with fused embedding gather:
// C[12800][3072] = bf16(emb[x_id[m]]) @ Wt^T + bm, C in bf16.
// 128x128 tile, 256 thr (4 waves), 16x16x32 bf16 MFMA, fp32 accum.
// ---------------------------------------------------------------------------
__global__ __launch_bounds__(256) void gemm_bf16(
    const int* __restrict__ x_id, const float* __restrict__ emb,
    const ushort* __restrict__ Bt,   // [N][512] bf16 (row n = W col n)
    const float* __restrict__ bias,  // [N] fp32
    ushort* __restrict__ C)          // [M][3072] bf16
{
  const int m0 = blockIdx.y * 128, n0 = blockIdx.x * 128;
  const int tid = threadIdx.x;
  const int w = tid >> 6, lane = tid & 63;
  const int l15 = lane & 15, lk = lane >> 4;
  __shared__ short As[128][40];      // +8 pad: row stride 80B (16B-aligned)
  __shared__ short Bs[128][40];
  __shared__ int rid[128];
  if (tid < 128) rid[tid] = x_id[m0 + tid];
  f32x4 acc[2][8];
  #pragma unroll
  for (int i = 0; i < 2; ++i)
    #pragma unroll
    for (int j = 0; j < 8; ++j) acc[i][j] = f32x4{0.f, 0.f, 0.f, 0.f};

  const int sr = tid >> 1;           // stage row 0..127
  const int sc = (tid & 1) * 8;      // k-offset 0 or 8
  __syncthreads();
  const float* arow = emb + (size_t)rid[sr] * 512;

  for (int k0 = 0; k0 < 512; k0 += 32) {
    const float4 f0 = *(const float4*)(arow + k0 + sc);
    const float4 f1 = *(const float4*)(arow + k0 + sc + 4);
    const float4 f2 = *(const float4*)(arow + k0 + 16 + sc);
    const float4 f3 = *(const float4*)(arow + k0 + 16 + sc + 4);
    const uint4 b0 = *(const uint4*)&Bt[(size_t)(n0 + sr) * 512 + k0 + sc];
    const uint4 b1 = *(const uint4*)&Bt[(size_t)(n0 + sr) * 512 + k0 + 16 + sc];
    u16x8 a0, a1;
    a0[0]=f2bf(f0.x); a0[1]=f2bf(f0.y); a0[2]=f2bf(f0.z); a0[3]=f2bf(f0.w);
    a0[4]=f2bf(f1.x); a0[5]=f2bf(f1.y); a0[6]=f2bf(f1.z); a0[7]=f2bf(f1.w);
    a1[0]=f2bf(f2.x); a1[1]=f2bf(f2.y); a1[2]=f2bf(f2.z); a1[3]=f2bf(f2.w);
    a1[4]=f2bf(f3.x); a1[5]=f2bf(f3.y); a1[6]=f2bf(f3.z); a1[7]=f2bf(f3.w);
    *(u16x8*)&As[sr][sc]      = a0;
    *(u16x8*)&As[sr][16 + sc] = a1;
    *(uint4*)&Bs[sr][sc]      = b0;
    *(uint4*)&Bs[sr][16 + sc] = b1;
    __syncthreads();

    bf16x8 af[2], bfr[8];
    #pragma unroll
    for (int rf = 0; rf < 2; ++rf)
      af[rf] = *(const bf16x8*)&As[w * 32 + rf * 16 + l15][lk * 8];
    #pragma unroll
    for (int cf = 0; cf < 8; ++cf)
      bfr[cf] = *(const bf16x8*)&Bs[cf * 16 + l15][lk * 8];
    #pragma unroll
    for (int rf = 0; rf < 2; ++rf)
      #pragma unroll
      for (int cf = 0; cf < 8; ++cf)
        acc[rf][cf] = __builtin_amdgcn_mfma_f32_16x16x32_bf16(
            af[rf], bfr[cf], acc[rf][cf], 0, 0, 0);
    __syncthreads();
  }

  #pragma unroll
  for (int rf = 0; rf < 2; ++rf) {
    #pragma unroll
    for (int cf = 0; cf < 8; ++cf) {
      const int col = n0 + cf * 16 + l15;
      const float bv = bias[col];
      const int rowb = m0 + w * 32 + rf * 16 + lk * 4;
      #pragma unroll
      for (int r = 0; r < 4; ++r)
        C[(size_t)(rowb + r) * N2 + col] = f2bf(acc[rf][cf][r] + bv);
    }
  }
}

// ---------------------------------------------------------------------------
// bf16 MFMA attention-score GEMM with fused epilogue:
// e_part[row][bx] = sum_n attV[n] * tanh(enc_bf[row]@Wh[:,n] + dterm[b][n])
// ---------------------------------------------------------------------------
__global__ __launch_bounds__(256) void gemm_att(
    const ushort* __restrict__ A,    // [12800][1024] bf16
    const ushort* __restrict__ Bt,   // [512][1024] bf16
    const float* __restrict__ dterm, // [32][512] fp32
    const float* __restrict__ attV,  // [512] fp32
    float* __restrict__ e_part)      // [12800][4]
{
  const int m0 = blockIdx.y * 128, n0 = blockIdx.x * 128;
  const int tid = threadIdx.x;
  const int w = tid >> 6, lane = tid & 63;
  const int l15 = lane & 15, lk = lane >> 4;
  __shared__ short As[128][40];
  __shared__ short Bs[128][40];
  f32x4 acc[2][8];
  #pragma unroll
  for (int i = 0; i < 2; ++i)
    #pragma unroll
    for (int j = 0; j < 8; ++j) acc[i][j] = f32x4{0.f, 0.f, 0.f, 0.f};

  const int sr = tid >> 1;
  const int sc = (tid & 1) * 8;

  for (int k0 = 0; k0 < 1024; k0 += 32) {
    const uint4 a0 = *(const uint4*)&A[(size_t)(m0 + sr) * 1024 + k0 + sc];
    const uint4 a1 = *(const uint4*)&A[(size_t)(m0 + sr) * 1024 + k0 + 16 + sc];
    const uint4 b0 = *(const uint4*)&Bt[(size_t)(n0 + sr) * 1024 + k0 + sc];
    const uint4 b1 = *(const uint4*)&Bt[(size_t)(n0 + sr) * 1024 + k0 + 16 + sc];
    *(uint4*)&As[sr][sc]      = a0;
    *(uint4*)&As[sr][16 + sc] = a1;
    *(uint4*)&Bs[sr][sc]      = b0;
    *(uint4*)&Bs[sr][16 + sc] = b1;
    __syncthreads();

    bf16x8 af[2], bfr[8];
    #pragma unroll
    for (int rf = 0; rf < 2; ++rf)
      af[rf] = *(const bf16x8*)&As[w * 32 + rf * 16 + l15][lk * 8];
    #pragma unroll
    for (int cf = 0; cf < 8; ++cf)
      bfr[cf] = *(const bf16x8*)&Bs[cf * 16 + l15][lk * 8];
    #pragma unroll
    for (int rf = 0; rf < 2; ++rf)
      #pragma unroll
      for (int cf = 0; cf < 8; ++cf)
        acc[rf][cf] = __builtin_amdgcn_mfma_f32_16x16x32_bf16(
            af[rf], bfr[cf], acc[rf][cf], 0, 0, 0);
    __syncthreads();
  }

  #pragma unroll
  for (int rf = 0; rf < 2; ++rf) {
    #pragma unroll
    for (int r = 0; r < 4; ++r) {
      const int row = m0 + w * 32 + rf * 16 + lk * 4 + r;
      const int b = row / S_LEN;
      float p = 0.f;
      #pragma unroll
      for (int cf = 0; cf < 8; ++cf) {
        const int col = n0 + cf * 16 + l15;
        p += attV[col] * tanh_fast(acc[rf][cf][r] + dterm[(size_t)b * 512 + col]);
      }
      p += __shfl_xor(p, 1); p += __shfl_xor(p, 2);
      p += __shfl_xor(p, 4); p += __shfl_xor(p, 8);
      if (l15 == 0) e_part[(size_t)row * 4 + blockIdx.x] = p;
    }
  }
}

// --------------------------- small kernels (transposed weights) ------------
__global__ __launch_bounds__(128) void k_state(const float* __restrict__ enc,
    const float* __restrict__ redWt,  // [512][1024] fp32: row j = red_W col j
    const float* __restrict__ red_b, float* __restrict__ state)
{
  const int b = blockIdx.y;
  const int j = blockIdx.x*128 + threadIdx.x;
  const float4* wr = (const float4*)(redWt + (size_t)j * 1024);
  const float4* fw = (const float4*)(enc + ((size_t)b*S_LEN + (S_LEN-1))*1024);
  const float4* bw = (const float4*)(enc + ((size_t)b*S_LEN)*1024 + 512);
  float acc = red_b[j];
  #pragma unroll 4
  for (int k = 0; k < 128; ++k) acc += dot4(fw[k], wr[k]);
  #pragma unroll 4
  for (int k = 0; k < 128; ++k) acc += dot4(bw[k], wr[128 + k]);
  state[(size_t)b*512 + j] = fmaxf(acc, 0.f);
}

__global__ __launch_bounds__(128) void k_dec(
    const int* __restrict__ y_id, const float* __restrict__ emb,
    const float* __restrict__ state,
    const float* __restrict__ decWUt, // [3072][512]: rows 0-1535 decW^T, 1536+ decU^T
    const float* __restrict__ dec_b, float* __restrict__ dst)
{
  const int b = blockIdx.y;
  const int j = blockIdx.x*128 + threadIdx.x;
  const float4* ye = (const float4*)(emb + (size_t)y_id[b] * 512);
  const float4* st = (const float4*)(state + (size_t)b * 512);
  const float4* w0 = (const float4*)(decWUt + (size_t)(j)        * 512);
  const float4* w1 = (const float4*)(decWUt + (size_t)(512  + j) * 512);
  const float4* w2 = (const float4*)(decWUt + (size_t)(1024 + j) * 512);
  const float4* u0 = (const float4*)(decWUt + (size_t)(G3 + j)        * 512);
  const float4* u1 = (const float4*)(decWUt + (size_t)(G3 + 512  + j) * 512);
  const float4* u2 = (const float4*)(decWUt + (size_t)(G3 + 1024 + j) * 512);
  float xz0 = dec_b[j], xz1 = dec_b[512+j], xz2 = dec_b[1024+j];
  float rc0 = dec_b[G3+j], rc1 = dec_b[G3+512+j], rc2 = dec_b[G3+1024+j];
  #pragma unroll 2
  for (int k = 0; k < 128; ++k) {
    const float4 yv = ye[k], sv = st[k];
    xz0 += dot4(yv, w0[k]); xz1 += dot4(yv, w1[k]); xz2 += dot4(yv, w2[k]);
    rc0 += dot4(sv, u0[k]); rc1 += dot4(sv, u1[k]); rc2 += dot4(sv, u2[k]);
  }
  const float z  = sigf(xz0 + rc0);
  const float r  = sigf(xz1 + rc1);
  const float hh = tanh_fast(xz2 + r*rc2);
  const float sj = state[(size_t)b*512 + j];
  dst[(size_t)b*512 + j] = z*sj + (1.f-z)*hh;
}

__global__ __launch_bounds__(128) void k_dterm(const float* __restrict__ dec,
    const float* __restrict__ WsT,   // [512][512] fp32: row j = att_Ws col j
    const float* __restrict__ att_bs, float* __restrict__ dterm)
{
  const int b = blockIdx.y;
  const int j = blockIdx.x*128 + threadIdx.x;
  const float4* d = (const float4*)(dec + (size_t)b*512);
  const float4* wr = (const float4*)(WsT + (size_t)j * 512);
  float acc = att_bs[j];
  #pragma unroll 4
  for (int k = 0; k < 128; ++k) acc += dot4(d[k], wr[k]);
  dterm[(size_t)b*512 + j] = acc;
}

__global__ __launch_bounds__(512) void k_soft(const float* __restrict__ e_part,
    const int* __restrict__ x_mask, float* __restrict__ wat)
{
  const int b = blockIdx.x, tid = threadIdx.x;
  __shared__ float sm[512];
  float e = -1e30f, ev = 0.f;
  if (tid < S_LEN) {
    const float* ep = e_part + (size_t)(b*S_LEN + tid)*4;
    ev = ep[0]+ep[1]+ep[2]+ep[3] + (float)x_mask[b*S_LEN+tid] * -1e10f;
    e = ev;
  }
  sm[tid] = e; __syncthreads();
  for (int s = 256; s > 0; s >>= 1) { if (tid < s) sm[tid] = fmaxf(sm[tid], sm[tid+s]); __syncthreads(); }
  const float m = sm[0]; __syncthreads();
  const float x = (tid < S_LEN) ? __expf(ev - m) : 0.f;
  sm[tid] = x; __syncthreads();
  for (int s = 256; s > 0; s >>= 1) { if (tid < s) sm[tid] += sm[tid+s]; __syncthreads(); }
  const float inv = 1.f / sm[0];
  if (tid < S_LEN) wat[b*S_LEN+tid] = x * inv;
}

__global__ __launch_bounds__(128) void k_ctx(const float* __restrict__ wat,
    const float* __restrict__ enc, float* __restrict__ ctx)
{
  const int b = blockIdx.y;
  const int j = blockIdx.x*128 + threadIdx.x;
  float acc = 0.f;
  const float* w = wat + b*S_LEN;
  const float* ep = enc + (size_t)b*S_LEN*1024 + j;
  #pragma unroll 4
  for (int s = 0; s < S_LEN; ++s) acc += w[s] * ep[(size_t)s*1024];
  ctx[(size_t)b*1024 + j] = acc;
}

__global__ __launch_bounds__(128) void k_yout(const float* __restrict__ dec,
    const float* __restrict__ ctx,
    const float* __restrict__ fcT,   // [512][1536] fp32: row j = fc_W col j
    const float* __restrict__ fc_b, float* __restrict__ y_out)
{
  const int b = blockIdx.y;
  const int j = blockIdx.x*128 + threadIdx.x;
  const float4* d = (const float4*)(dec + (size_t)b*512);
  const float4* c = (const float4*)(ctx + (size_t)b*1024);
  const float4* wr = (const float4*)(fcT + (size_t)j * 1536);
  float acc = fc_b[j];
  #pragma unroll 4
  for (int k = 0; k < 128; ++k) acc += dot4(d[k], wr[k]);
  #pragma unroll 4
  for (int k = 0; k < 256; ++k) acc += dot4(c[k], wr[128 + k]);
  y_out[(size_t)b*512 + j] = acc;
}

__global__ __launch_bounds__(256) void k_pgen(const float* __restrict__ ctx,
    const float* __restrict__ dec,
    const int* __restrict__ y_id, const float* __restrict__ emb,
    const float* __restrict__ pg_Wh, const float* __restrict__ pg_Ws,
    const float* __restrict__ pg_Wx, const float* __restrict__ pg_b,
    float* __restrict__ pg)
{
  const int b = blockIdx.x, tid = threadIdx.x;
  __shared__ float sm[256];
  const float* ye = emb + (size_t)y_id[b] * 512;
  float acc = 0.f;
  for (int k = tid; k < 1024; k += 256) acc += ctx[(size_t)b*1024+k]*pg_Wh[k];
  for (int k = tid; k < 512;  k += 256) acc += dec[(size_t)b*512+k]*pg_Ws[k] + ye[k]*pg_Wx[k];
  sm[tid] = acc; __syncthreads();
  for (int s = 128; s > 0; s >>= 1) { if (tid < s) sm[tid] += sm[tid+s]; __syncthreads(); }
  if (tid == 0) pg[b] = sigf(sm[0] + pg_b[0]);
}

__global__ __launch_bounds__(256) void k_vocab(const float* __restrict__ y_out,
    const float* __restrict__ vocab_W, float* __restrict__ logits)
{
  __shared__ float y_lds[256][32];   // [k][b], one k-half at a time (32 KB)
  const int tid = threadIdx.x;
  const int vq = tid & 63, bq = tid >> 6;
  const int v = blockIdx.x * 256 + vq * 4;
  float acc[8][4];
  #pragma unroll
  for (int i = 0; i < 8; ++i)
    #pragma unroll
    for (int j = 0; j < 4; ++j) acc[i][j] = 0.f;
  for (int half = 0; half < 2; ++half) {
    __syncthreads();
    for (int i = 0; i < 32; ++i) {
      const int idx = tid + 256*i;
      const int k = idx >> 5, b = idx & 31;
      y_lds[k][b] = y_out[(size_t)b*512 + half*256 + k];
    }
    __syncthreads();
    if (v < VOC) {
      #pragma unroll 4
      for (int k = 0; k < 256; ++k) {
        const float4 wv = *(const float4*)&vocab_W[(size_t)(half*256 + k) * VOC + v];
        const float4 ya = *(const float4*)&y_lds[k][bq*8];
        const float4 yb = *(const float4*)&y_lds[k][bq*8+4];
        const float yy[8] = {ya.x,ya.y,ya.z,ya.w,yb.x,yb.y,yb.z,yb.w};
        #pragma unroll
        for (int i = 0; i < 8; ++i) {
          acc[i][0] += yy[i]*wv.x; acc[i][1] += yy[i]*wv.y;
          acc[i][2] += yy[i]*wv.z; acc[i][3] += yy[i]*wv.w;
        }
      }
    }
  }
  if (v < VOC) {
    #pragma unroll
    for (int i = 0; i < 8; ++i)
      *(float4*)&logits[(size_t)(bq*8+i)*VOC + v] = make_float4(acc[i][0],acc[i][1],acc[i][2],acc[i][3]);
  }
}

__global__ __launch_bounds__(1024) void k_vred(const float* __restrict__ logits,
                                               float* __restrict__ red2)
{
  const int b = blockIdx.x, tid = threadIdx.x;
  __shared__ float sm[1024];
  float m = -1e30f;
  for (int i = tid; i < VOC; i += 1024) m = fmaxf(m, logits[(size_t)b*VOC + i]);
  sm[tid] = m; __syncthreads();
  for (int s = 512; s > 0; s >>= 1) { if (tid < s) sm[tid] = fmaxf(sm[tid], sm[tid+s]); __syncthreads(); }
  m = sm[0]; __syncthreads();
  float sum = 0.f;
  for (int i = tid; i < VOC; i += 1024) sum += __expf(logits[(size_t)b*VOC + i] - m);
  sm[tid] = sum; __syncthreads();
  for (int s = 512; s > 0; s >>= 1) { if (tid < s) sm[tid] += sm[tid+s]; __syncthreads(); }
  if (tid == 0) { red2[b*2] = m; red2[b*2+1] = sm[0]; }
}

__global__ __launch_bounds__(256) void k_final(const float* __restrict__ logits,
    const float* __restrict__ red2, const float* __restrict__ pg,
    float* __restrict__ out)
{
  const size_t idx = (size_t)blockIdx.x*256 + threadIdx.x;
  const int b = (int)(idx / OUTW);
  const int c = (int)(idx - (size_t)b*OUTW);
  float v = 0.f;
  if (c < VOC) {
    const float m = red2[b*2], s = red2[b*2+1];
    v = pg[b] * __expf(logits[(size_t)b*VOC + c] - m) / s;
  }
  out[idx] = v;
}

__global__ __launch_bounds__(256) void k_scatter(const float* __restrict__ wat,
    const int* __restrict__ x_mask, const float* __restrict__ pg,
    const int* __restrict__ x_id, float* __restrict__ out)
{
  const int i = blockIdx.x*256 + threadIdx.x;   // < 12800
  const int b = i / S_LEN;
  const float aw = wat[i] * (1.f - (float)x_mask[i]) * (1.f - pg[b]);
  atomicAdd(out + (size_t)b*OUTW + x_id[i], aw);
}

// ---------------------------------------------------------------------------
extern "C" void kernel_launch(void* const* d_in, const int* in_sizes, int n_in,
                              void* d_out, int out_size, void* d_ws, size_t ws_size,
                              hipStream_t stream)
{
  (void)in_sizes; (void)n_in; (void)out_size; (void)ws_size;
  const int*   x_id     = (const int*)d_in[0];
  const int*   y_id     = (const int*)d_in[1];
  const int*   x_mask   = (const int*)d_in[2];
  const float* emb      = (const float*)d_in[3];
  const float* enc_fw_W = (const float*)d_in[4];
  const float* enc_fw_U = (const float*)d_in[5];
  const float* enc_fw_b = (const float*)d_in[6];
  const float* enc_bw_W = (const float*)d_in[7];
  const float* enc_bw_U = (const float*)d_in[8];
  const float* enc_bw_b = (const float*)d_in[9];
  const float* red_W    = (const float*)d_in[10];
  const float* red_b    = (const float*)d_in[11];
  const float* dec_W    = (const float*)d_in[12];
  const float* dec_U    = (const float*)d_in[13];
  const float* dec_b    = (const float*)d_in[14];
  const float* att_Wh   = (const float*)d_in[15];
  const float* att_Ws   = (const float*)d_in[16];
  const float* att_bs   = (const float*)d_in[17];
  const float* att_Wc   = (const float*)d_in[18]; (void)att_Wc; // cover == 0
  const float* att_V    = (const float*)d_in[19];
  const float* fc_W     = (const float*)d_in[20];
  const float* fc_b     = (const float*)d_in[21];
  const float* vocab_W  = (const float*)d_in[22];
  const float* pg_Wh    = (const float*)d_in[23];
  const float* pg_Ws    = (const float*)d_in[24];
  const float* pg_Wx    = (const float*)d_in[25];
  const float* pg_b     = (const float*)d_in[26];
  float* out = (float*)d_out;

  const size_t NPKT = (size_t)2*2*BATCH*HID;            // [dir][parity][b][j]
  char* p = (char*)d_ws;
  ushort* xzm   = (ushort*)p; p += (size_t)BATCH*S_LEN*N2*2;     // 78.6 MB
  float*  enc   = (float*)p;  p += (size_t)BATCH*S_LEN*1024*4;   // 52.4 MB
  ushort* encbf = (ushort*)p; p += (size_t)BATCH*S_LEN*1024*2;   // 26.2 MB
  ull*   hpkt   = (ull*)p;    p += NPKT*8;                       // 1 MB
  ushort* Wt    = (ushort*)p; p += (size_t)N2*512*2;             // 3.1 MB
  ushort* Whbf  = (ushort*)p; p += (size_t)512*1024*2;           // 1.0 MB
  ushort* Utbf  = (ushort*)p; p += (size_t)2*G3*512*2;           // 3.1 MB
  float*  redWt = (float*)p;  p += (size_t)512*1024*4;           // 2.1 MB
  float*  decWUt= (float*)p;  p += (size_t)N2*512*4;             // 6.3 MB
  float*  WsT   = (float*)p;  p += (size_t)512*512*4;            // 1.0 MB
  float*  fcT   = (float*)p;  p += (size_t)512*1536*4;           // 3.1 MB
  float*  bm    = (float*)p;  p += (size_t)N2*4;
  float*  fstate = (float*)p; p += (size_t)BATCH*HID*4;
  float*  decs   = (float*)p; p += (size_t)BATCH*HID*4;
  float*  dterm  = (float*)p; p += (size_t)BATCH*HID*4;
  float*  epart  = (float*)p; p += (size_t)BATCH*S_LEN*4*4;
  float*  wat    = (float*)p; p += (size_t)BATCH*S_LEN*4;
  float*  ctx    = (float*)p; p += (size_t)BATCH*1024*4;
  float*  yout   = (float*)p; p += (size_t)BATCH*HID*4;
  float*  pg     = (float*)p; p += (size_t)256*4;
  float*  logits = (float*)p; p += (size_t)BATCH*VOC*4;          // 6.4 MB
  float*  red2   = (float*)p; p += (size_t)64*4;

  // zero the packet buffer: {0.0f, tag 0} == valid h(0) for every slot
  hipMemsetAsync(hpkt, 0, NPKT * sizeof(ull), stream);

  // weight conversions/transposes (bf16 for MFMA paths, fp32 for matvec paths)
  k_transW<<<dim3(512/64, N2/64), 256, 0, stream>>>(
      enc_fw_W, enc_bw_W, G3, G3, 512, Wt, enc_fw_b, enc_bw_b, bm);
  k_transW<<<dim3(1024/64, 512/64), 256, 0, stream>>>(
      att_Wh, att_Wh, 512, 512, 1024, Whbf, nullptr, nullptr, nullptr);
  k_transW<<<dim3(512/64, G3/64), 256, 0, stream>>>(
      enc_fw_U, enc_fw_U, G3, G3, 512, Utbf, nullptr, nullptr, nullptr);
  k_transW<<<dim3(512/64, G3/64), 256, 0, stream>>>(
      enc_bw_U, enc_bw_U, G3, G3, 512, Utbf + (size_t)G3*512, nullptr, nullptr, nullptr);
  k_transF<<<dim3(1024/64, 512/64), 256, 0, stream>>>(
      red_W, red_W, 512, 512, 1024, redWt);
  k_transF<<<dim3(512/64, N2/64), 256, 0, stream>>>(
      dec_W, dec_U, G3, G3, 512, decWUt);
  k_transF<<<dim3(512/64, 512/64), 256, 0, stream>>>(
      att_Ws, att_Ws, 512, 512, 512, WsT);
  k_transF<<<dim3(1536/64, 512/64), 256, 0, stream>>>(
      fc_W, fc_W, 512, 512, 1536, fcT);
  // merged input projection (bf16 MFMA, fused embedding gather)
  gemm_bf16<<<dim3(N2/128, BATCH*S_LEN/128), 256, 0, stream>>>(x_id, emb, Wt, bm, xzm);
  // persistent bidirectional GRU scan (tagged packets + MFMA matvec)
  gru_scan<<<128,512,0,stream>>>(xzm, Utbf, enc_fw_b, enc_bw_b,
                                 enc, encbf, hpkt);
  // reduce state + decoder step + attention query term
  k_state<<<dim3(4,32),128,0,stream>>>(enc, redWt, red_b, fstate);
  k_dec<<<dim3(4,32),128,0,stream>>>(y_id, emb, fstate, decWUt, dec_b, decs);
  k_dterm<<<dim3(4,32),128,0,stream>>>(decs, WsT, att_bs, dterm);
  // attention scores (bf16 MFMA + fused tanh * att_V reduction)
  gemm_att<<<dim3(4, BATCH*S_LEN/128), 256, 0, stream>>>(encbf, Whbf, dterm,
                                                         att_V, epart);
  k_soft<<<32,512,0,stream>>>(epart, x_mask, wat);
  k_ctx<<<dim3(8,32),128,0,stream>>>(wat, enc, ctx);
  k_yout<<<dim3(4,32),128,0,stream>>>(decs, ctx, fcT, fc_b, yout);
  k_pgen<<<32,256,0,stream>>>(ctx, decs, y_id, emb, pg_Wh, pg_Ws, pg_Wx, pg_b, pg);
  // vocab distribution + final assembly
  k_vocab<<<196,256,0,stream>>>(yout, vocab_W, logits);
  k_vred<<<32,1024,0,stream>>>(logits, red2);
  k_final<<<6300,256,0,stream>>>(logits, red2, pg, out);
  k_scatter<<<50,256,0,stream>>>(wat, x_mask, pg, x_id, out);
}

// Round 13
// 1325.519 us; speedup vs baseline: 5.7377x; 1.0542x over previous
//
#include <hip/hip_runtime.h>
#include <math.h>

#define S_LEN 400
#define BATCH 32
#define HID   512
#define G3    1536
#define N2    3072
#define VOC   50000
#define OUTW  (VOC + S_LEN)

typedef unsigned long long ull;
typedef unsigned int uint;
typedef unsigned short ushort;
typedef short bf16x8 __attribute__((ext_vector_type(8)));
typedef float f32x4 __attribute__((ext_vector_type(4)));
typedef ushort u16x8 __attribute__((ext_vector_type(8)));

__device__ __forceinline__ float sigf(float x) { return 1.f / (1.f + __expf(-x)); }
__device__ __forceinline__ float tanh_fast(float x) {
  const float xc = fminf(fmaxf(x, -15.f), 15.f);
  const float e = __expf(-2.f * xc);
  return (1.f - e) / (1.f + e);
}
__device__ __forceinline__ ushort f2bf(float f) {       // RNE fp32 -> bf16
  uint u = __float_as_uint(f);
  u += 0x7FFFu + ((u >> 16) & 1u);
  return (ushort)(u >> 16);
}
__device__ __forceinline__ float bf2f(ushort h) {
  return __uint_as_float((uint)h << 16);
}
__device__ __forceinline__ float dot4(float4 a, float4 b) {
  return a.x*b.x + a.y*b.y + a.z*b.z + a.w*b.w;
}

// 64x64 tile transpose helper for the extra blocks embedded in gru_scan.
// 512 threads. dstH != nullptr -> bf16 output, else fp32 via dstF.
__device__ void trans_tile_512(const float* __restrict__ srcA,
                               const float* __restrict__ srcB,
                               const int split, const int stride, const int Krows,
                               const int k0, const int n0,
                               ushort* __restrict__ dstH, float* __restrict__ dstF)
{
  __shared__ float tt[64][65];
  const int tid = threadIdx.x;
  const int j = tid & 63, i0 = tid >> 6;    // i0: 0..7
  {
    const int n = n0 + j;
    const float* s = (n < split) ? (srcA + n) : (srcB + (n - split));
    #pragma unroll
    for (int i = i0; i < 64; i += 8)
      tt[i][j] = s[(size_t)(k0 + i) * stride];
  }
  __syncthreads();
  const int ii = tid & 63;
  if (dstH != nullptr) {
    #pragma unroll
    for (int jj = i0; jj < 64; jj += 8)
      dstH[(size_t)(n0 + jj) * Krows + k0 + ii] = f2bf(tt[ii][jj]);
  } else {
    #pragma unroll
    for (int jj = i0; jj < 64; jj += 8)
      dstF[(size_t)(n0 + jj) * Krows + k0 + ii] = tt[ii][jj];
  }
}

// ---------------------------------------------------------------------------
// Persistent bidirectional GRU scan — tagged-packet sync + MFMA matvec.
// Blocks 0..127: the scan (structure unchanged from round 12 — at the
// measured sync floor ~2.0 us/step = P(~1.4) + C(~0.65)).
// Blocks 128..1023: one 64x64 weight-transpose tile each (Whbf / redWt /
// decWUt / WsT / fcT), hidden on idle CUs under the scan; they never wait
// on the scan, so no deadlock regardless of dispatch order.
// ---------------------------------------------------------------------------
__global__ __launch_bounds__(512) void gru_scan(
    const ushort* __restrict__ xzm,           // [32*400][3072] bf16 fw|bw
    const ushort* __restrict__ Utbf,          // [2][1536][512] bf16 (U^T)
    const float* __restrict__ bfw, const float* __restrict__ bbw,
    float* __restrict__ enc_seq, ushort* __restrict__ enc_bf,
    ull* __restrict__ hpkt,
    // transpose-job inputs/outputs (blocks >= 128)
    const float* __restrict__ att_Wh, const float* __restrict__ red_W,
    const float* __restrict__ dec_W, const float* __restrict__ dec_U,
    const float* __restrict__ att_Ws, const float* __restrict__ fc_W,
    ushort* __restrict__ Whbf, float* __restrict__ redWt,
    float* __restrict__ decWUt, float* __restrict__ WsT,
    float* __restrict__ fcT)
{
  if (blockIdx.x >= 128) {
    const int tb = blockIdx.x - 128;
    if (tb < 128) {                 // Whbf[n<512][k<1024] = bf16(att_Wh[k][n])
      trans_tile_512(att_Wh, att_Wh, 512, 512, 1024,
                     (tb % 16) * 64, (tb / 16) * 64, Whbf, nullptr);
    } else if (tb < 256) {          // redWt[n<512][k<1024] = red_W[k][n]
      const int t = tb - 128;
      trans_tile_512(red_W, red_W, 512, 512, 1024,
                     (t % 16) * 64, (t / 16) * 64, nullptr, redWt);
    } else if (tb < 640) {          // decWUt[n<3072][k<512] = {dec_W|dec_U}[k][n]
      const int t = tb - 256;
      trans_tile_512(dec_W, dec_U, G3, G3, 512,
                     (t % 8) * 64, (t / 8) * 64, nullptr, decWUt);
    } else if (tb < 704) {          // WsT[n<512][k<512] = att_Ws[k][n]
      const int t = tb - 640;
      trans_tile_512(att_Ws, att_Ws, 512, 512, 512,
                     (t % 8) * 64, (t / 8) * 64, nullptr, WsT);
    } else {                        // fcT[n<512][k<1536] = fc_W[k][n]
      const int t = tb - 704;
      trans_tile_512(fc_W, fc_W, 512, 512, 1536,
                     (t % 24) * 64, (t / 24) * 64, nullptr, fcT);
    }
    return;
  }

  const int bid = blockIdx.x;        // 0..127
  const int group = bid & 7;
  const int dir = group >> 2;
  const int bg  = group & 3;
  const int ht  = bid >> 3;          // 0..15: j-tile of 32
  const int tid = threadIdx.x;
  const int lane = tid & 63;
  const int w  = tid >> 6;           // wave 0..7
  const int l15 = lane & 15;
  const int lk  = lane >> 4;

  const float* __restrict__ br = (dir ? bbw : bfw) + G3;   // bias row 1

  // U fragments in registers (waves 0..5): gate = w%3, jh = w/3 (16 j's).
  const int gate = w % 3, jh = w / 3;
  bf16x8 ufrag[16];
  if (w < 6) {
    const ushort* ub = Utbf + ((size_t)dir * G3 + gate * 512 + ht * 32 + jh * 16 + l15) * 512
                     + lk * 8;
    #pragma unroll
    for (int s = 0; s < 16; ++s)
      ufrag[s] = *(const bf16x8*)(ub + s * 32);
  }

  __shared__ ushort h_bf[16][520];       // bf16 h, rows 8-15 zero (16.6 KB)
  __shared__ float redm[3][8][32];       // [gate][batch][j32] (3 KB)

  // zero h_bf once (rows 8-15 stay zero forever)
  for (int i = tid; i < 16 * 520; i += 512) ((ushort*)h_bf)[i] = 0;

  // consumer mapping: wave w = batch-in-group
  const int cb = w;
  // gate/producer mapping (threads 0..255)
  const int gbi = tid >> 5;              // 0..7 for tid<256
  const int gj  = tid & 31;
  const int gjq = ht * 32 + gj;
  const int gb  = bg * 8 + (gbi & 7);
  const float brz = br[gjq], brr = br[512 + gjq], brh = br[1024 + gjq];

  ull* __restrict__ pk = hpkt + (size_t)dir * (2 * BATCH * HID);   // [parity][b][j]
  __syncthreads();   // h_bf zero visible

  for (int t = 0; t < S_LEN; ++t) {
    const int ts = dir ? (S_LEN - 1 - t) : t;

    // xz prefetch (bf16, independent of h; overlaps the poll)
    float xzv0 = 0.f, xzv1 = 0.f, xzv2 = 0.f;
    if (tid < 256) {
      const ushort* xp = xzm + ((size_t)gb * S_LEN + ts) * N2 + dir * G3 + gjq;
      xzv0 = bf2f(xp[0]); xzv1 = bf2f(xp[512]); xzv2 = bf2f(xp[1024]);
    }

    // ---- consume h(t): coalesced tagged poll (+ own fp32 hold, tid<256) ----
    float hold = 0.f;
    {
      ull* bp = pk + ((size_t)(t & 1) * BATCH + (bg * 8 + cb)) * HID + lane;
      ull* hp = pk + ((size_t)(t & 1) * BATCH + gb) * HID + gjq;
      const uint tu = (uint)t;
      for (;;) {
        ull v0 = __hip_atomic_load(bp,       __ATOMIC_RELAXED, __HIP_MEMORY_SCOPE_AGENT);
        ull v1 = __hip_atomic_load(bp + 64,  __ATOMIC_RELAXED, __HIP_MEMORY_SCOPE_AGENT);
        ull v2 = __hip_atomic_load(bp + 128, __ATOMIC_RELAXED, __HIP_MEMORY_SCOPE_AGENT);
        ull v3 = __hip_atomic_load(bp + 192, __ATOMIC_RELAXED, __HIP_MEMORY_SCOPE_AGENT);
        ull v4 = __hip_atomic_load(bp + 256, __ATOMIC_RELAXED, __HIP_MEMORY_SCOPE_AGENT);
        ull v5 = __hip_atomic_load(bp + 320, __ATOMIC_RELAXED, __HIP_MEMORY_SCOPE_AGENT);
        ull v6 = __hip_atomic_load(bp + 384, __ATOMIC_RELAXED, __HIP_MEMORY_SCOPE_AGENT);
        ull v7 = __hip_atomic_load(bp + 448, __ATOMIC_RELAXED, __HIP_MEMORY_SCOPE_AGENT);
        bool ok = ((uint)(v0 >> 32) == tu) & ((uint)(v1 >> 32) == tu)
                & ((uint)(v2 >> 32) == tu) & ((uint)(v3 >> 32) == tu)
                & ((uint)(v4 >> 32) == tu) & ((uint)(v5 >> 32) == tu)
                & ((uint)(v6 >> 32) == tu) & ((uint)(v7 >> 32) == tu);
        ull hv = 0;
        if (tid < 256) {
          hv = __hip_atomic_load(hp, __ATOMIC_RELAXED, __HIP_MEMORY_SCOPE_AGENT);
          ok &= ((uint)(hv >> 32) == tu);
        }
        if (__all(ok)) {
          h_bf[cb][lane]       = f2bf(__uint_as_float((uint)v0));
          h_bf[cb][lane + 64]  = f2bf(__uint_as_float((uint)v1));
          h_bf[cb][lane + 128] = f2bf(__uint_as_float((uint)v2));
          h_bf[cb][lane + 192] = f2bf(__uint_as_float((uint)v3));
          h_bf[cb][lane + 256] = f2bf(__uint_as_float((uint)v4));
          h_bf[cb][lane + 320] = f2bf(__uint_as_float((uint)v5));
          h_bf[cb][lane + 384] = f2bf(__uint_as_float((uint)v6));
          h_bf[cb][lane + 448] = f2bf(__uint_as_float((uint)v7));
          if (tid < 256) hold = __uint_as_float((uint)hv);
          break;
        }
        __builtin_amdgcn_s_sleep(1);
      }
    }
    __syncthreads();   // S1: h_bf ready

    // ---- recurrent matvec: MFMA 16x16x32 bf16, waves 0..5, full K ----
    if (w < 6) {
      f32x4 acc = f32x4{0.f, 0.f, 0.f, 0.f};
      #pragma unroll
      for (int s = 0; s < 16; ++s) {
        const bf16x8 af = *(const bf16x8*)&h_bf[l15][s * 32 + lk * 8];
        acc = __builtin_amdgcn_mfma_f32_16x16x32_bf16(af, ufrag[s], acc, 0, 0, 0);
      }
      if (lk < 2) {   // rows 0..7 = real batches
        #pragma unroll
        for (int r = 0; r < 4; ++r)
          redm[gate][lk * 4 + r][jh * 16 + l15] = acc[r];
      }
    }
    __syncthreads();   // S2: redm ready

    // ---- gates + publish h(t+1) ----
    if (tid < 256) {
      const float rz = redm[0][gbi][gj] + brz;
      const float rr = redm[1][gbi][gj] + brr;
      const float rh = redm[2][gbi][gj] + brh;
      const float z  = sigf(xzv0 + rz);
      const float r  = sigf(xzv1 + rr);
      const float hh = tanh_fast(xzv2 + r * rh);
      const float hnew = z * hold + (1.f - z) * hh;
      const ull pack = ((ull)(uint)(t + 1) << 32) | (ull)__float_as_uint(hnew);
      __hip_atomic_store(pk + ((size_t)((t + 1) & 1) * BATCH + gb) * HID + gjq,
                         pack, __ATOMIC_RELAXED, __HIP_MEMORY_SCOPE_AGENT);
      const size_t eidx = ((size_t)gb * S_LEN + ts) * 1024 + dir * 512 + gjq;
      enc_seq[eidx] = hnew;
      enc_bf[eidx]  = f2bf(hnew);
    }
    __syncthreads();   // S3: publishes issued; h_bf/redm safe for next fill
  }
}

// ---------------------------------------------------------------------------
// Gather + convert: A_bf[r][k] = bf16(emb[x_id[r]][k]).  3200 blocks x 256.
// ---------------------------------------------------------------------------
__global__ __launch_bounds__(256) void k_cvtA(
    const int* __restrict__ x_id, const float* __restrict__ emb,
    ushort* __restrict__ Abf)
{
  const int tid = threadIdx.x;
  const int row = blockIdx.x * 4 + (tid >> 6);
  const int k8 = (tid & 63) * 8;
  const int rid = x_id[row];
  const float4 e0 = *(const float4*)&emb[(size_t)rid * 512 + k8];
  const float4 e1 = *(const float4*)&emb[(size_t)rid * 512 + k8 + 4];
  u16x8 o;
  o[0] = f2bf(e0.x); o[1] = f2bf(e0.y); o[2] = f2bf(e0.z); o[3] = f2bf(e0.w);
  o[4] = f2bf(e1.x); o[5] = f2bf(e1.y); o[6] = f2bf(e1.z); o[7] = f2bf(e1.w);
  *(u16x8*)&Abf[(size_t)row * 512 + k8] = o;
}

// ---------------------------------------------------------------------------
// Upfront transposes in ONE launch (768 blocks x 256 thr):
//  b <384: Wt[n<3072][k<512] = bf16({fwW|bwW}[k][n]) + bias merge
//  384..575: Utbf fw;  576..767: Utbf bw
// ---------------------------------------------------------------------------
__global__ __launch_bounds__(256) void k_transUp(
    const float* __restrict__ fwW, const float* __restrict__ bwW,
    const float* __restrict__ fwb, const float* __restrict__ bwb,
    const float* __restrict__ fwU, const float* __restrict__ bwU,
    ushort* __restrict__ Wt, float* __restrict__ bm,
    ushort* __restrict__ Utbf)
{
  __shared__ float tt[64][65];
  const int b = blockIdx.x;
  const int tid = threadIdx.x;
  const int j = tid & 63, i0 = tid >> 6;   // i0: 0..3
  const float* srcA; const float* srcB; int split, k0, n0; ushort* dst;
  if (b < 384)      { srcA = fwW; srcB = bwW; split = G3;
                      k0 = (b % 8) * 64; n0 = (b / 8) * 64; dst = Wt; }
  else if (b < 576) { const int t = b - 384; srcA = fwU; srcB = fwU; split = N2;
                      k0 = (t % 8) * 64; n0 = (t / 8) * 64; dst = Utbf; }
  else              { const int t = b - 576; srcA = bwU; srcB = bwU; split = N2;
                      k0 = (t % 8) * 64; n0 = (t / 8) * 64;
                      dst = Utbf + (size_t)G3 * 512; }
  {
    const int n = n0 + j;
    const float* s = (n < split) ? (srcA + n) : (srcB + (n - split));
    #pragma unroll
    for (int i = i0; i < 64; i += 4)
      tt[i][j] = s[(size_t)(k0 + i) * G3];
  }
  __syncthreads();
  const int ii = tid & 63;
  #pragma unroll
  for (int jj = i0; jj < 64; jj += 4)
    dst[(size_t)(n0 + jj) * 512 + k0 + ii] = f2bf(tt[ii][jj]);
  if (b < 384 && k0 == 0 && tid < 64) {
    const int n = n0 + tid;
    bm[n] = (n < G3) ? fwb[n] : bwb[n - G3];
  }
}

// ---------------------------------------------------------------------------
// bf16 MFMA GEMM: C[12800][3072] = A[12800][512] @ Wt^T + bm, C in bf16.
// 128x128 tile, 256 thr (4 waves), 16x16x32 bf16 MFMA, fp32 accum.
// ---------------------------------------------------------------------------
__global__ __launch_bounds__(256) void gemm_bf16(
    const ushort* __restrict__ A,    // [M][512] bf16
    const ushort* __restrict__ Bt,   // [N][512] bf16 (row n = W col n)
    const float* __restrict__ bias,  // [N] fp32
    ushort* __restrict__ C)          // [M][3072] bf16
{
  const int m0 = blockIdx.y * 128, n0 = blockIdx.x * 128;
  const int tid = threadIdx.x;
  const int w = tid >> 6, lane = tid & 63;
  const int l15 = lane & 15, lk = lane >> 4;
  __shared__ short As[128][40];      // +8 pad: row stride 80B (16B-aligned)
  __shared__ short Bs[128][40];
  f32x4 acc[2][8];
  #pragma unroll
  for (int i = 0; i < 2; ++i)
    #pragma unroll
    for (int j = 0; j < 8; ++j) acc[i][j] = f32x4{0.f, 0.f, 0.f, 0.f};

  const int sr = tid >> 1;           // stage row 0..127
  const int sc = (tid & 1) * 8;      // k-offset 0 or 8

  for (int k0 = 0; k0 < 512; k0 += 32) {
    const uint4 a0 = *(const uint4*)&A[(size_t)(m0 + sr) * 512 + k0 + sc];
    const uint4 a1 = *(const uint4*)&A[(size_t)(m0 + sr) * 512 + k0 + 16 + sc];
    const uint4 b0 = *(const uint4*)&Bt[(size_t)(n0 + sr) * 512 + k0 + sc];
    const uint4 b1 = *(const uint4*)&Bt[(size_t)(n0 + sr) * 512 + k0 + 16 + sc];
    *(uint4*)&As[sr][sc]      = a0;
    *(uint4*)&As[sr][16 + sc] = a1;
    *(uint4*)&Bs[sr][sc]      = b0;
    *(uint4*)&Bs[sr][16 + sc] = b1;
    __syncthreads();

    bf16x8 af[2], bfr[8];
    #pragma unroll
    for (int rf = 0; rf < 2; ++rf)
      af[rf] = *(const bf16x8*)&As[w * 32 + rf * 16 + l15][lk * 8];
    #pragma unroll
    for (int cf = 0; cf < 8; ++cf)
      bfr[cf] = *(const bf16x8*)&Bs[cf * 16 + l15][lk * 8];
    #pragma unroll
    for (int rf = 0; rf < 2; ++rf)
      #pragma unroll
      for (int cf = 0; cf < 8; ++cf)
        acc[rf][cf] = __builtin_amdgcn_mfma_f32_16x16x32_bf16(
            af[rf], bfr[cf], acc[rf][cf], 0, 0, 0);
    __syncthreads();
  }

  #pragma unroll
  for (int rf = 0; rf < 2; ++rf) {
    #pragma unroll
    for (int cf = 0; cf < 8; ++cf) {
      const int col = n0 + cf * 16 + l15;
      const float bv = bias[col];
      const int rowb = m0 + w * 32 + rf * 16 + lk * 4;
      #pragma unroll
      for (int r = 0; r < 4; ++r)
        C[(size_t)(rowb + r) * N2 + col] = f2bf(acc[rf][cf][r] + bv);
    }
  }
}

// ---------------------------------------------------------------------------
// bf16 MFMA attention-score GEMM with fused epilogue:
// e_part[row][bx] = sum_n attV[n] * tanh(enc_bf[row]@Wh[:,n] + dterm[b][n])
// ---------------------------------------------------------------------------
__global__ __launch_bounds__(256) void gemm_att(
    const ushort* __restrict__ A,    // [12800][1024] bf16
    const ushort* __restrict__ Bt,   // [512][1024] bf16
    const float* __restrict__ dterm, // [32][512] fp32
    const float* __restrict__ attV,  // [512] fp32
    float* __restrict__ e_part)      // [12800][4]
{
  const int m0 = blockIdx.y * 128, n0 = blockIdx.x * 128;
  const int tid = threadIdx.x;
  const int w = tid >> 6, lane = tid & 63;
  const int l15 = lane & 15, lk = lane >> 4;
  __shared__ short As[128][40];
  __shared__ short Bs[128][40];
  f32x4 acc[2][8];
  #pragma unroll
  for (int i = 0; i < 2; ++i)
    #pragma unroll
    for (int j = 0; j < 8; ++j) acc[i][j] = f32x4{0.f, 0.f, 0.f, 0.f};

  const int sr = tid >> 1;
  const int sc = (tid & 1) * 8;

  for (int k0 = 0; k0 < 1024; k0 += 32) {
    const uint4 a0 = *(const uint4*)&A[(size_t)(m0 + sr) * 1024 + k0 + sc];
    const uint4 a1 = *(const uint4*)&A[(size_t)(m0 + sr) * 1024 + k0 + 16 + sc];
    const uint4 b0 = *(const uint4*)&Bt[(size_t)(n0 + sr) * 1024 + k0 + sc];
    const uint4 b1 = *(const uint4*)&Bt[(size_t)(n0 + sr) * 1024 + k0 + 16 + sc];
    *(uint4*)&As[sr][sc]      = a0;
    *(uint4*)&As[sr][16 + sc] = a1;
    *(uint4*)&Bs[sr][sc]      = b0;
    *(uint4*)&Bs[sr][16 + sc] = b1;
    __syncthreads();

    bf16x8 af[2], bfr[8];
    #pragma unroll
    for (int rf = 0; rf < 2; ++rf)
      af[rf] = *(const bf16x8*)&As[w * 32 + rf * 16 + l15][lk * 8];
    #pragma unroll
    for (int cf = 0; cf < 8; ++cf)
      bfr[cf] = *(const bf16x8*)&Bs[cf * 16 + l15][lk * 8];
    #pragma unroll
    for (int rf = 0; rf < 2; ++rf)
      #pragma unroll
      for (int cf = 0; cf < 8; ++cf)
        acc[rf][cf] = __builtin_amdgcn_mfma_f32_16x16x32_bf16(
            af[rf], bfr[cf], acc[rf][cf], 0, 0, 0);
    __syncthreads();
  }

  #pragma unroll
  for (int rf = 0; rf < 2; ++rf) {
    #pragma unroll
    for (int r = 0; r < 4; ++r) {
      const int row = m0 + w * 32 + rf * 16 + lk * 4 + r;
      const int b = row / S_LEN;
      float p = 0.f;
      #pragma unroll
      for (int cf = 0; cf < 8; ++cf) {
        const int col = n0 + cf * 16 + l15;
        p += attV[col] * tanh_fast(acc[rf][cf][r] + dterm[(size_t)b * 512 + col]);
      }
      p += __shfl_xor(p, 1); p += __shfl_xor(p, 2);
      p += __shfl_xor(p, 4); p += __shfl_xor(p, 8);
      if (l15 == 0) e_part[(size_t)row * 4 + blockIdx.x] = p;
    }
  }
}

// --------------------------- small kernels (transposed weights) ------------
__global__ __launch_bounds__(128) void k_state(const float* __restrict__ enc,
    const float* __restrict__ redWt,  // [512][1024] fp32: row j = red_W col j
    const float* __restrict__ red_b, float* __restrict__ state)
{
  const int b = blockIdx.y;
  const int j = blockIdx.x*128 + threadIdx.x;
  const float4* wr = (const float4*)(redWt + (size_t)j * 1024);
  const float4* fw = (const float4*)(enc + ((size_t)b*S_LEN + (S_LEN-1))*1024);
  const float4* bw = (const float4*)(enc + ((size_t)b*S_LEN)*1024 + 512);
  float acc = red_b[j];
  #pragma unroll 4
  for (int k = 0; k < 128; ++k) acc += dot4(fw[k], wr[k]);
  #pragma unroll 4
  for (int k = 0; k < 128; ++k) acc += dot4(bw[k], wr[128 + k]);
  state[(size_t)b*512 + j] = fmaxf(acc, 0.f);
}

__global__ __launch_bounds__(128) void k_dec(
    const int* __restrict__ y_id, const float* __restrict__ emb,
    const float* __restrict__ state,
    const float* __restrict__ decWUt, // [3072][512]: rows 0-1535 decW^T, 1536+ decU^T
    const float* __restrict__ dec_b, float* __restrict__ dst)
{
  const int b = blockIdx.y;
  const int j = blockIdx.x*128 + threadIdx.x;
  const float4* ye = (const float4*)(emb + (size_t)y_id[b] * 512);
  const float4* st = (const float4*)(state + (size_t)b * 512);
  const float4* w0 = (const float4*)(decWUt + (size_t)(j)        * 512);
  const float4* w1 = (const float4*)(decWUt + (size_t)(512  + j) * 512);
  const float4* w2 = (const float4*)(decWUt + (size_t)(1024 + j) * 512);
  const float4* u0 = (const float4*)(decWUt + (size_t)(G3 + j)        * 512);
  const float4* u1 = (const float4*)(decWUt + (size_t)(G3 + 512  + j) * 512);
  const float4* u2 = (const float4*)(decWUt + (size_t)(G3 + 1024 + j) * 512);
  float xz0 = dec_b[j], xz1 = dec_b[512+j], xz2 = dec_b[1024+j];
  float rc0 = dec_b[G3+j], rc1 = dec_b[G3+512+j], rc2 = dec_b[G3+1024+j];
  #pragma unroll 2
  for (int k = 0; k < 128; ++k) {
    const float4 yv = ye[k], sv = st[k];
    xz0 += dot4(yv, w0[k]); xz1 += dot4(yv, w1[k]); xz2 += dot4(yv, w2[k]);
    rc0 += dot4(sv, u0[k]); rc1 += dot4(sv, u1[k]); rc2 += dot4(sv, u2[k]);
  }
  const float z  = sigf(xz0 + rc0);
  const float r  = sigf(xz1 + rc1);
  const float hh = tanh_fast(xz2 + r*rc2);
  const float sj = state[(size_t)b*512 + j];
  dst[(size_t)b*512 + j] = z*sj + (1.f-z)*hh;
}

__global__ __launch_bounds__(128) void k_dterm(const float* __restrict__ dec,
    const float* __restrict__ WsT,   // [512][512] fp32: row j = att_Ws col j
    const float* __restrict__ att_bs, float* __restrict__ dterm)
{
  const int b = blockIdx.y;
  const int j = blockIdx.x*128 + threadIdx.x;
  const float4* d = (const float4*)(dec + (size_t)b*512);
  const float4* wr = (const float4*)(WsT + (size_t)j * 512);
  float acc = att_bs[j];
  #pragma unroll 4
  for (int k = 0; k < 128; ++k) acc += dot4(d[k], wr[k]);
  dterm[(size_t)b*512 + j] = acc;
}

__global__ __launch_bounds__(512) void k_soft(const float* __restrict__ e_part,
    const int* __restrict__ x_mask, float* __restrict__ wat)
{
  const int b = blockIdx.x, tid = threadIdx.x;
  __shared__ float sm[512];
  float e = -1e30f, ev = 0.f;
  if (tid < S_LEN) {
    const float* ep = e_part + (size_t)(b*S_LEN + tid)*4;
    ev = ep[0]+ep[1]+ep[2]+ep[3] + (float)x_mask[b*S_LEN+tid] * -1e10f;
    e = ev;
  }
  sm[tid] = e; __syncthreads();
  for (int s = 256; s > 0; s >>= 1) { if (tid < s) sm[tid] = fmaxf(sm[tid], sm[tid+s]); __syncthreads(); }
  const float m = sm[0]; __syncthreads();
  const float x = (tid < S_LEN) ? __expf(ev - m) : 0.f;
  sm[tid] = x; __syncthreads();
  for (int s = 256; s > 0; s >>= 1) { if (tid < s) sm[tid] += sm[tid+s]; __syncthreads(); }
  const float inv = 1.f / sm[0];
  if (tid < S_LEN) wat[b*S_LEN+tid] = x * inv;
}

__global__ __launch_bounds__(128) void k_ctx(const float* __restrict__ wat,
    const float* __restrict__ enc, float* __restrict__ ctx)
{
  const int b = blockIdx.y;
  const int j = blockIdx.x*128 + threadIdx.x;
  float acc = 0.f;
  const float* w = wat + b*S_LEN;
  const float* ep = enc + (size_t)b*S_LEN*1024 + j;
  #pragma unroll 4
  for (int s = 0; s < S_LEN; ++s) acc += w[s] * ep[(size_t)s*1024];
  ctx[(size_t)b*1024 + j] = acc;
}

__global__ __launch_bounds__(128) void k_yout(const float* __restrict__ dec,
    const float* __restrict__ ctx,
    const float* __restrict__ fcT,   // [512][1536] fp32: row j = fc_W col j
    const float* __restrict__ fc_b, float* __restrict__ y_out)
{
  const int b = blockIdx.y;
  const int j = blockIdx.x*128 + threadIdx.x;
  const float4* d = (const float4*)(dec + (size_t)b*512);
  const float4* c = (const float4*)(ctx + (size_t)b*1024);
  const float4* wr = (const float4*)(fcT + (size_t)j * 1536);
  float acc = fc_b[j];
  #pragma unroll 4
  for (int k = 0; k < 128; ++k) acc += dot4(d[k], wr[k]);
  #pragma unroll 4
  for (int k = 0; k < 256; ++k) acc += dot4(c[k], wr[128 + k]);
  y_out[(size_t)b*512 + j] = acc;
}

__global__ __launch_bounds__(256) void k_pgen(const float* __restrict__ ctx,
    const float* __restrict__ dec,
    const int* __restrict__ y_id, const float* __restrict__ emb,
    const float* __restrict__ pg_Wh, const float* __restrict__ pg_Ws,
    const float* __restrict__ pg_Wx, const float* __restrict__ pg_b,
    float* __restrict__ pg)
{
  const int b = blockIdx.x, tid = threadIdx.x;
  __shared__ float sm[256];
  const float* ye = emb + (size_t)y_id[b] * 512;
  float acc = 0.f;
  for (int k = tid; k < 1024; k += 256) acc += ctx[(size_t)b*1024+k]*pg_Wh[k];
  for (int k = tid; k < 512;  k += 256) acc += dec[(size_t)b*512+k]*pg_Ws[k] + ye[k]*pg_Wx[k];
  sm[tid] = acc; __syncthreads();
  for (int s = 128; s > 0; s >>= 1) { if (tid < s) sm[tid] += sm[tid+s]; __syncthreads(); }
  if (tid == 0) pg[b] = sigf(sm[0] + pg_b[0]);
}

__global__ __launch_bounds__(256) void k_vocab(const float* __restrict__ y_out,
    const float* __restrict__ vocab_W, float* __restrict__ logits)
{
  __shared__ float y_lds[256][32];   // [k][b], one k-half at a time (32 KB)
  const int tid = threadIdx.x;
  const int vq = tid & 63, bq = tid >> 6;
  const int v = blockIdx.x * 256 + vq * 4;
  float acc[8][4];
  #pragma unroll
  for (int i = 0; i < 8; ++i)
    #pragma unroll
    for (int j = 0; j < 4; ++j) acc[i][j] = 0.f;
  for (int half = 0; half < 2; ++half) {
    __syncthreads();
    for (int i = 0; i < 32; ++i) {
      const int idx = tid + 256*i;
      const int k = idx >> 5, b = idx & 31;
      y_lds[k][b] = y_out[(size_t)b*512 + half*256 + k];
    }
    __syncthreads();
    if (v < VOC) {
      #pragma unroll 4
      for (int k = 0; k < 256; ++k) {
        const float4 wv = *(const float4*)&vocab_W[(size_t)(half*256 + k) * VOC + v];
        const float4 ya = *(const float4*)&y_lds[k][bq*8];
        const float4 yb = *(const float4*)&y_lds[k][bq*8+4];
        const float yy[8] = {ya.x,ya.y,ya.z,ya.w,yb.x,yb.y,yb.z,yb.w};
        #pragma unroll
        for (int i = 0; i < 8; ++i) {
          acc[i][0] += yy[i]*wv.x; acc[i][1] += yy[i]*wv.y;
          acc[i][2] += yy[i]*wv.z; acc[i][3] += yy[i]*wv.w;
        }
      }
    }
  }
  if (v < VOC) {
    #pragma unroll
    for (int i = 0; i < 8; ++i)
      *(float4*)&logits[(size_t)(bq*8+i)*VOC + v] = make_float4(acc[i][0],acc[i][1],acc[i][2],acc[i][3]);
  }
}

__global__ __launch_bounds__(1024) void k_vred(const float* __restrict__ logits,
                                               float* __restrict__ red2)
{
  const int b = blockIdx.x, tid = threadIdx.x;
  __shared__ float sm[1024];
  float m = -1e30f;
  for (int i = tid; i < VOC; i += 1024) m = fmaxf(m, logits[(size_t)b*VOC + i]);
  sm[tid] = m; __syncthreads();
  for (int s = 512; s > 0; s >>= 1) { if (tid < s) sm[tid] = fmaxf(sm[tid], sm[tid+s]); __syncthreads(); }
  m = sm[0]; __syncthreads();
  float sum = 0.f;
  for (int i = tid; i < VOC; i += 1024) sum += __expf(logits[(size_t)b*VOC + i] - m);
  sm[tid] = sum; __syncthreads();
  for (int s = 512; s > 0; s >>= 1) { if (tid < s) sm[tid] += sm[tid+s]; __syncthreads(); }
  if (tid == 0) { red2[b*2] = m; red2[b*2+1] = sm[0]; }
}

__global__ __launch_bounds__(256) void k_final(const float* __restrict__ logits,
    const float* __restrict__ red2, const float* __restrict__ pg,
    float* __restrict__ out)
{
  const size_t idx = (size_t)blockIdx.x*256 + threadIdx.x;
  const int b = (int)(idx / OUTW);
  const int c = (int)(idx - (size_t)b*OUTW);
  float v = 0.f;
  if (c < VOC) {
    const float m = red2[b*2], s = red2[b*2+1];
    v = pg[b] * __expf(logits[(size_t)b*VOC + c] - m) / s;
  }
  out[idx] = v;
}

__global__ __launch_bounds__(256) void k_scatter(const float* __restrict__ wat,
    const int* __restrict__ x_mask, const float* __restrict__ pg,
    const int* __restrict__ x_id, float* __restrict__ out)
{
  const int i = blockIdx.x*256 + threadIdx.x;   // < 12800
  const int b = i / S_LEN;
  const float aw = wat[i] * (1.f - (float)x_mask[i]) * (1.f - pg[b]);
  atomicAdd(out + (size_t)b*OUTW + x_id[i], aw);
}

// ---------------------------------------------------------------------------
extern "C" void kernel_launch(void* const* d_in, const int* in_sizes, int n_in,
                              void* d_out, int out_size, void* d_ws, size_t ws_size,
                              hipStream_t stream)
{
  (void)in_sizes; (void)n_in; (void)out_size; (void)ws_size;
  const int*   x_id     = (const int*)d_in[0];
  const int*   y_id     = (const int*)d_in[1];
  const int*   x_mask   = (const int*)d_in[2];
  const float* emb      = (const float*)d_in[3];
  const float* enc_fw_W = (const float*)d_in[4];
  const float* enc_fw_U = (const float*)d_in[5];
  const float* enc_fw_b = (const float*)d_in[6];
  const float* enc_bw_W = (const float*)d_in[7];
  const float* enc_bw_U = (const float*)d_in[8];
  const float* enc_bw_b = (const float*)d_in[9];
  const float* red_W    = (const float*)d_in[10];
  const float* red_b    = (const float*)d_in[11];
  const float* dec_W    = (const float*)d_in[12];
  const float* dec_U    = (const float*)d_in[13];
  const float* dec_b    = (const float*)d_in[14];
  const float* att_Wh   = (const float*)d_in[15];
  const float* att_Ws   = (const float*)d_in[16];
  const float* att_bs   = (const float*)d_in[17];
  const float* att_Wc   = (const float*)d_in[18]; (void)att_Wc; // cover == 0
  const float* att_V    = (const float*)d_in[19];
  const float* fc_W     = (const float*)d_in[20];
  const float* fc_b     = (const float*)d_in[21];
  const float* vocab_W  = (const float*)d_in[22];
  const float* pg_Wh    = (const float*)d_in[23];
  const float* pg_Ws    = (const float*)d_in[24];
  const float* pg_Wx    = (const float*)d_in[25];
  const float* pg_b     = (const float*)d_in[26];
  float* out = (float*)d_out;

  const size_t NPKT = (size_t)2*2*BATCH*HID;            // [dir][parity][b][j]
  char* p = (char*)d_ws;
  ushort* xzm   = (ushort*)p; p += (size_t)BATCH*S_LEN*N2*2;     // 78.6 MB
  float*  enc   = (float*)p;  p += (size_t)BATCH*S_LEN*1024*4;   // 52.4 MB
  ushort* encbf = (ushort*)p; p += (size_t)BATCH*S_LEN*1024*2;   // 26.2 MB
  ull*   hpkt   = (ull*)p;    p += NPKT*8;                       // 1 MB
  ushort* Abf   = (ushort*)p; p += (size_t)BATCH*S_LEN*512*2;    // 13.1 MB
  ushort* Wt    = (ushort*)p; p += (size_t)N2*512*2;             // 3.1 MB
  ushort* Whbf  = (ushort*)p; p += (size_t)512*1024*2;           // 1.0 MB
  ushort* Utbf  = (ushort*)p; p += (size_t)2*G3*512*2;           // 3.1 MB
  float*  redWt = (float*)p;  p += (size_t)512*1024*4;           // 2.1 MB
  float*  decWUt= (float*)p;  p += (size_t)N2*512*4;             // 6.3 MB
  float*  WsT   = (float*)p;  p += (size_t)512*512*4;            // 1.0 MB
  float*  fcT   = (float*)p;  p += (size_t)512*1536*4;           // 3.1 MB
  float*  bm    = (float*)p;  p += (size_t)N2*4;
  float*  fstate = (float*)p; p += (size_t)BATCH*HID*4;
  float*  decs   = (float*)p; p += (size_t)BATCH*HID*4;
  float*  dterm  = (float*)p; p += (size_t)BATCH*HID*4;
  float*  epart  = (float*)p; p += (size_t)BATCH*S_LEN*4*4;
  float*  wat    = (float*)p; p += (size_t)BATCH*S_LEN*4;
  float*  ctx    = (float*)p; p += (size_t)BATCH*1024*4;
  float*  yout   = (float*)p; p += (size_t)BATCH*HID*4;
  float*  pg     = (float*)p; p += (size_t)256*4;
  float*  logits = (float*)p; p += (size_t)BATCH*VOC*4;          // 6.4 MB
  float*  red2   = (float*)p; p += (size_t)64*4;

  // zero the packet buffer: {0.0f, tag 0} == valid h(0) for every slot
  hipMemsetAsync(hpkt, 0, NPKT * sizeof(ull), stream);

  // upfront conversions: embedding gather + the two scan-critical transposes
  k_cvtA<<<BATCH*S_LEN/4, 256, 0, stream>>>(x_id, emb, Abf);
  k_transUp<<<768, 256, 0, stream>>>(enc_fw_W, enc_bw_W, enc_fw_b, enc_bw_b,
                                     enc_fw_U, enc_bw_U, Wt, bm, Utbf);
  // merged input projection (bf16 MFMA): xz = A @ [Wfw|Wbw] + [bfw0|bbw0]
  gemm_bf16<<<dim3(N2/128, BATCH*S_LEN/128), 256, 0, stream>>>(Abf, Wt, bm, xzm);
  // persistent bidirectional GRU scan; blocks 128.. run the post-scan weight
  // transposes (Whbf/redWt/decWUt/WsT/fcT) hidden on idle CUs
  gru_scan<<<128 + 896, 512, 0, stream>>>(xzm, Utbf, enc_fw_b, enc_bw_b,
                                          enc, encbf, hpkt,
                                          att_Wh, red_W, dec_W, dec_U, att_Ws,
                                          fc_W, Whbf, redWt, decWUt, WsT, fcT);
  // reduce state + decoder step + attention query term
  k_state<<<dim3(4,32),128,0,stream>>>(enc, redWt, red_b, fstate);
  k_dec<<<dim3(4,32),128,0,stream>>>(y_id, emb, fstate, decWUt, dec_b, decs);
  k_dterm<<<dim3(4,32),128,0,stream>>>(decs, WsT, att_bs, dterm);
  // attention scores (bf16 MFMA + fused tanh * att_V reduction)
  gemm_att<<<dim3(4, BATCH*S_LEN/128), 256, 0, stream>>>(encbf, Whbf, dterm,
                                                         att_V, epart);
  k_soft<<<32,512,0,stream>>>(epart, x_mask, wat);
  k_ctx<<<dim3(8,32),128,0,stream>>>(wat, enc, ctx);
  k_yout<<<dim3(4,32),128,0,stream>>>(decs, ctx, fcT, fc_b, yout);
  k_pgen<<<32,256,0,stream>>>(ctx, decs, y_id, emb, pg_Wh, pg_Ws, pg_Wx, pg_b, pg);
  // vocab distribution + final assembly
  k_vocab<<<196,256,0,stream>>>(yout, vocab_W, logits);
  k_vred<<<32,1024,0,stream>>>(logits, red2);
  k_final<<<6300,256,0,stream>>>(logits, red2, pg, out);
  k_scatter<<<50,256,0,stream>>>(wat, x_mask, pg, x_id, out);
}